// Round 3
// baseline (9391.210 us; speedup 1.0000x reference)
//
#include <hip/hip_runtime.h>
#include <cstddef>
#include <cstdint>

// ---------------------------------------------------------------------------
// Hyperbolic (Poincare-ball) entity-typing forward pass, MI355X / gfx950.
// Round 3: GRU with REGISTER-RESIDENT bf16 weights (192 u32/lane, 8 waves =
// full W_dir per block), LDS partial reduction, role-split gate math.
// Zero global weight traffic inside the 128-step recurrence.
// ---------------------------------------------------------------------------

#define EPS_  1e-15f
#define PMAX_ 0.99999f    // 1 - 1e-5

__device__ __forceinline__ float wred(float v){
#pragma unroll
  for (int o = 32; o; o >>= 1) v += __shfl_xor(v, o, 64);
  return v;
}
__device__ __forceinline__ void wred2(float& a, float& b){
#pragma unroll
  for (int o = 32; o; o >>= 1){ a += __shfl_xor(a, o, 64); b += __shfl_xor(b, o, 64); }
}
__device__ __forceinline__ void wred3(float& a, float& b, float& c){
#pragma unroll
  for (int o = 32; o; o >>= 1){
    a += __shfl_xor(a, o, 64); b += __shfl_xor(b, o, 64); c += __shfl_xor(c, o, 64);
  }
}
__device__ __forceinline__ float wredmax(float v){
#pragma unroll
  for (int o = 32; o; o >>= 1) v = fmaxf(v, __shfl_xor(v, o, 64));
  return v;
}
__device__ __forceinline__ float snorm(float s){ return sqrtf(fmaxf(s, EPS_)); }
__device__ __forceinline__ float clamp11(float x){
  return fminf(fmaxf(x, -1.f + 1e-7f), 1.f - 1e-7f);
}
__device__ __forceinline__ float bf2f(unsigned short u){
  union { unsigned int i; float f; } v; v.i = ((unsigned int)u) << 16; return v.f;
}
__device__ __forceinline__ unsigned short f2bf(float f){
  union { float f; unsigned int i; } v; v.f = f;
  unsigned int x = v.i;
  x += 0x7fffu + ((x >> 16) & 1u);   // RNE
  return (unsigned short)(x >> 16);
}
__device__ __forceinline__ float bflo(unsigned u){
  union { unsigned i; float f; } v; v.i = u << 16; return v.f;
}
__device__ __forceinline__ float bfhi(unsigned u){
  union { unsigned i; float f; } v; v.i = u & 0xffff0000u; return v.f;
}

template<int N>
__device__ __forceinline__ float sq_part(const float* a){
  float s = 0.f;
#pragma unroll
  for (int i = 0; i < N; i++) s += a[i]*a[i];
  return s;
}
template<int N>
__device__ __forceinline__ float dot_part(const float* a, const float* b){
  float s = 0.f;
#pragma unroll
  for (int i = 0; i < N; i++) s += a[i]*b[i];
  return s;
}
// mobius_add given full-row scalars x2,y2,xy
template<int N>
__device__ __forceinline__ void madd_vec(const float* x, float x2, const float* y,
                                         float y2, float xy, float* o){
  const float c1 = 1.f + 2.f*xy + y2;
  const float c2 = 1.f - x2;
  const float inv = 1.f / fmaxf(1.f + 2.f*xy + x2*y2, EPS_);
#pragma unroll
  for (int i = 0; i < N; i++) o[i] = (c1*x[i] + c2*y[i]) * inv;
}
// mobius_matvec tail: v = mx (in place) -> project(tanh(mxn/xn*artanh(xn))*mx/mxn)
template<int N>
__device__ __forceinline__ void mt_project(float* v, float mxn2, float xn2, float* n2out){
  const float xn  = snorm(xn2);
  const float mxn = snorm(mxn2);
  const float t   = tanhf(mxn/xn * atanhf(clamp11(xn)));
  float sc = t/mxn;
  float n2 = sc*sc*mxn2;
  const float n = snorm(n2);
  if (n > PMAX_){ const float s = PMAX_/n; sc *= s; n2 *= s*s; }
#pragma unroll
  for (int i = 0; i < N; i++) v[i] *= sc;
  *n2out = n2;
}
// scalar-only variant: sc and n2 from mxn2, with xn & artanh(xn) precomputed
__device__ __forceinline__ void mt_scale(float mxn2, float xn, float art,
                                         float* sc, float* n2){
  const float mxn = snorm(mxn2);
  const float t   = tanhf(mxn/xn * art);
  float s  = t/mxn;
  float nn = t*t;                      // sc^2 * mxn2 == t^2
  const float n = snorm(nn);
  if (n > PMAX_){ const float f = PMAX_/n; s *= f; nn *= f*f; }
  *sc = s; *n2 = nn;
}
template<int N>
__device__ __forceinline__ void project_vec(float* v, float* n2io){
  float n2 = *n2io;
  const float n = snorm(n2);
  if (n > PMAX_){
    const float s = PMAX_/n;
#pragma unroll
    for (int i = 0; i < N; i++) v[i] *= s;
    n2 *= s*s;
  }
  *n2io = n2;
}

// ---------------------------------------------------------------------------
// Generic tiled f32 GEMM: C[M,N] = A[M,K] @ B[K,N].
// AMODE: 0 = f32 direct, 1 = f32 row-gathered via idx (A = lut), 2 = bf16 direct.
// ---------------------------------------------------------------------------
template<int AMODE>
__global__ __launch_bounds__(256) void mm_kernel(const void* __restrict__ Aptr,
    const int* __restrict__ idx, const float* __restrict__ Bm,
    float* __restrict__ Cm, int M, int N, int K)
{
  __shared__ __align__(16) float As[8][128];
  __shared__ __align__(16) float Bs[8][132];
  const int tid = threadIdx.x;
  const int n0 = blockIdx.x * 128;
  const int m0 = blockIdx.y * 128;
  const int tr = tid >> 4, tc = tid & 15;
  const int sm = tid & 127, sk = (tid >> 7) * 4;
  const int bk = tid >> 5,  bn = (tid & 31) * 4;
  long arow;
  if constexpr (AMODE == 1) arow = (long)idx[m0 + sm] * K;
  else                      arow = (long)(m0 + sm) * K;
  float acc[8][8];
#pragma unroll
  for (int i = 0; i < 8; i++)
#pragma unroll
    for (int j = 0; j < 8; j++) acc[i][j] = 0.f;

  for (int k0 = 0; k0 < K; k0 += 8){
    float av[4], bv[4];
    if constexpr (AMODE == 2){
      const unsigned short* A = (const unsigned short*)Aptr;
      const ushort4 u = *reinterpret_cast<const ushort4*>(A + arow + k0 + sk);
      av[0]=bf2f(u.x); av[1]=bf2f(u.y); av[2]=bf2f(u.z); av[3]=bf2f(u.w);
    } else {
      const float* A = (const float*)Aptr;
      if (k0 + sk + 3 < K){
        const float4 f = *reinterpret_cast<const float4*>(A + arow + k0 + sk);
        av[0]=f.x; av[1]=f.y; av[2]=f.z; av[3]=f.w;
      } else {
#pragma unroll
        for (int i = 0; i < 4; i++){
          const int kk = k0 + sk + i;
          av[i] = (kk < K) ? A[arow + kk] : 0.f;
        }
      }
    }
    {
      const int kb = k0 + bk;
      if (kb < K){
        const float4 f = *reinterpret_cast<const float4*>(Bm + (long)kb*N + n0 + bn);
        bv[0]=f.x; bv[1]=f.y; bv[2]=f.z; bv[3]=f.w;
      } else { bv[0]=bv[1]=bv[2]=bv[3]=0.f; }
    }
    __syncthreads();
    As[sk+0][sm]=av[0]; As[sk+1][sm]=av[1]; As[sk+2][sm]=av[2]; As[sk+3][sm]=av[3];
    *reinterpret_cast<float4*>(&Bs[bk][bn]) = make_float4(bv[0],bv[1],bv[2],bv[3]);
    __syncthreads();
#pragma unroll
    for (int k = 0; k < 8; k++){
      float a[8], bb[8];
      *(float4*)&a[0]  = *(const float4*)&As[k][tr*8];
      *(float4*)&a[4]  = *(const float4*)&As[k][tr*8+4];
      *(float4*)&bb[0] = *(const float4*)&Bs[k][tc*8];
      *(float4*)&bb[4] = *(const float4*)&Bs[k][tc*8+4];
#pragma unroll
      for (int i = 0; i < 8; i++)
#pragma unroll
        for (int j = 0; j < 8; j++) acc[i][j] += a[i]*bb[j];
    }
  }
#pragma unroll
  for (int i = 0; i < 8; i++){
    const long row = m0 + tr*8 + i;
    *(float4*)(Cm + row*N + n0 + tc*8)     = make_float4(acc[i][0],acc[i][1],acc[i][2],acc[i][3]);
    *(float4*)(Cm + row*N + n0 + tc*8 + 4) = make_float4(acc[i][4],acc[i][5],acc[i][6],acc[i][7]);
  }
}

// ---------------------------------------------------------------------------
// 32x32 LDS-tiled transpose: dst[k*R + j] = src[j*Kc + k]
// ---------------------------------------------------------------------------
__global__ __launch_bounds__(256) void transpose_k(const float* __restrict__ src,
    float* __restrict__ dst, int R, int Kc)
{
  __shared__ float t[32][33];
  const int bx = blockIdx.x * 32;   // k dim
  const int by = blockIdx.y * 32;   // j dim
  const int tx = threadIdx.x & 31, ty = threadIdx.x >> 5;
#pragma unroll
  for (int i = 0; i < 32; i += 8){
    const int j = by + ty + i, k = bx + tx;
    t[ty+i][tx] = (j < R && k < Kc) ? src[(long)j*Kc + k] : 0.f;
  }
  __syncthreads();
#pragma unroll
  for (int i = 0; i < 32; i += 8){
    const int k = bx + ty + i, j = by + tx;
    if (k < Kc && j < R) dst[(long)k*R + j] = t[tx][ty+i];
  }
}

// pack WtHH [2][256][768] f32 -> wpack [2][256][384] u32 (2 bf16 each)
// j2 = gate*128 + jj maps to source cols gate*256 + 2jj, 2jj+1
__global__ __launch_bounds__(256) void pack_whh(const float* __restrict__ WtHH,
    unsigned int* __restrict__ wp)
{
  const int tid = blockIdx.x*256 + threadIdx.x;   // 0 .. 196607
  if (tid < 2*256*384){
    const int j2 = tid % 384, rest = tid / 384;   // rest = dir*256 + k
    const int gate = j2 >> 7, jj = j2 & 127;
    const float* src = WtHH + (long)rest*768 + gate*256 + jj*2;
    wp[tid] = ((unsigned)f2bf(src[1]) << 16) | (unsigned)f2bf(src[0]);
  }
}

// build gather-index arrays: ctxidx[t*256+b]=context[b*128+t]; chidx[t*256+b]=mchars[b*16+t]
__global__ void build_idx(const int* __restrict__ context, const int* __restrict__ mchars,
                          int* __restrict__ ctxidx, int* __restrict__ chidx)
{
  const int tid = blockIdx.x*256 + threadIdx.x;
  if (tid < 32768){
    const int t = tid >> 8, b = tid & 255;
    ctxidx[tid] = context[b*128 + t];
  } else if (tid < 32768 + 4096){
    const int o = tid - 32768;
    const int t = o >> 8, b = o & 255;
    chidx[o] = mchars[b*16 + t];
  }
}

// out[r] = sum_k lut[idx[r]][k]^2   (one wave per row)
__global__ __launch_bounds__(256) void sqn_gather(const float* __restrict__ lut,
    const int* __restrict__ idx, int K, float* __restrict__ outp)
{
  const int wv = threadIdx.x >> 6, lane = threadIdx.x & 63;
  const int r = blockIdx.x*4 + wv;
  const float* row = lut + (long)idx[r]*K;
  float s = 0.f;
  for (int k = lane; k < K; k += 64) s += row[k]*row[k];
  s = wred(s);
  if (lane == 0) outp[r] = s;
}

// mobius_matvec tail transform applied per (row, gate); out bf16 + |out_bf16|^2
__global__ __launch_bounds__(256) void xg_transform(const float* __restrict__ mx,
    const float* __restrict__ xsqn, unsigned short* __restrict__ outp,
    float* __restrict__ n2o, int G)
{
  const int wv = threadIdx.x >> 6, lane = threadIdx.x & 63;
  const int wg = blockIdx.x*4 + wv;
  const int row = wg / G, g = wg - row*G;
  const long base = (long)row*(G*256) + g*256;
  float M[4];
#pragma unroll
  for (int i = 0; i < 4; i++) M[i] = mx[base + i*64 + lane];
  const float mxn2 = wred(sq_part<4>(M));
  float pn2; mt_project<4>(M, mxn2, xsqn[row], &pn2);
  float s = 0.f;
#pragma unroll
  for (int i = 0; i < 4; i++){
    const unsigned short u = f2bf(M[i]);
    outp[base + i*64 + lane] = u;
    const float rv = bf2f(u);
    s += rv*rv;
  }
  s = wred(s);
  if (lane == 0) n2o[wg] = s;
}

// ---------------------------------------------------------------------------
// Mobius GRU, register-resident bf16 weights.
// Grid: 256 blocks = 2 dirs x 128 batch-pairs; block = 512 thr (8 waves).
// Wave w owns k-slice [32w, 32w+32); lane l owns cols j0=4l..4l+3 of each gate.
// Per-lane weights: wr/wh/wz[32] uint2 = 192 VGPRs (static-indexed, unrolled).
// ---------------------------------------------------------------------------
__global__ __launch_bounds__(512,2) void gru_kernel(
    const unsigned short* __restrict__ xg,     // [2][32768][768] bf16
    const float* __restrict__ xgn2,            // [2][32768][3]
    const unsigned int* __restrict__ wpack,    // [2][256][384]
    const float* __restrict__ bias_f, const float* __restrict__ bias_b,
    unsigned short* __restrict__ states_f, unsigned short* __restrict__ states_b)
{
  const int bid = blockIdx.x;            // 0..255
  const int dir = bid >> 7;
  const int bp  = bid & 127;             // batch pair index
  const int tid = threadIdx.x;
  const int w = tid >> 6, lane = tid & 63;
  const int j0 = lane << 2;
  const int bglob0 = bp * 2;
  const unsigned short* xgd = xg + (long)dir * 32768 * 768;
  const float* xnd = xgn2 + (long)dir * 32768 * 3;
  const float* bias = dir ? bias_b : bias_f;
  unsigned short* states = dir ? states_b : states_f;

  // ---- load this wave's weight slice into registers (once) ----
  uint2 wr[32], wh[32], wz[32];
  {
    const unsigned int* wb = wpack + (long)dir*256*384 + (long)(w*32)*384 + lane*2;
#pragma unroll
    for (int k = 0; k < 32; k++){
      wr[k] = *(const uint2*)(wb + (long)k*384);
      wh[k] = *(const uint2*)(wb + (long)k*384 + 128);
      wz[k] = *(const uint2*)(wb + (long)k*384 + 256);
    }
  }

  __shared__ __align__(16) float part[8][2][512];   // 32 KB partials
  __shared__ __align__(16) float hs[2][256];
  __shared__ __align__(16) float rhb[2][256];
  __shared__ __align__(16) float zb[2][256];
  __shared__ float scal[2][2];                      // [b][0]=hn2, [1]=rhn2

  // ---- per-role bias registers ----
  float bg[4] = {0,0,0,0}, bh4[4] = {0,0,0,0};
  float bg2 = 0.f, bh2 = 0.f;
  if (w < 2){
#pragma unroll
    for (int i = 0; i < 4; i++){ bg[i] = bias[512 + j0+i]; bh4[i] = bias[256 + j0+i]; }
    bg2 = sq_part<4>(bg); bh2 = sq_part<4>(bh4);
    wred2(bg2, bh2);
  } else if (w < 4){
#pragma unroll
    for (int i = 0; i < 4; i++) bg[i] = bias[j0+i];
    bg2 = wred(sq_part<4>(bg));
  }

  if (w < 2){
#pragma unroll
    for (int i = 0; i < 4; i++) hs[w][j0+i] = 0.f;
    if (lane == 0){ scal[w][0] = 0.f; scal[w][1] = 0.f; }
  }
  __syncthreads();

  for (int t = 0; t < 128; t++){
    const int tt = dir ? (127 - t) : t;
    // ---- prefetch role inputs (issued before phase-1 FMA wall) ----
    float xgv[4] = {0,0,0,0}, y2g = 0.f, xgh4[4] = {0,0,0,0}, y2h = 0.f;
    if (w < 4){
      const int b = w & 1, isr = w >> 1;
      const long rx = (long)tt*256 + bglob0 + b;
      const ushort4 u = *(const ushort4*)(xgd + rx*768 + (isr ? 0 : 512) + j0);
      xgv[0]=bf2f(u.x); xgv[1]=bf2f(u.y); xgv[2]=bf2f(u.z); xgv[3]=bf2f(u.w);
      y2g = xnd[rx*3 + (isr ? 0 : 2)];
      if (w < 2){
        const ushort4 uh = *(const ushort4*)(xgd + rx*768 + 256 + j0);
        xgh4[0]=bf2f(uh.x); xgh4[1]=bf2f(uh.y); xgh4[2]=bf2f(uh.z); xgh4[3]=bf2f(uh.w);
        y2h = xnd[rx*3 + 1];
      }
    }

    // ---- phase 1: r/z partials from register weights ----
#pragma unroll
    for (int b = 0; b < 2; b++){
      float ar0=0,ar1=0,ar2=0,ar3=0, az0=0,az1=0,az2=0,az3=0;
#pragma unroll
      for (int kc = 0; kc < 4; kc++){
        float hk[8];
        *(float4*)&hk[0] = *(const float4*)&hs[b][w*32 + kc*8];
        *(float4*)&hk[4] = *(const float4*)&hs[b][w*32 + kc*8 + 4];
#pragma unroll
        for (int kk = 0; kk < 8; kk++){
          const int k = kc*8 + kk;
          const float hv = hk[kk];
          ar0 += hv*bflo(wr[k].x); ar1 += hv*bfhi(wr[k].x);
          ar2 += hv*bflo(wr[k].y); ar3 += hv*bfhi(wr[k].y);
          az0 += hv*bflo(wz[k].x); az1 += hv*bfhi(wz[k].x);
          az2 += hv*bflo(wz[k].y); az3 += hv*bfhi(wz[k].y);
        }
      }
      *(float4*)&part[w][b][j0]     = make_float4(ar0,ar1,ar2,ar3);
      *(float4*)&part[w][b][256+j0] = make_float4(az0,az1,az2,az3);
    }
    __syncthreads();   // B1: partials ready

    // ---- gate math: 4 waves, one (b, gate) each ----
    if (w < 4){
      const int b = w & 1, isr = w >> 1;
      const int off = (isr ? 0 : 256) + j0;
      float a[4] = {0,0,0,0};
#pragma unroll
      for (int p = 0; p < 8; p++){
        const float4 v = *(const float4*)&part[p][b][off];
        a[0]+=v.x; a[1]+=v.y; a[2]+=v.z; a[3]+=v.w;
      }
      const float hn2v = scal[b][0];
      const float xn_h = snorm(hn2v), art_h = atanhf(clamp11(xn_h));
      const float p2 = wred(sq_part<4>(a));
      float sc, n2; mt_scale(p2, xn_h, art_h, &sc, &n2);
#pragma unroll
      for (int i = 0; i < 4; i++) a[i] *= sc;
      const float xy = wred(dot_part<4>(a, xgv));
      float m1[4]; madd_vec<4>(a, n2, xgv, y2g, xy, m1);
      float m1n2 = sq_part<4>(m1), xyb = dot_part<4>(m1, bg);
      wred2(m1n2, xyb);
      float m2[4]; madd_vec<4>(m1, m1n2, bg, bg2, xyb, m2);
      const float m2n2 = wred(sq_part<4>(m2));
      const float nn = snorm(m2n2), fg = atanhf(clamp11(nn))/nn;
      float g[4];
#pragma unroll
      for (int i = 0; i < 4; i++) g[i] = 1.f/(1.f + expf(-fg*m2[i]));
      if (isr){
        float h4[4];
        *(float4*)&h4[0] = *(const float4*)&hs[b][j0];
        float rh[4]; float wx2 = 0.f;
#pragma unroll
        for (int i = 0; i < 4; i++){ rh[i] = g[i]*h4[i]; wx2 += rh[i]*rh[i]; }
        wx2 = wred(wx2);
        const float wxn = snorm(wx2);
        const float trh = tanhf(wxn/xn_h * art_h);
        float scrh = trh/wxn, rhn2 = trh*trh;
        const float n = snorm(rhn2);
        if (n > PMAX_){ const float f = PMAX_/n; scrh *= f; rhn2 *= f*f; }
#pragma unroll
        for (int i = 0; i < 4; i++) rh[i] *= scrh;
        *(float4*)&rhb[b][j0] = make_float4(rh[0],rh[1],rh[2],rh[3]);
        if (lane == 0) scal[b][1] = rhn2;
      } else {
        *(float4*)&zb[b][j0] = make_float4(g[0],g[1],g[2],g[3]);
      }
    }
    __syncthreads();   // B2: rh, z ready

    // ---- phase 2: h-gate partials from rh ----
#pragma unroll
    for (int b = 0; b < 2; b++){
      float a0=0,a1=0,a2=0,a3=0;
#pragma unroll
      for (int kc = 0; kc < 4; kc++){
        float rk[8];
        *(float4*)&rk[0] = *(const float4*)&rhb[b][w*32 + kc*8];
        *(float4*)&rk[4] = *(const float4*)&rhb[b][w*32 + kc*8 + 4];
#pragma unroll
        for (int kk = 0; kk < 8; kk++){
          const int k = kc*8 + kk;
          const float hv = rk[kk];
          a0 += hv*bflo(wh[k].x); a1 += hv*bfhi(wh[k].x);
          a2 += hv*bflo(wh[k].y); a3 += hv*bfhi(wh[k].y);
        }
      }
      *(float4*)&part[w][b][j0] = make_float4(a0,a1,a2,a3);
    }
    __syncthreads();   // B3: h-partials ready

    // ---- h-update: 2 waves, one batch row each ----
    if (w < 2){
      const int b = w;
      float ah[4] = {0,0,0,0};
#pragma unroll
      for (int p = 0; p < 8; p++){
        const float4 v = *(const float4*)&part[p][b][j0];
        ah[0]+=v.x; ah[1]+=v.y; ah[2]+=v.z; ah[3]+=v.w;
      }
      const float hn2v  = scal[b][0];
      const float rhn2v = scal[b][1];
      const float rxn = snorm(rhn2v), artr = atanhf(clamp11(rxn));
      float mx2 = sq_part<4>(ah), xyraw = dot_part<4>(ah, xgh4);
      wred2(mx2, xyraw);
      float sch, pn2; mt_scale(mx2, rxn, artr, &sch, &pn2);
#pragma unroll
      for (int i = 0; i < 4; i++) ah[i] *= sch;
      const float xy = xyraw * sch;
      float m1[4]; madd_vec<4>(ah, pn2, xgh4, y2h, xy, m1);
      float m1n2 = sq_part<4>(m1), xyb = dot_part<4>(m1, bh4);
      wred2(m1n2, xyb);
      float ht[4]; madd_vec<4>(m1, m1n2, bh4, bh2, xyb, ht);
      float h4[4];
      *(float4*)&h4[0] = *(const float4*)&hs[b][j0];
      float htn2 = sq_part<4>(ht);
      float nh[4];
#pragma unroll
      for (int i = 0; i < 4; i++) nh[i] = -h4[i];
      float xyd = dot_part<4>(nh, ht);
      wred2(htn2, xyd);
      float dl[4]; madd_vec<4>(nh, hn2v, ht, htn2, xyd, dl);
      float z4[4];
      *(float4*)&z4[0] = *(const float4*)&zb[b][j0];
      float pw[4]; float dln2 = 0.f, wz2 = 0.f, xyhr = 0.f;
#pragma unroll
      for (int i = 0; i < 4; i++){
        dln2 += dl[i]*dl[i];
        pw[i] = z4[i]*dl[i];
        wz2  += pw[i]*pw[i];
        xyhr += h4[i]*pw[i];
      }
      wred3(dln2, wz2, xyhr);
      float pwn2, scpw;
      {
        const float dn   = snorm(dln2);
        const float artd = atanhf(clamp11(dn));
        const float wzn  = snorm(wz2);
        const float tpw  = tanhf(wzn/dn * artd);
        scpw = tpw/wzn; pwn2 = tpw*tpw;
        const float n = snorm(pwn2);
        if (n > PMAX_){ const float f = PMAX_/n; scpw *= f; pwn2 *= f*f; }
      }
#pragma unroll
      for (int i = 0; i < 4; i++) pw[i] *= scpw;
      const float xyh = xyhr * scpw;
      float hnew[4]; madd_vec<4>(h4, hn2v, pw, pwn2, xyh, hnew);
      *(float4*)&hs[b][j0] = make_float4(hnew[0],hnew[1],hnew[2],hnew[3]);
      const float hn2n = wred(sq_part<4>(hnew));
      if (lane == 0) scal[b][0] = hn2n;
      const int bglob = bglob0 + b;
      unsigned short* srow = states + ((long)bglob*128 + tt)*256 + j0;
      ushort4 su; su.x=f2bf(hnew[0]); su.y=f2bf(hnew[1]); su.z=f2bf(hnew[2]); su.w=f2bf(hnew[3]);
      *(ushort4*)srow = su;
    }
    __syncthreads();   // B4: hs/scal ready for next step
  }
}

// ---------------------------------------------------------------------------
// Char Mobius-RNN: h = project(madd(madd(matvec(h, W), xg), b)), 16 steps.
// ---------------------------------------------------------------------------
__global__ __launch_bounds__(256) void char_rnn(
    const unsigned short* __restrict__ xgc,   // [16*256][256] rows t*256+b, bf16
    const float* __restrict__ Wc,             // [256][256] row-major (k,j)
    const float* __restrict__ cb,             // [256]
    float* __restrict__ cstates)              // [256*16][256] rows b*16+t
{
  const int wv = threadIdx.x >> 6, lane = threadIdx.x & 63;
  const int b = blockIdx.x*4 + wv;
  const int j0 = lane << 2;
  __shared__ __align__(16) float hs[4][256];
  float h[4] = {0.f,0.f,0.f,0.f};
  float hn2 = 0.f;
#pragma unroll
  for (int i = 0; i < 4; i++) hs[wv][j0+i] = 0.f;
  float cbv[4];
#pragma unroll
  for (int i = 0; i < 4; i++) cbv[i] = cb[j0+i];
  const float cb2 = wred(sq_part<4>(cbv));
  for (int t = 0; t < 16; t++){
    __syncthreads();
    const unsigned short* xr = xgc + ((long)t*256 + b)*256;
    float xgv[4];
    { const ushort4 u = *(const ushort4*)(xr + j0); xgv[0]=bf2f(u.x); xgv[1]=bf2f(u.y); xgv[2]=bf2f(u.z); xgv[3]=bf2f(u.w); }
    float a[4]={0.f,0.f,0.f,0.f};
#pragma unroll 2
    for (int k0 = 0; k0 < 256; k0 += 4){
      const float4 hk = *(const float4*)&hs[wv][k0];
#pragma unroll
      for (int kk = 0; kk < 4; kk++){
        const float hv = (&hk.x)[kk];
        const float4 w4 = *(const float4*)(Wc + (long)(k0+kk)*256 + j0);
        a[0] += hv*w4.x; a[1] += hv*w4.y; a[2] += hv*w4.z; a[3] += hv*w4.w;
      }
    }
    const float mxn2 = wred(sq_part<4>(a));
    float pn2; mt_project<4>(a, mxn2, hn2, &pn2);
    const float y2 = wred(sq_part<4>(xgv));
    const float xy = wred(dot_part<4>(a, xgv));
    float m1[4]; madd_vec<4>(a, pn2, xgv, y2, xy, m1);
    const float m1n2 = wred(sq_part<4>(m1));
    const float xyb  = wred(dot_part<4>(m1, cbv));
    float m2[4]; madd_vec<4>(m1, m1n2, cbv, cb2, xyb, m2);
    float m2n2 = wred(sq_part<4>(m2));
    project_vec<4>(m2, &m2n2);
#pragma unroll
    for (int i = 0; i < 4; i++) h[i] = m2[i];
    hn2 = m2n2;
    *(float4*)&hs[wv][j0] = make_float4(h[0],h[1],h[2],h[3]);
    *(float4*)(cstates + ((long)b*16 + t)*256 + j0) = make_float4(h[0],h[1],h[2],h[3]);
  }
}

// ---------------------------------------------------------------------------
// cc concat: ctx = project(madd(madd(mt(mxa,|sf|), mt(mxb,|sb|)), cc_bias)), bf16 out
// ---------------------------------------------------------------------------
__global__ __launch_bounds__(256) void cc_rowwise(const unsigned short* __restrict__ sf,
    const unsigned short* __restrict__ sb, const float* __restrict__ mxa,
    const float* __restrict__ mxb, const float* __restrict__ ccb,
    unsigned short* __restrict__ ctxo, int rowoff)
{
  const int wv = threadIdx.x >> 6, lane = threadIdx.x & 63;
  const int rloc = blockIdx.x*4 + wv;
  const long r = rowoff + rloc;
  float s = 0.f;
#pragma unroll
  for (int i = 0; i < 4; i++){ const float v = bf2f(sf[r*256 + i*64+lane]); s += v*v; }
  const float sfn2 = wred(s);
  s = 0.f;
#pragma unroll
  for (int i = 0; i < 4; i++){ const float v = bf2f(sb[r*256 + i*64+lane]); s += v*v; }
  const float sbn2 = wred(s);
  float A[8], Bv[8];
#pragma unroll
  for (int i = 0; i < 8; i++){ A[i]  = mxa[(long)rloc*512 + i*64+lane];
                               Bv[i] = mxb[(long)rloc*512 + i*64+lane]; }
  float pan2, pbn2;
  { const float n2 = wred(sq_part<8>(A));  mt_project<8>(A,  n2, sfn2, &pan2); }
  { const float n2 = wred(sq_part<8>(Bv)); mt_project<8>(Bv, n2, sbn2, &pbn2); }
  const float xy = wred(dot_part<8>(A, Bv));
  float M1[8]; madd_vec<8>(A, pan2, Bv, pbn2, xy, M1);
  const float m1n2 = wred(sq_part<8>(M1));
  float Cb[8];
#pragma unroll
  for (int i = 0; i < 8; i++) Cb[i] = ccb[i*64+lane];
  const float cb2 = wred(sq_part<8>(Cb));
  const float xyb = wred(dot_part<8>(M1, Cb));
  float M2[8]; madd_vec<8>(M1, m1n2, Cb, cb2, xyb, M2);
  float m2n2 = wred(sq_part<8>(M2));
  project_vec<8>(M2, &m2n2);
#pragma unroll
  for (int i = 0; i < 8; i++) ctxo[r*512 + i*64+lane] = f2bf(M2[i]);
}

// attn_emb = madd(ctx(bf16), pe) -> f32 + sqn
__global__ __launch_bounds__(256) void attn_add(const unsigned short* __restrict__ ctxv,
    const int* __restrict__ pos, const float* __restrict__ pet,
    float* __restrict__ oemb, float* __restrict__ osqn)
{
  const int wv = threadIdx.x >> 6, lane = threadIdx.x & 63;
  const long r = blockIdx.x*4 + wv;
  float X[8];
#pragma unroll
  for (int i = 0; i < 8; i++) X[i] = bf2f(ctxv[r*512 + i*64+lane]);
  const float x2 = wred(sq_part<8>(X));
  const int p = pos[r];
  float Y[8];
#pragma unroll
  for (int i = 0; i < 8; i++) Y[i] = pet[(long)p*512 + i*64+lane];
  const float y2 = wred(sq_part<8>(Y));
  const float xy = wred(dot_part<8>(X, Y));
  float O[8]; madd_vec<8>(X, x2, Y, y2, xy, O);
#pragma unroll
  for (int i = 0; i < 8; i++) oemb[r*512 + i*64+lane] = O[i];
  const float on2 = wred(sq_part<8>(O));
  if (lane == 0) osqn[r] = on2;
}

// mention variant: pos_idx = mentions>0 ? i+1 : 0 ; values f32
__global__ __launch_bounds__(256) void attn_add_m(const float* __restrict__ mvv,
    const int* __restrict__ mentions, const float* __restrict__ pet,
    float* __restrict__ oemb, float* __restrict__ osqn)
{
  const int wv = threadIdx.x >> 6, lane = threadIdx.x & 63;
  const long r = blockIdx.x*4 + wv;
  float X[8];
#pragma unroll
  for (int i = 0; i < 8; i++) X[i] = mvv[r*512 + i*64+lane];
  const float x2 = wred(sq_part<8>(X));
  const int men = mentions[r];
  const int p = (men > 0) ? (int)(r & 7) + 1 : 0;
  float Y[8];
#pragma unroll
  for (int i = 0; i < 8; i++) Y[i] = pet[(long)p*512 + i*64+lane];
  const float y2 = wred(sq_part<8>(Y));
  const float xy = wred(dot_part<8>(X, Y));
  float O[8]; madd_vec<8>(X, x2, Y, y2, xy, O);
#pragma unroll
  for (int i = 0; i < 8; i++) oemb[r*512 + i*64+lane] = O[i];
  const float on2 = wred(sq_part<8>(O));
  if (lane == 0) osqn[r] = on2;
}

// q = project(madd(mt(mxq,|emb|), bq)); k likewise; d = 2*artanh(|madd(-q,k)|)
__global__ __launch_bounds__(256) void qk_pdist(const float* __restrict__ mxq,
    const float* __restrict__ mxk, const float* __restrict__ sqn,
    const float* __restrict__ bq, const float* __restrict__ bk,
    float* __restrict__ dout)
{
  const int wv = threadIdx.x >> 6, lane = threadIdx.x & 63;
  const int r = blockIdx.x*4 + wv;
  const float xn2 = sqn[r];
  float Q[8];
#pragma unroll
  for (int i = 0; i < 8; i++) Q[i] = mxq[(long)r*512 + i*64+lane];
  { const float n2 = wred(sq_part<8>(Q)); float pn2; mt_project<8>(Q, n2, xn2, &pn2);
    float Bq[8];
#pragma unroll
    for (int i = 0; i < 8; i++) Bq[i] = bq[i*64+lane];
    const float b2 = wred(sq_part<8>(Bq));
    const float xy = wred(dot_part<8>(Q, Bq));
    float O[8]; madd_vec<8>(Q, pn2, Bq, b2, xy, O);
#pragma unroll
    for (int i = 0; i < 8; i++) Q[i] = O[i];
  }
  float qn2 = wred(sq_part<8>(Q));
  project_vec<8>(Q, &qn2);
  float Kv[8];
#pragma unroll
  for (int i = 0; i < 8; i++) Kv[i] = mxk[(long)r*512 + i*64+lane];
  { const float n2 = wred(sq_part<8>(Kv)); float pn2; mt_project<8>(Kv, n2, xn2, &pn2);
    float Bk[8];
#pragma unroll
    for (int i = 0; i < 8; i++) Bk[i] = bk[i*64+lane];
    const float b2 = wred(sq_part<8>(Bk));
    const float xy = wred(dot_part<8>(Kv, Bk));
    float O[8]; madd_vec<8>(Kv, pn2, Bk, b2, xy, O);
#pragma unroll
    for (int i = 0; i < 8; i++) Kv[i] = O[i];
  }
  float kn2 = wred(sq_part<8>(Kv));
  project_vec<8>(Kv, &kn2);
  float NQ[8];
#pragma unroll
  for (int i = 0; i < 8; i++) NQ[i] = -Q[i];
  const float xy = wred(dot_part<8>(NQ, Kv));
  float Z[8]; madd_vec<8>(NQ, qn2, Kv, kn2, xy, Z);
  const float zn2 = wred(sq_part<8>(Z));
  const float d = 2.f * atanhf(clamp11(snorm(zn2)));
  if (lane == 0) dout[r] = d;
}

__global__ __launch_bounds__(256) void softmax128(const float* __restrict__ d,
    const float* __restrict__ beta, float* __restrict__ w)
{
  const int wv = threadIdx.x >> 6, lane = threadIdx.x & 63;
  const int b = blockIdx.x*4 + wv;
  const float bt = beta[0];
  const float x0 = -bt * d[b*128 + lane];
  const float x1 = -bt * d[b*128 + 64 + lane];
  const float m = wredmax(fmaxf(x0, x1));
  const float e0 = expf(x0 - m), e1 = expf(x1 - m);
  const float s = wred(e0 + e1);
  w[b*128 + lane]      = e0 / s;
  w[b*128 + 64 + lane] = e1 / s;
}

__global__ void softmax8(const float* __restrict__ d, const float* __restrict__ beta,
                         float* __restrict__ w)
{
  const int b = threadIdx.x;   // 256
  const float bt = beta[0];
  float x[8]; float m = -1e30f;
#pragma unroll
  for (int i = 0; i < 8; i++){ x[i] = -bt * d[b*8+i]; m = fmaxf(m, x[i]); }
  float s = 0.f;
#pragma unroll
  for (int i = 0; i < 8; i++){ x[i] = expf(x[i]-m); s += x[i]; }
#pragma unroll
  for (int i = 0; i < 8; i++) w[b*8+i] = x[i] / s;
}

// weighted gyromidpoint via Klein model; one wave per batch row
template<int NPL, bool BF16V, bool HASW>
__global__ __launch_bounds__(256) void midpoint_kernel(const void* __restrict__ vals,
    const float* __restrict__ wts, float* __restrict__ outp, int Lseq)
{
  const int wv = threadIdx.x >> 6, lane = threadIdx.x & 63;
  const int b = blockIdx.x*4 + wv;
  const int D = NPL*64;
  float num[NPL];
#pragma unroll
  for (int i = 0; i < NPL; i++) num[i] = 0.f;
  float den = 0.f;
  for (int l = 0; l < Lseq; l++){
    const long base = ((long)b*Lseq + l)*D;
    float v[NPL]; float s = 0.f;
#pragma unroll
    for (int i = 0; i < NPL; i++){
      v[i] = BF16V ? bf2f(((const unsigned short*)vals)[base + i*64+lane])
                   : ((const float*)vals)[base + i*64+lane];
      s += v[i]*v[i];
    }
    const float v2 = wred(s);
    const float f = 2.f/(1.f + v2);          // klein = f*v
    const float kl2 = v2*f*f;
    const float gamma = 1.f/sqrtf(fmaxf(1.f - kl2, EPS_));
    const float wgt = HASW ? wts[b*Lseq + l] : 1.f;
    const float wg = wgt*gamma;
#pragma unroll
    for (int i = 0; i < NPL; i++) num[i] += wg*(f*v[i]);
    den += wg;
  }
  den = fmaxf(den, EPS_);
  float x[NPL]; float s = 0.f;
#pragma unroll
  for (int i = 0; i < NPL; i++){ x[i] = num[i]/den; s += x[i]*x[i]; }
  const float k2 = wred(s);
  const float inv = 1.f/(1.f + sqrtf(fmaxf(1.f - k2, EPS_)));
#pragma unroll
  for (int i = 0; i < NPL; i++) outp[(long)b*D + i*64+lane] = x[i]*inv;
}

// mention w2s mobius_linear with tanh nonlinearity
__global__ __launch_bounds__(256) void mv_rowwise(const float* __restrict__ mx,
    const float* __restrict__ xsqn, const float* __restrict__ bb, float* __restrict__ outp)
{
  const int wv = threadIdx.x >> 6, lane = threadIdx.x & 63;
  const long r = blockIdx.x*4 + wv;
  float M[8];
#pragma unroll
  for (int i = 0; i < 8; i++) M[i] = mx[r*512 + i*64+lane];
  { const float n2 = wred(sq_part<8>(M)); float pn2; mt_project<8>(M, n2, xsqn[r], &pn2);
    float Bv[8];
#pragma unroll
    for (int i = 0; i < 8; i++) Bv[i] = bb[i*64+lane];
    const float b2 = wred(sq_part<8>(Bv));
    const float xy = wred(dot_part<8>(M, Bv));
    float O[8]; madd_vec<8>(M, pn2, Bv, b2, xy, O);
#pragma unroll
    for (int i = 0; i < 8; i++) M[i] = O[i];
  }
  float on2 = wred(sq_part<8>(M));
  project_vec<8>(M, &on2);
  // nonlin: project(expmap0(tanh(logmap0(M))))
  { const float n = snorm(on2);
    const float fac = atanhf(clamp11(n))/n;
#pragma unroll
    for (int i = 0; i < 8; i++) M[i] = tanhf(fac*M[i]); }
  const float un2 = wred(sq_part<8>(M));
  { const float n = snorm(un2);
    const float fac = tanhf(n)/n;
    float en2 = fac*fac*un2;
#pragma unroll
    for (int i = 0; i < 8; i++) M[i] *= fac;
    project_vec<8>(M, &en2); }
#pragma unroll
  for (int i = 0; i < 8; i++) outp[r*512 + i*64+lane] = M[i];
}

// joint = project(madd(madd(madd(mt(jm),mt(jc)),mt(jch)),fc_bias))
__global__ __launch_bounds__(256) void final_rowwise(const float* __restrict__ jm,
    const float* __restrict__ jc, const float* __restrict__ jch,
    const float* __restrict__ mvec, const float* __restrict__ cvec,
    const float* __restrict__ chvec, const float* __restrict__ fcb,
    float* __restrict__ joint)
{
  const int wv = threadIdx.x >> 6, lane = threadIdx.x & 63;
  const long b = blockIdx.x*4 + wv;
  float s;
  s = 0.f; for (int i = 0; i < 8; i++){ const float v = mvec[b*512 + i*64+lane]; s += v*v; }
  const float mn2 = wred(s);
  s = 0.f; for (int i = 0; i < 8; i++){ const float v = cvec[b*512 + i*64+lane]; s += v*v; }
  const float cn2 = wred(s);
  s = 0.f; for (int i = 0; i < 4; i++){ const float v = chvec[b*256 + i*64+lane]; s += v*v; }
  const float chn2 = wred(s);
  float A[20];
#pragma unroll
  for (int i = 0; i < 20; i++) A[i] = jm[b*1280 + i*64+lane];
  float an2;
  { const float n2 = wred(sq_part<20>(A)); mt_project<20>(A, n2, mn2, &an2); }
  float T[20];
#pragma unroll
  for (int i = 0; i < 20; i++) T[i] = jc[b*1280 + i*64+lane];
  float tn2;
  { const float n2 = wred(sq_part<20>(T)); mt_project<20>(T, n2, cn2, &tn2); }
  { const float xy = wred(dot_part<20>(A, T));
    float O[20]; madd_vec<20>(A, an2, T, tn2, xy, O);
#pragma unroll
    for (int i = 0; i < 20; i++) A[i] = O[i];
    an2 = wred(sq_part<20>(A)); }
#pragma unroll
  for (int i = 0; i < 20; i++) T[i] = jch[b*1280 + i*64+lane];
  { const float n2 = wred(sq_part<20>(T)); mt_project<20>(T, n2, chn2, &tn2); }
  { const float xy = wred(dot_part<20>(A, T));
    float O[20]; madd_vec<20>(A, an2, T, tn2, xy, O);
#pragma unroll
    for (int i = 0; i < 20; i++) A[i] = O[i];
    an2 = wred(sq_part<20>(A)); }
#pragma unroll
  for (int i = 0; i < 20; i++) T[i] = fcb[i*64+lane];
  tn2 = wred(sq_part<20>(T));
  { const float xy = wred(dot_part<20>(A, T));
    float O[20]; madd_vec<20>(A, an2, T, tn2, xy, O);
#pragma unroll
    for (int i = 0; i < 20; i++) A[i] = O[i];
    an2 = wred(sq_part<20>(A)); }
  project_vec<20>(A, &an2);
#pragma unroll
  for (int i = 0; i < 20; i++) joint[b*1280 + i*64+lane] = A[i];
}

// hyperbolic MLR head: out[b,c] = 2*a_n*asinh(2<z,a> / (clip(1-|z|^2)*a_n))
__global__ __launch_bounds__(256) void mlr_kernel(const float* __restrict__ joint,
    const float* __restrict__ P, const float* __restrict__ A, float* __restrict__ outp)
{
  const int wv = threadIdx.x >> 6, lane = threadIdx.x & 63;
  const int pair = blockIdx.x*4 + wv;
  const long b = pair >> 7, c = pair & 127;
  float Pv[20], J[20];
#pragma unroll
  for (int i = 0; i < 20; i++){
    Pv[i] = -P[c*1280 + i*64+lane];
    J[i]  = joint[b*1280 + i*64+lane];
  }
  const float p2 = wred(sq_part<20>(Pv));
  const float j2 = wred(sq_part<20>(J));
  const float xy = wred(dot_part<20>(Pv, J));
  float Z[20]; madd_vec<20>(Pv, p2, J, j2, xy, Z);
  float sza = 0.f, sz2 = 0.f, sa2 = 0.f;
#pragma unroll
  for (int i = 0; i < 20; i++){
    const float a = A[c*1280 + i*64+lane];
    sza += Z[i]*a; sz2 += Z[i]*Z[i]; sa2 += a*a;
  }
  float za = sza, z2 = sz2, a2 = sa2;
  wred3(za, z2, a2);
  const float an = sqrtf(fmaxf(a2, EPS_));
  const float v = 2.f*za / (fmaxf(1.f - z2, EPS_)*an);
  if (lane == 0) outp[pair] = 2.f*an*asinhf(v);
}

// ---------------------------------------------------------------------------
extern "C" void kernel_launch(void* const* d_in, const int* in_sizes, int n_in,
                              void* d_out, int out_size, void* d_ws, size_t ws_size,
                              hipStream_t stream)
{
  (void)in_sizes; (void)n_in; (void)out_size;
  const int*   context   = (const int*)  d_in[0];
  const int*   ctx_position=(const int*) d_in[1];
  const int*   mentions  = (const int*)  d_in[2];
  const int*   mchars    = (const int*)  d_in[3];
  const float* word_lut  = (const float*)d_in[4];
  const float* char_lut  = (const float*)d_in[5];
  const float* gf_Wih    = (const float*)d_in[6];
  const float* gf_Whh    = (const float*)d_in[7];
  const float* gf_b      = (const float*)d_in[8];
  const float* gb_Wih    = (const float*)d_in[9];
  const float* gb_Whh    = (const float*)d_in[10];
  const float* gb_b      = (const float*)d_in[11];
  const float* w2s_W     = (const float*)d_in[12];
  const float* w2s_b     = (const float*)d_in[13];
  const float* men_pos   = (const float*)d_in[14];
  const float* men_Wq    = (const float*)d_in[15];
  const float* men_bq    = (const float*)d_in[16];
  const float* men_Wk    = (const float*)d_in[17];
  const float* men_bk    = (const float*)d_in[18];
  const float* men_beta  = (const float*)d_in[19];
  const float* char_W    = (const float*)d_in[20];
  const float* char_U    = (const float*)d_in[21];
  const float* char_b    = (const float*)d_in[22];
  const float* cc_Wa     = (const float*)d_in[23];
  const float* cc_Wb     = (const float*)d_in[24];
  const float* cc_bias   = (const float*)d_in[25];
  const float* ctx_pos_t = (const float*)d_in[26];
  const float* ctx_Wq    = (const float*)d_in[27];
  const float* ctx_bq    = (const float*)d_in[28];
  const float* ctx_Wk    = (const float*)d_in[29];
  const float* ctx_bk    = (const float*)d_in[30];
  const float* ctx_beta  = (const float*)d_in[31];
  const float* fc_Wm     = (const float*)d_in[32];
  const float* fc_Wc     = (const float*)d_in[33];
  const float* fc_Wch    = (const float*)d_in[34];
  const float* fc_bias   = (const float*)d_in[35];
  const float* mlr_p     = (const float*)d_in[36];
  const float* mlr_a     = (const float*)d_in[37];
  float* out = (float*)d_out;

  // ---- workspace bump allocator ----
  char* wsb = (char*)d_ws;
  size_t off = 0;
  auto alloc = [&](size_t bytes) -> void* {
    void* p = wsb + off;
    off += (bytes + 255) & ~(size_t)255;
    return p;
  };
  float* WtIH = (float*)alloc(2UL*300*768*4);     // [dir][k][j] = Wih[j][k]
  float* WtHH = (float*)alloc(2UL*256*768*4);     // [dir][k][j] = Whh[j][k]
  unsigned int* wpackHH = (unsigned int*)alloc(2UL*256*384*4);  // bf16-pair packed
  int*   ctxidx = (int*)alloc(32768UL*4);
  int*   chidx  = (int*)alloc(4096UL*4);
  float* xsqn   = (float*)alloc(32768UL*4);
  float* msqn   = (float*)alloc(2048UL*4);
  float* chsqn  = (float*)alloc(4096UL*4);
  unsigned short* xg = (unsigned short*)alloc(2UL*32768*768*2);   // bf16
  float* xgn2 = (float*)alloc(2UL*32768*3*4);     // per-(row,gate) |xg|^2
  float* chn2d = (float*)alloc(4096UL*4);         // char-path n2 (unused)
  unsigned short* states_f = (unsigned short*)alloc(32768UL*256*2);
  unsigned short* states_b = (unsigned short*)alloc(32768UL*256*2);
  unsigned short* ctxv = (unsigned short*)alloc(32768UL*512*2);
  float* attn_sqn = (float*)alloc(32768UL*4);
  float* dctx = (float*)alloc(32768UL*4);
  float* wctx = (float*)alloc(32768UL*4);
  float* ctx_vec = (float*)alloc(256UL*512*4);
  float* mxbuf = (float*)alloc(2UL*8192*512*4);   // shared chunk scratch
  float* mv = (float*)alloc(2048UL*512*4);
  float* attn_embm = (float*)alloc(2048UL*512*4);
  float* amsqn = (float*)alloc(2048UL*4);
  float* dm = (float*)alloc(2048UL*4);
  float* wm = (float*)alloc(2048UL*4);
  float* mention_vec = (float*)alloc(256UL*512*4);
  unsigned short* xgc = (unsigned short*)alloc(4096UL*256*2);
  float* char_states = (float*)alloc(4096UL*256*4);
  float* char_vec = (float*)alloc(256UL*256*4);
  float* joint = (float*)alloc(256UL*1280*4);
  if (off > ws_size) return;                       // workspace too small: bail cleanly
  float* attn_embc = (float*)xg;                   // overlay: xg dead after GRU
  float* mxh0 = mxbuf;
  float* mxh1 = mxbuf + 8192UL*512;

  // ---- weight transposes + bf16 pack ----
  transpose_k<<<dim3(10,24),256,0,stream>>>(gf_Wih, WtIH,            768, 300);
  transpose_k<<<dim3(10,24),256,0,stream>>>(gb_Wih, WtIH + 300*768,  768, 300);
  transpose_k<<<dim3(8,24), 256,0,stream>>>(gf_Whh, WtHH,            768, 256);
  transpose_k<<<dim3(8,24), 256,0,stream>>>(gb_Whh, WtHH + 256*768,  768, 256);
  pack_whh<<<768,256,0,stream>>>(WtHH, wpackHH);

  // ---- gather indices + input sqn ----
  build_idx<<<144,256,0,stream>>>(context, mchars, ctxidx, chidx);
  sqn_gather<<<8192,256,0,stream>>>(word_lut, ctxidx, 300, xsqn);
  sqn_gather<<<512, 256,0,stream>>>(word_lut, mentions, 300, msqn);
  sqn_gather<<<1024,256,0,stream>>>(char_lut, chidx, 256, chsqn);

  // ---- GRU input precompute: xg[dir] = mobius_matvec(emb, Wih^T), bf16 ----
  for (int d2 = 0; d2 < 2; d2++){
    const float* wih_t = WtIH + (size_t)d2*300*768;
    for (int c = 0; c < 4; c++){
      mm_kernel<1><<<dim3(6,64),256,0,stream>>>(word_lut, ctxidx + c*8192, wih_t,
                                                mxbuf, 8192, 768, 300);
      xg_transform<<<6144,256,0,stream>>>(mxbuf, xsqn + c*8192,
          xg + ((size_t)d2*32768 + (size_t)c*8192)*768,
          xgn2 + ((size_t)d2*32768 + (size_t)c*8192)*3, 3);
    }
  }

  // ---- bidirectional Mobius GRU (register-resident weights) ----
  gru_kernel<<<256,512,0,stream>>>(xg, xgn2, wpackHH, gf_b, gb_b, states_f, states_b);

  // ---- mobius concat of directions -> ctx (bf16) ----
  for (int c = 0; c < 4; c++){
    mm_kernel<2><<<dim3(4,64),256,0,stream>>>(states_f + (size_t)c*8192*256, nullptr,
                                              cc_Wa, mxh0, 8192, 512, 256);
    mm_kernel<2><<<dim3(4,64),256,0,stream>>>(states_b + (size_t)c*8192*256, nullptr,
                                              cc_Wb, mxh1, 8192, 512, 256);
    cc_rowwise<<<2048,256,0,stream>>>(states_f, states_b, mxh0, mxh1, cc_bias,
                                      ctxv, c*8192);
  }

  // ---- context distance attention ----
  attn_add<<<8192,256,0,stream>>>(ctxv, ctx_position, ctx_pos_t, attn_embc, attn_sqn);
  for (int c = 0; c < 4; c++){
    mm_kernel<0><<<dim3(4,64),256,0,stream>>>(attn_embc + (size_t)c*8192*512, nullptr,
                                              ctx_Wq, mxh0, 8192, 512, 512);
    mm_kernel<0><<<dim3(4,64),256,0,stream>>>(attn_embc + (size_t)c*8192*512, nullptr,
                                              ctx_Wk, mxh1, 8192, 512, 512);
    qk_pdist<<<2048,256,0,stream>>>(mxh0, mxh1, attn_sqn + c*8192, ctx_bq, ctx_bk,
                                    dctx + c*8192);
  }
  softmax128<<<64,256,0,stream>>>(dctx, ctx_beta, wctx);
  midpoint_kernel<8,true,true><<<64,256,0,stream>>>(ctxv, wctx, ctx_vec, 128);

  // ---- mention encoder ----
  mm_kernel<1><<<dim3(4,16),256,0,stream>>>(word_lut, mentions, w2s_W, mxh0, 2048, 512, 300);
  mv_rowwise<<<512,256,0,stream>>>(mxh0, msqn, w2s_b, mv);
  attn_add_m<<<512,256,0,stream>>>(mv, mentions, men_pos, attn_embm, amsqn);
  mm_kernel<0><<<dim3(4,16),256,0,stream>>>(attn_embm, nullptr, men_Wq, mxh0, 2048, 512, 512);
  mm_kernel<0><<<dim3(4,16),256,0,stream>>>(attn_embm, nullptr, men_Wk, mxh1, 2048, 512, 512);
  qk_pdist<<<512,256,0,stream>>>(mxh0, mxh1, amsqn, men_bq, men_bk, dm);
  softmax8<<<1,256,0,stream>>>(dm, men_beta, wm);
  midpoint_kernel<8,false,true><<<64,256,0,stream>>>(mv, wm, mention_vec, 8);

  // ---- char encoder ----
  mm_kernel<1><<<dim3(2,32),256,0,stream>>>(char_lut, chidx, char_U, mxh0, 4096, 256, 256);
  xg_transform<<<1024,256,0,stream>>>(mxh0, chsqn, xgc, chn2d, 1);
  char_rnn<<<64,256,0,stream>>>(xgc, char_W, char_b, char_states);
  midpoint_kernel<4,false,false><<<64,256,0,stream>>>(char_states, nullptr, char_vec, 16);

  // ---- full mobius concat + MLR ----
  float* jm = mxh0;
  float* jc = mxh0 + 256UL*1280;
  float* jch = mxh0 + 2UL*256*1280;
  mm_kernel<0><<<dim3(10,2),256,0,stream>>>(mention_vec, nullptr, fc_Wm, jm, 256, 1280, 512);
  mm_kernel<0><<<dim3(10,2),256,0,stream>>>(ctx_vec,     nullptr, fc_Wc, jc, 256, 1280, 512);
  mm_kernel<0><<<dim3(10,2),256,0,stream>>>(char_vec,    nullptr, fc_Wch, jch, 256, 1280, 256);
  final_rowwise<<<64,256,0,stream>>>(jm, jc, jch, mention_vec, ctx_vec, char_vec,
                                     fc_bias, joint);
  mlr_kernel<<<8192,256,0,stream>>>(joint, mlr_p, mlr_a, out);
}

// Round 4
// 5823.466 us; speedup vs baseline: 1.6126x; 1.6126x over previous
//
#include <hip/hip_runtime.h>
#include <cstddef>
#include <cstdint>

// ---------------------------------------------------------------------------
// Hyperbolic (Poincare-ball) entity-typing forward pass, MI355X / gfx950.
// Round 4: GRU = round-1 math skeleton + weights streamed L2->LDS via
// global_load_lds (zero-VGPR async), j-per-lane FMA (no LDS duplication),
// LDS partial redistribution, per-row chains verbatim. f32 weights (exact).
// ---------------------------------------------------------------------------

#define EPS_  1e-15f
#define PMAX_ 0.99999f    // 1 - 1e-5

__device__ __forceinline__ float wred(float v){
#pragma unroll
  for (int o = 32; o; o >>= 1) v += __shfl_xor(v, o, 64);
  return v;
}
__device__ __forceinline__ void wred2(float& a, float& b){
#pragma unroll
  for (int o = 32; o; o >>= 1){ a += __shfl_xor(a, o, 64); b += __shfl_xor(b, o, 64); }
}
__device__ __forceinline__ void wred3(float& a, float& b, float& c){
#pragma unroll
  for (int o = 32; o; o >>= 1){
    a += __shfl_xor(a, o, 64); b += __shfl_xor(b, o, 64); c += __shfl_xor(c, o, 64);
  }
}
__device__ __forceinline__ void wred4(float& a, float& b, float& c, float& d){
#pragma unroll
  for (int o = 32; o; o >>= 1){
    a += __shfl_xor(a, o, 64); b += __shfl_xor(b, o, 64);
    c += __shfl_xor(c, o, 64); d += __shfl_xor(d, o, 64);
  }
}
__device__ __forceinline__ float wredmax(float v){
#pragma unroll
  for (int o = 32; o; o >>= 1) v = fmaxf(v, __shfl_xor(v, o, 64));
  return v;
}
__device__ __forceinline__ float snorm(float s){ return sqrtf(fmaxf(s, EPS_)); }
__device__ __forceinline__ float clamp11(float x){
  return fminf(fmaxf(x, -1.f + 1e-7f), 1.f - 1e-7f);
}
__device__ __forceinline__ float bf2f(unsigned short u){
  union { unsigned int i; float f; } v; v.i = ((unsigned int)u) << 16; return v.f;
}
__device__ __forceinline__ unsigned short f2bf(float f){
  union { float f; unsigned int i; } v; v.f = f;
  unsigned int x = v.i;
  x += 0x7fffu + ((x >> 16) & 1u);   // RNE
  return (unsigned short)(x >> 16);
}

template<int N>
__device__ __forceinline__ float sq_part(const float* a){
  float s = 0.f;
#pragma unroll
  for (int i = 0; i < N; i++) s += a[i]*a[i];
  return s;
}
template<int N>
__device__ __forceinline__ float dot_part(const float* a, const float* b){
  float s = 0.f;
#pragma unroll
  for (int i = 0; i < N; i++) s += a[i]*b[i];
  return s;
}
template<int N>
__device__ __forceinline__ void madd_vec(const float* x, float x2, const float* y,
                                         float y2, float xy, float* o){
  const float c1 = 1.f + 2.f*xy + y2;
  const float c2 = 1.f - x2;
  const float inv = 1.f / fmaxf(1.f + 2.f*xy + x2*y2, EPS_);
#pragma unroll
  for (int i = 0; i < N; i++) o[i] = (c1*x[i] + c2*y[i]) * inv;
}
template<int N>
__device__ __forceinline__ void mt_project(float* v, float mxn2, float xn2, float* n2out){
  const float xn  = snorm(xn2);
  const float mxn = snorm(mxn2);
  const float t   = tanhf(mxn/xn * atanhf(clamp11(xn)));
  float sc = t/mxn;
  float n2 = sc*sc*mxn2;
  const float n = snorm(n2);
  if (n > PMAX_){ const float s = PMAX_/n; sc *= s; n2 *= s*s; }
#pragma unroll
  for (int i = 0; i < N; i++) v[i] *= sc;
  *n2out = n2;
}
__device__ __forceinline__ void mt_scale(float mxn2, float xn, float art,
                                         float* sc, float* n2){
  const float mxn = snorm(mxn2);
  const float t   = tanhf(mxn/xn * art);
  float s  = t/mxn;
  float nn = t*t;
  const float n = snorm(nn);
  if (n > PMAX_){ const float f = PMAX_/n; s *= f; nn *= f*f; }
  *sc = s; *n2 = nn;
}
template<int N>
__device__ __forceinline__ void project_vec(float* v, float* n2io){
  float n2 = *n2io;
  const float n = snorm(n2);
  if (n > PMAX_){
    const float s = PMAX_/n;
#pragma unroll
    for (int i = 0; i < N; i++) v[i] *= s;
    n2 *= s*s;
  }
  *n2io = n2;
}

// async 16B global->LDS: linear wave-uniform-base + lane*16
__device__ __forceinline__ void gll16(const void* g, void* l){
  __builtin_amdgcn_global_load_lds(
      (const __attribute__((address_space(1))) void*)g,
      (__attribute__((address_space(3))) void*)l, 16, 0, 0);
}
// stage 64KB (256 thr x 16 x 16B), linear layout
__device__ __forceinline__ void stage64k(const float* __restrict__ gsrc,
                                         float* lbase, int w, int lane){
#pragma unroll
  for (int i = 0; i < 16; i++){
    const float* g = gsrc + ((size_t)(i*4 + w)*64 + lane)*4;
    char* l = (char*)lbase + (size_t)((i*4 + w)*64)*16;
    gll16(g, l);
  }
}

// ---------------------------------------------------------------------------
// Generic tiled f32 GEMM: C[M,N] = A[M,K] @ B[K,N].
// AMODE: 0 = f32 direct, 1 = f32 row-gathered via idx (A = lut), 2 = bf16 direct.
// ---------------------------------------------------------------------------
template<int AMODE>
__global__ __launch_bounds__(256) void mm_kernel(const void* __restrict__ Aptr,
    const int* __restrict__ idx, const float* __restrict__ Bm,
    float* __restrict__ Cm, int M, int N, int K)
{
  __shared__ __align__(16) float As[8][128];
  __shared__ __align__(16) float Bs[8][132];
  const int tid = threadIdx.x;
  const int n0 = blockIdx.x * 128;
  const int m0 = blockIdx.y * 128;
  const int tr = tid >> 4, tc = tid & 15;
  const int sm = tid & 127, sk = (tid >> 7) * 4;
  const int bk = tid >> 5,  bn = (tid & 31) * 4;
  long arow;
  if constexpr (AMODE == 1) arow = (long)idx[m0 + sm] * K;
  else                      arow = (long)(m0 + sm) * K;
  float acc[8][8];
#pragma unroll
  for (int i = 0; i < 8; i++)
#pragma unroll
    for (int j = 0; j < 8; j++) acc[i][j] = 0.f;

  for (int k0 = 0; k0 < K; k0 += 8){
    float av[4], bv[4];
    if constexpr (AMODE == 2){
      const unsigned short* A = (const unsigned short*)Aptr;
      const ushort4 u = *reinterpret_cast<const ushort4*>(A + arow + k0 + sk);
      av[0]=bf2f(u.x); av[1]=bf2f(u.y); av[2]=bf2f(u.z); av[3]=bf2f(u.w);
    } else {
      const float* A = (const float*)Aptr;
      if (k0 + sk + 3 < K){
        const float4 f = *reinterpret_cast<const float4*>(A + arow + k0 + sk);
        av[0]=f.x; av[1]=f.y; av[2]=f.z; av[3]=f.w;
      } else {
#pragma unroll
        for (int i = 0; i < 4; i++){
          const int kk = k0 + sk + i;
          av[i] = (kk < K) ? A[arow + kk] : 0.f;
        }
      }
    }
    {
      const int kb = k0 + bk;
      if (kb < K){
        const float4 f = *reinterpret_cast<const float4*>(Bm + (long)kb*N + n0 + bn);
        bv[0]=f.x; bv[1]=f.y; bv[2]=f.z; bv[3]=f.w;
      } else { bv[0]=bv[1]=bv[2]=bv[3]=0.f; }
    }
    __syncthreads();
    As[sk+0][sm]=av[0]; As[sk+1][sm]=av[1]; As[sk+2][sm]=av[2]; As[sk+3][sm]=av[3];
    *reinterpret_cast<float4*>(&Bs[bk][bn]) = make_float4(bv[0],bv[1],bv[2],bv[3]);
    __syncthreads();
#pragma unroll
    for (int k = 0; k < 8; k++){
      float a[8], bb[8];
      *(float4*)&a[0]  = *(const float4*)&As[k][tr*8];
      *(float4*)&a[4]  = *(const float4*)&As[k][tr*8+4];
      *(float4*)&bb[0] = *(const float4*)&Bs[k][tc*8];
      *(float4*)&bb[4] = *(const float4*)&Bs[k][tc*8+4];
#pragma unroll
      for (int i = 0; i < 8; i++)
#pragma unroll
        for (int j = 0; j < 8; j++) acc[i][j] += a[i]*bb[j];
    }
  }
#pragma unroll
  for (int i = 0; i < 8; i++){
    const long row = m0 + tr*8 + i;
    *(float4*)(Cm + row*N + n0 + tc*8)     = make_float4(acc[i][0],acc[i][1],acc[i][2],acc[i][3]);
    *(float4*)(Cm + row*N + n0 + tc*8 + 4) = make_float4(acc[i][4],acc[i][5],acc[i][6],acc[i][7]);
  }
}

// ---------------------------------------------------------------------------
// 32x32 LDS-tiled transpose: dst[k*R + j] = src[j*Kc + k]
// ---------------------------------------------------------------------------
__global__ __launch_bounds__(256) void transpose_k(const float* __restrict__ src,
    float* __restrict__ dst, int R, int Kc)
{
  __shared__ float t[32][33];
  const int bx = blockIdx.x * 32;   // k dim
  const int by = blockIdx.y * 32;   // j dim
  const int tx = threadIdx.x & 31, ty = threadIdx.x >> 5;
#pragma unroll
  for (int i = 0; i < 32; i += 8){
    const int j = by + ty + i, k = bx + tx;
    t[ty+i][tx] = (j < R && k < Kc) ? src[(long)j*Kc + k] : 0.f;
  }
  __syncthreads();
#pragma unroll
  for (int i = 0; i < 32; i += 8){
    const int k = bx + ty + i, j = by + tx;
    if (k < Kc && j < R) dst[(long)k*R + j] = t[tx][ty+i];
  }
}

// split WtHH [2][256][768] (r|h|z) -> Wrz [2][256][512] (r|z), Wh [2][256][256]
__global__ void split_whh(const float* __restrict__ WtHH,
                          float* __restrict__ Wrz, float* __restrict__ Wh)
{
  const int tid = blockIdx.x*256 + threadIdx.x;    // 0 .. 393215
  if (tid < 2*256*768){
    const int col = tid % 768, rk = tid / 768;     // rk = dir*256 + k
    const float v = WtHH[tid];
    if (col < 256)       Wrz[(long)rk*512 + col] = v;
    else if (col < 512)  Wh [(long)rk*256 + (col - 256)] = v;
    else                 Wrz[(long)rk*512 + 256 + (col - 512)] = v;
  }
}

// build gather-index arrays: ctxidx[t*256+b]=context[b*128+t]; chidx[t*256+b]=mchars[b*16+t]
__global__ void build_idx(const int* __restrict__ context, const int* __restrict__ mchars,
                          int* __restrict__ ctxidx, int* __restrict__ chidx)
{
  const int tid = blockIdx.x*256 + threadIdx.x;
  if (tid < 32768){
    const int t = tid >> 8, b = tid & 255;
    ctxidx[tid] = context[b*128 + t];
  } else if (tid < 32768 + 4096){
    const int o = tid - 32768;
    const int t = o >> 8, b = o & 255;
    chidx[o] = mchars[b*16 + t];
  }
}

// out[r] = sum_k lut[idx[r]][k]^2   (one wave per row)
__global__ __launch_bounds__(256) void sqn_gather(const float* __restrict__ lut,
    const int* __restrict__ idx, int K, float* __restrict__ outp)
{
  const int wv = threadIdx.x >> 6, lane = threadIdx.x & 63;
  const int r = blockIdx.x*4 + wv;
  const float* row = lut + (long)idx[r]*K;
  float s = 0.f;
  for (int k = lane; k < K; k += 64) s += row[k]*row[k];
  s = wred(s);
  if (lane == 0) outp[r] = s;
}

// mobius_matvec tail transform applied per (row, gate); out bf16 + |out_bf16|^2
__global__ __launch_bounds__(256) void xg_transform(const float* __restrict__ mx,
    const float* __restrict__ xsqn, unsigned short* __restrict__ outp,
    float* __restrict__ n2o, int G)
{
  const int wv = threadIdx.x >> 6, lane = threadIdx.x & 63;
  const int wg = blockIdx.x*4 + wv;
  const int row = wg / G, g = wg - row*G;
  const long base = (long)row*(G*256) + g*256;
  float M[4];
#pragma unroll
  for (int i = 0; i < 4; i++) M[i] = mx[base + i*64 + lane];
  const float mxn2 = wred(sq_part<4>(M));
  float pn2; mt_project<4>(M, mxn2, xsqn[row], &pn2);
  float s = 0.f;
#pragma unroll
  for (int i = 0; i < 4; i++){
    const unsigned short u = f2bf(M[i]);
    outp[base + i*64 + lane] = u;
    const float rv = bf2f(u);
    s += rv*rv;
  }
  s = wred(s);
  if (lane == 0) n2o[wg] = s;
}

// ---------------------------------------------------------------------------
// Mobius GRU v4: 128 blocks x 256 thr; 4 rows/block (row = wave for chains).
// FMA phases: j-per-lane over streamed-LDS f32 weights (global_load_lds dbuf).
// Phase1 wave roles: gate g=w>>1 (0:r,1:z), j-half jh=w&1, 2 j per lane.
// Phase2 wave roles: k-subrange kh=w>>1, j-half jh=w&1.
// LDS: wbuf 2x64KB | hs 4K | pr 4K | pz 4K | rhb 4K = 144KB (dynamic).
// ---------------------------------------------------------------------------
#define GRU_LDS_BYTES 147456

__global__ __launch_bounds__(256,1) void gru_kernel(
    const unsigned short* __restrict__ xg,     // [2][32768][768] bf16
    const float* __restrict__ xgn2,            // [2][32768][3]
    const float* __restrict__ Wrz,             // [2][256][512]
    const float* __restrict__ Wh,              // [2][256][256]
    const float* __restrict__ bias_f, const float* __restrict__ bias_b,
    unsigned short* __restrict__ states_f, unsigned short* __restrict__ states_b)
{
  extern __shared__ __align__(16) char smem[];
  float* wbuf = (float*)smem;                    // 2 x 16384 f32
  float* hs   = (float*)(smem + 131072);         // [4][256]
  float* pr   = (float*)(smem + 135168);         // [4][256]
  float* pz   = (float*)(smem + 139264);         // [4][256]
  float* rhb  = (float*)(smem + 143360);         // [4][256]

  const int bid = blockIdx.x;
  const int dir = bid >> 6;
  const int b0  = (bid & 63) * 4;
  const int tid = threadIdx.x;
  const int w = tid >> 6, lane = tid & 63;
  const int j0 = lane << 2;

  const unsigned short* xgd = xg + (long)dir*32768*768;
  const float* xnd = xgn2 + (long)dir*32768*3;
  const float* wrz_d = Wrz + (long)dir*256*512;
  const float* wh_d  = Wh  + (long)dir*256*256;
  const float* bias = dir ? bias_b : bias_f;
  unsigned short* states = dir ? states_b : states_f;

  // FMA-role constants
  const int g   = w >> 1;            // phase1 gate: 0=r, 1=z
  const int jh  = w & 1;
  const int jj  = jh*128 + lane*2;   // gate-local j pair
  const int col1 = g*256 + jj;       // column inside Wrz row
  const int kh  = w >> 1;            // phase2 k-subrange

  // row-role (this wave owns batch row brow)
  const int brow = b0 + w;
  float br4[4], bh4[4], bz4[4];
#pragma unroll
  for (int i = 0; i < 4; i++){
    br4[i] = bias[      j0+i];
    bh4[i] = bias[256 + j0+i];
    bz4[i] = bias[512 + j0+i];
  }
  float br2 = sq_part<4>(br4), bh2 = sq_part<4>(bh4), bz2 = sq_part<4>(bz4);
  wred3(br2, bh2, bz2);

  float h[4] = {0.f,0.f,0.f,0.f};
  float hn2 = 0.f;
  *(float4*)&hs[w*256 + j0] = make_float4(0.f,0.f,0.f,0.f);
  __syncthreads();

  int cb = 0;
  stage64k(wrz_d, wbuf, w, lane);    // Wrz chunk 0 -> buf 0

  for (int t = 0; t < 128; t++){
    const int tt = dir ? (127 - t) : t;
    const long rx = (long)tt*256 + brow;
    const unsigned short* xr = xgd + rx*768;
    float xgr[4], xgh[4], xgz[4];
    { const ushort4 u = *(const ushort4*)(xr + j0);       xgr[0]=bf2f(u.x); xgr[1]=bf2f(u.y); xgr[2]=bf2f(u.z); xgr[3]=bf2f(u.w); }
    { const ushort4 u = *(const ushort4*)(xr + 256 + j0); xgh[0]=bf2f(u.x); xgh[1]=bf2f(u.y); xgh[2]=bf2f(u.z); xgh[3]=bf2f(u.w); }
    { const ushort4 u = *(const ushort4*)(xr + 512 + j0); xgz[0]=bf2f(u.x); xgz[1]=bf2f(u.y); xgz[2]=bf2f(u.z); xgz[3]=bf2f(u.w); }
    const float y2r = xnd[rx*3 + 0];
    const float y2h = xnd[rx*3 + 1];
    const float y2z = xnd[rx*3 + 2];

    // ================= phase 1: r/z matvec partials =================
    float a00=0.f,a01=0.f,a10=0.f,a11=0.f,a20=0.f,a21=0.f,a30=0.f,a31=0.f;
#pragma unroll 1
    for (int c = 0; c < 8; c++){
      __syncthreads();                          // stage(c) landed, buf free
      if (c < 7) stage64k(wrz_d + (size_t)(c+1)*32*512, wbuf + (cb^1)*16384, w, lane);
      const float* wb = wbuf + cb*16384;        // [32][512]
      const int kb = c*32;
      float4 hb0, hb1, hb2, hb3;
#pragma unroll
      for (int kk = 0; kk < 32; kk++){
        if ((kk & 3) == 0){
          hb0 = *(const float4*)&hs[0*256 + kb + kk];
          hb1 = *(const float4*)&hs[1*256 + kb + kk];
          hb2 = *(const float4*)&hs[2*256 + kb + kk];
          hb3 = *(const float4*)&hs[3*256 + kb + kk];
        }
        const float2 wv = *(const float2*)&wb[kk*512 + col1];
        const int q = kk & 3;
        const float h0 = (&hb0.x)[q], h1 = (&hb1.x)[q], h2 = (&hb2.x)[q], h3 = (&hb3.x)[q];
        a00 += h0*wv.x; a01 += h0*wv.y;
        a10 += h1*wv.x; a11 += h1*wv.y;
        a20 += h2*wv.x; a21 += h2*wv.y;
        a30 += h3*wv.x; a31 += h3*wv.y;
      }
      cb ^= 1;
    }
    {
      float* dst = g ? pz : pr;
      *(float2*)&dst[0*256 + jj] = make_float2(a00, a01);
      *(float2*)&dst[1*256 + jj] = make_float2(a10, a11);
      *(float2*)&dst[2*256 + jj] = make_float2(a20, a21);
      *(float2*)&dst[3*256 + jj] = make_float2(a30, a31);
    }
    __syncthreads();                            // B_a: partials visible
    stage64k(wh_d, wbuf + (cb^1)*16384, w, lane);   // prefetch Wh chunk0
    cb ^= 1;

    // ================= gate chain (row = w) =================
    float az[4], ar[4];
    *(float4*)az = *(const float4*)&pz[w*256 + j0];
    *(float4*)ar = *(const float4*)&pr[w*256 + j0];
    const float xn_h  = snorm(hn2);
    const float art_h = atanhf(clamp11(xn_h));
    float pz2 = sq_part<4>(az), pr2 = sq_part<4>(ar);
    wred2(pz2, pr2);
    float scz, n2z; mt_scale(pz2, xn_h, art_h, &scz, &n2z);
    float scr, n2r; mt_scale(pr2, xn_h, art_h, &scr, &n2r);
    float pzv[4], prv[4];
#pragma unroll
    for (int i = 0; i < 4; i++){ pzv[i] = az[i]*scz; prv[i] = ar[i]*scr; }
    float xyz = dot_part<4>(pzv, xgz), xyr = dot_part<4>(prv, xgr);
    wred2(xyz, xyr);
    float m1z[4]; madd_vec<4>(pzv, n2z, xgz, y2z, xyz, m1z);
    float m1r[4]; madd_vec<4>(prv, n2r, xgr, y2r, xyr, m1r);
    float m1n2z = sq_part<4>(m1z), xybz = dot_part<4>(m1z, bz4);
    float m1n2r = sq_part<4>(m1r), xybr = dot_part<4>(m1r, br4);
    wred4(m1n2z, xybz, m1n2r, xybr);
    float m2z[4]; madd_vec<4>(m1z, m1n2z, bz4, bz2, xybz, m2z);
    float m2r[4]; madd_vec<4>(m1r, m1n2r, br4, br2, xybr, m2r);
    float m2n2z = sq_part<4>(m2z), m2n2r = sq_part<4>(m2r);
    wred2(m2n2z, m2n2r);
    float z[4], r[4];
    {
      const float nz = snorm(m2n2z), fz = atanhf(clamp11(nz))/nz;
      const float nr = snorm(m2n2r), fr = atanhf(clamp11(nr))/nr;
#pragma unroll
      for (int i = 0; i < 4; i++){
        z[i] = 1.f/(1.f + expf(-fz*m2z[i]));
        r[i] = 1.f/(1.f + expf(-fr*m2r[i]));
      }
    }
    float rh[4]; float wx2 = 0.f;
#pragma unroll
    for (int i = 0; i < 4; i++){ rh[i] = r[i]*h[i]; wx2 += rh[i]*rh[i]; }
    wx2 = wred(wx2);
    float rhn2, scrh;
    {
      const float wxn = snorm(wx2);
      const float trh = tanhf(wxn/xn_h * art_h);
      scrh = trh/wxn; rhn2 = trh*trh;
      const float n = snorm(rhn2);
      if (n > PMAX_){ const float f = PMAX_/n; scrh *= f; rhn2 *= f*f; }
    }
#pragma unroll
    for (int i = 0; i < 4; i++) rh[i] *= scrh;
    *(float4*)&rhb[w*256 + j0] = make_float4(rh[0],rh[1],rh[2],rh[3]);

    // ================= phase 2: h-gate matvec partials =================
    float c00=0.f,c01=0.f,c10=0.f,c11=0.f,c20=0.f,c21=0.f,c30=0.f,c31=0.f;
#pragma unroll 1
    for (int c = 0; c < 4; c++){
      __syncthreads();                          // B_b (c==0): rhb ready + Wh chunk landed
      if (c < 3) stage64k(wh_d + (size_t)(c+1)*64*256, wbuf + (cb^1)*16384, w, lane);
      const float* wb = wbuf + cb*16384;        // [64][256]
      const int kb = c*64 + kh*32;
      float4 hb0, hb1, hb2, hb3;
#pragma unroll
      for (int kk = 0; kk < 32; kk++){
        if ((kk & 3) == 0){
          hb0 = *(const float4*)&rhb[0*256 + kb + kk];
          hb1 = *(const float4*)&rhb[1*256 + kb + kk];
          hb2 = *(const float4*)&rhb[2*256 + kb + kk];
          hb3 = *(const float4*)&rhb[3*256 + kb + kk];
        }
        const float2 wv = *(const float2*)&wb[(kh*32 + kk)*256 + jj];
        const int q = kk & 3;
        const float h0 = (&hb0.x)[q], h1 = (&hb1.x)[q], h2 = (&hb2.x)[q], h3 = (&hb3.x)[q];
        c00 += h0*wv.x; c01 += h0*wv.y;
        c10 += h1*wv.x; c11 += h1*wv.y;
        c20 += h2*wv.x; c21 += h2*wv.y;
        c30 += h3*wv.x; c31 += h3*wv.y;
      }
      cb ^= 1;
    }
    {
      float* dst = kh ? pz : pr;                // reuse as phase2 partials
      *(float2*)&dst[0*256 + jj] = make_float2(c00, c01);
      *(float2*)&dst[1*256 + jj] = make_float2(c10, c11);
      *(float2*)&dst[2*256 + jj] = make_float2(c20, c21);
      *(float2*)&dst[3*256 + jj] = make_float2(c30, c31);
    }
    __syncthreads();                            // B_c
    if (t < 127){                               // prefetch next step's Wrz chunk0
      stage64k(wrz_d, wbuf + (cb^1)*16384, w, lane);
      cb ^= 1;
    }

    // ================= h-update chain (row = w) =================
    float ah[4];
    {
      float4 p0 = *(const float4*)&pr[w*256 + j0];
      float4 p1 = *(const float4*)&pz[w*256 + j0];
      ah[0] = p0.x + p1.x; ah[1] = p0.y + p1.y; ah[2] = p0.z + p1.z; ah[3] = p0.w + p1.w;
    }
    const float rxn  = snorm(rhn2);
    const float artr = atanhf(clamp11(rxn));
    float mx2 = sq_part<4>(ah), xyraw = dot_part<4>(ah, xgh);
    wred2(mx2, xyraw);
    float sch, pn2; mt_scale(mx2, rxn, artr, &sch, &pn2);
#pragma unroll
    for (int i = 0; i < 4; i++) ah[i] *= sch;
    const float xy = xyraw * sch;
    float m1[4]; madd_vec<4>(ah, pn2, xgh, y2h, xy, m1);
    float m1n2 = sq_part<4>(m1), xyb = dot_part<4>(m1, bh4);
    wred2(m1n2, xyb);
    float ht[4]; madd_vec<4>(m1, m1n2, bh4, bh2, xyb, ht);
    float htn2 = sq_part<4>(ht);
    float nh[4];
#pragma unroll
    for (int i = 0; i < 4; i++) nh[i] = -h[i];
    float xyd = dot_part<4>(nh, ht);
    wred2(htn2, xyd);
    float dl[4]; madd_vec<4>(nh, hn2, ht, htn2, xyd, dl);
    float pw[4]; float dln2 = 0.f, wz2 = 0.f, xyhr = 0.f;
#pragma unroll
    for (int i = 0; i < 4; i++){
      dln2 += dl[i]*dl[i];
      pw[i] = z[i]*dl[i];
      wz2  += pw[i]*pw[i];
      xyhr += h[i]*pw[i];
    }
    wred3(dln2, wz2, xyhr);
    float pwn2, scpw;
    {
      const float dn   = snorm(dln2);
      const float artd = atanhf(clamp11(dn));
      const float wzn  = snorm(wz2);
      const float tpw  = tanhf(wzn/dn * artd);
      scpw = tpw/wzn; pwn2 = tpw*tpw;
      const float n = snorm(pwn2);
      if (n > PMAX_){ const float f = PMAX_/n; scpw *= f; pwn2 *= f*f; }
    }
#pragma unroll
    for (int i = 0; i < 4; i++) pw[i] *= scpw;
    const float xyh = xyhr * scpw;
    float hnew[4]; madd_vec<4>(h, hn2, pw, pwn2, xyh, hnew);
#pragma unroll
    for (int i = 0; i < 4; i++) h[i] = hnew[i];
    hn2 = wred(sq_part<4>(h));
    *(float4*)&hs[w*256 + j0] = make_float4(h[0],h[1],h[2],h[3]);
    unsigned short* srow = states + ((long)brow*128 + tt)*256 + j0;
    ushort4 su; su.x=f2bf(h[0]); su.y=f2bf(h[1]); su.z=f2bf(h[2]); su.w=f2bf(h[3]);
    *(ushort4*)srow = su;
    __syncthreads();                            // B_d: hs ready for next step
  }
}

// ---------------------------------------------------------------------------
// Char Mobius-RNN: h = project(madd(madd(matvec(h, W), xg), b)), 16 steps.
// ---------------------------------------------------------------------------
__global__ __launch_bounds__(256) void char_rnn(
    const unsigned short* __restrict__ xgc,
    const float* __restrict__ Wc,
    const float* __restrict__ cb,
    float* __restrict__ cstates)
{
  const int wv = threadIdx.x >> 6, lane = threadIdx.x & 63;
  const int b = blockIdx.x*4 + wv;
  const int j0 = lane << 2;
  __shared__ __align__(16) float hs[4][256];
  float h[4] = {0.f,0.f,0.f,0.f};
  float hn2 = 0.f;
#pragma unroll
  for (int i = 0; i < 4; i++) hs[wv][j0+i] = 0.f;
  float cbv[4];
#pragma unroll
  for (int i = 0; i < 4; i++) cbv[i] = cb[j0+i];
  const float cb2 = wred(sq_part<4>(cbv));
  for (int t = 0; t < 16; t++){
    __syncthreads();
    const unsigned short* xr = xgc + ((long)t*256 + b)*256;
    float xgv[4];
    { const ushort4 u = *(const ushort4*)(xr + j0); xgv[0]=bf2f(u.x); xgv[1]=bf2f(u.y); xgv[2]=bf2f(u.z); xgv[3]=bf2f(u.w); }
    float a[4]={0.f,0.f,0.f,0.f};
#pragma unroll 2
    for (int k0 = 0; k0 < 256; k0 += 4){
      const float4 hk = *(const float4*)&hs[wv][k0];
#pragma unroll
      for (int kk = 0; kk < 4; kk++){
        const float hv = (&hk.x)[kk];
        const float4 w4 = *(const float4*)(Wc + (long)(k0+kk)*256 + j0);
        a[0] += hv*w4.x; a[1] += hv*w4.y; a[2] += hv*w4.z; a[3] += hv*w4.w;
      }
    }
    const float mxn2 = wred(sq_part<4>(a));
    float pn2; mt_project<4>(a, mxn2, hn2, &pn2);
    const float y2 = wred(sq_part<4>(xgv));
    const float xy = wred(dot_part<4>(a, xgv));
    float m1[4]; madd_vec<4>(a, pn2, xgv, y2, xy, m1);
    const float m1n2 = wred(sq_part<4>(m1));
    const float xyb  = wred(dot_part<4>(m1, cbv));
    float m2[4]; madd_vec<4>(m1, m1n2, cbv, cb2, xyb, m2);
    float m2n2 = wred(sq_part<4>(m2));
    project_vec<4>(m2, &m2n2);
#pragma unroll
    for (int i = 0; i < 4; i++) h[i] = m2[i];
    hn2 = m2n2;
    *(float4*)&hs[wv][j0] = make_float4(h[0],h[1],h[2],h[3]);
    *(float4*)(cstates + ((long)b*16 + t)*256 + j0) = make_float4(h[0],h[1],h[2],h[3]);
  }
}

// ---------------------------------------------------------------------------
// cc concat: ctx = project(madd(madd(mt(mxa,|sf|), mt(mxb,|sb|)), cc_bias)), bf16 out
// ---------------------------------------------------------------------------
__global__ __launch_bounds__(256) void cc_rowwise(const unsigned short* __restrict__ sf,
    const unsigned short* __restrict__ sb, const float* __restrict__ mxa,
    const float* __restrict__ mxb, const float* __restrict__ ccb,
    unsigned short* __restrict__ ctxo, int rowoff)
{
  const int wv = threadIdx.x >> 6, lane = threadIdx.x & 63;
  const int rloc = blockIdx.x*4 + wv;
  const long r = rowoff + rloc;
  float s = 0.f;
#pragma unroll
  for (int i = 0; i < 4; i++){ const float v = bf2f(sf[r*256 + i*64+lane]); s += v*v; }
  const float sfn2 = wred(s);
  s = 0.f;
#pragma unroll
  for (int i = 0; i < 4; i++){ const float v = bf2f(sb[r*256 + i*64+lane]); s += v*v; }
  const float sbn2 = wred(s);
  float A[8], Bv[8];
#pragma unroll
  for (int i = 0; i < 8; i++){ A[i]  = mxa[(long)rloc*512 + i*64+lane];
                               Bv[i] = mxb[(long)rloc*512 + i*64+lane]; }
  float pan2, pbn2;
  { const float n2 = wred(sq_part<8>(A));  mt_project<8>(A,  n2, sfn2, &pan2); }
  { const float n2 = wred(sq_part<8>(Bv)); mt_project<8>(Bv, n2, sbn2, &pbn2); }
  const float xy = wred(dot_part<8>(A, Bv));
  float M1[8]; madd_vec<8>(A, pan2, Bv, pbn2, xy, M1);
  const float m1n2 = wred(sq_part<8>(M1));
  float Cb[8];
#pragma unroll
  for (int i = 0; i < 8; i++) Cb[i] = ccb[i*64+lane];
  const float cb2 = wred(sq_part<8>(Cb));
  const float xyb = wred(dot_part<8>(M1, Cb));
  float M2[8]; madd_vec<8>(M1, m1n2, Cb, cb2, xyb, M2);
  float m2n2 = wred(sq_part<8>(M2));
  project_vec<8>(M2, &m2n2);
#pragma unroll
  for (int i = 0; i < 8; i++) ctxo[r*512 + i*64+lane] = f2bf(M2[i]);
}

// attn_emb = madd(ctx(bf16), pe) -> f32 + sqn
__global__ __launch_bounds__(256) void attn_add(const unsigned short* __restrict__ ctxv,
    const int* __restrict__ pos, const float* __restrict__ pet,
    float* __restrict__ oemb, float* __restrict__ osqn)
{
  const int wv = threadIdx.x >> 6, lane = threadIdx.x & 63;
  const long r = blockIdx.x*4 + wv;
  float X[8];
#pragma unroll
  for (int i = 0; i < 8; i++) X[i] = bf2f(ctxv[r*512 + i*64+lane]);
  const float x2 = wred(sq_part<8>(X));
  const int p = pos[r];
  float Y[8];
#pragma unroll
  for (int i = 0; i < 8; i++) Y[i] = pet[(long)p*512 + i*64+lane];
  const float y2 = wred(sq_part<8>(Y));
  const float xy = wred(dot_part<8>(X, Y));
  float O[8]; madd_vec<8>(X, x2, Y, y2, xy, O);
#pragma unroll
  for (int i = 0; i < 8; i++) oemb[r*512 + i*64+lane] = O[i];
  const float on2 = wred(sq_part<8>(O));
  if (lane == 0) osqn[r] = on2;
}

// mention variant: pos_idx = mentions>0 ? i+1 : 0 ; values f32
__global__ __launch_bounds__(256) void attn_add_m(const float* __restrict__ mvv,
    const int* __restrict__ mentions, const float* __restrict__ pet,
    float* __restrict__ oemb, float* __restrict__ osqn)
{
  const int wv = threadIdx.x >> 6, lane = threadIdx.x & 63;
  const long r = blockIdx.x*4 + wv;
  float X[8];
#pragma unroll
  for (int i = 0; i < 8; i++) X[i] = mvv[r*512 + i*64+lane];
  const float x2 = wred(sq_part<8>(X));
  const int men = mentions[r];
  const int p = (men > 0) ? (int)(r & 7) + 1 : 0;
  float Y[8];
#pragma unroll
  for (int i = 0; i < 8; i++) Y[i] = pet[(long)p*512 + i*64+lane];
  const float y2 = wred(sq_part<8>(Y));
  const float xy = wred(dot_part<8>(X, Y));
  float O[8]; madd_vec<8>(X, x2, Y, y2, xy, O);
#pragma unroll
  for (int i = 0; i < 8; i++) oemb[r*512 + i*64+lane] = O[i];
  const float on2 = wred(sq_part<8>(O));
  if (lane == 0) osqn[r] = on2;
}

// q = project(madd(mt(mxq,|emb|), bq)); k likewise; d = 2*artanh(|madd(-q,k)|)
__global__ __launch_bounds__(256) void qk_pdist(const float* __restrict__ mxq,
    const float* __restrict__ mxk, const float* __restrict__ sqn,
    const float* __restrict__ bq, const float* __restrict__ bk,
    float* __restrict__ dout)
{
  const int wv = threadIdx.x >> 6, lane = threadIdx.x & 63;
  const int r = blockIdx.x*4 + wv;
  const float xn2 = sqn[r];
  float Q[8];
#pragma unroll
  for (int i = 0; i < 8; i++) Q[i] = mxq[(long)r*512 + i*64+lane];
  { const float n2 = wred(sq_part<8>(Q)); float pn2; mt_project<8>(Q, n2, xn2, &pn2);
    float Bq[8];
#pragma unroll
    for (int i = 0; i < 8; i++) Bq[i] = bq[i*64+lane];
    const float b2 = wred(sq_part<8>(Bq));
    const float xy = wred(dot_part<8>(Q, Bq));
    float O[8]; madd_vec<8>(Q, pn2, Bq, b2, xy, O);
#pragma unroll
    for (int i = 0; i < 8; i++) Q[i] = O[i];
  }
  float qn2 = wred(sq_part<8>(Q));
  project_vec<8>(Q, &qn2);
  float Kv[8];
#pragma unroll
  for (int i = 0; i < 8; i++) Kv[i] = mxk[(long)r*512 + i*64+lane];
  { const float n2 = wred(sq_part<8>(Kv)); float pn2; mt_project<8>(Kv, n2, xn2, &pn2);
    float Bk[8];
#pragma unroll
    for (int i = 0; i < 8; i++) Bk[i] = bk[i*64+lane];
    const float b2 = wred(sq_part<8>(Bk));
    const float xy = wred(dot_part<8>(Kv, Bk));
    float O[8]; madd_vec<8>(Kv, pn2, Bk, b2, xy, O);
#pragma unroll
    for (int i = 0; i < 8; i++) Kv[i] = O[i];
  }
  float kn2 = wred(sq_part<8>(Kv));
  project_vec<8>(Kv, &kn2);
  float NQ[8];
#pragma unroll
  for (int i = 0; i < 8; i++) NQ[i] = -Q[i];
  const float xy = wred(dot_part<8>(NQ, Kv));
  float Z[8]; madd_vec<8>(NQ, qn2, Kv, kn2, xy, Z);
  const float zn2 = wred(sq_part<8>(Z));
  const float d = 2.f * atanhf(clamp11(snorm(zn2)));
  if (lane == 0) dout[r] = d;
}

__global__ __launch_bounds__(256) void softmax128(const float* __restrict__ d,
    const float* __restrict__ beta, float* __restrict__ w)
{
  const int wv = threadIdx.x >> 6, lane = threadIdx.x & 63;
  const int b = blockIdx.x*4 + wv;
  const float bt = beta[0];
  const float x0 = -bt * d[b*128 + lane];
  const float x1 = -bt * d[b*128 + 64 + lane];
  const float m = wredmax(fmaxf(x0, x1));
  const float e0 = expf(x0 - m), e1 = expf(x1 - m);
  const float s = wred(e0 + e1);
  w[b*128 + lane]      = e0 / s;
  w[b*128 + 64 + lane] = e1 / s;
}

__global__ void softmax8(const float* __restrict__ d, const float* __restrict__ beta,
                         float* __restrict__ w)
{
  const int b = threadIdx.x;   // 256
  const float bt = beta[0];
  float x[8]; float m = -1e30f;
#pragma unroll
  for (int i = 0; i < 8; i++){ x[i] = -bt * d[b*8+i]; m = fmaxf(m, x[i]); }
  float s = 0.f;
#pragma unroll
  for (int i = 0; i < 8; i++){ x[i] = expf(x[i]-m); s += x[i]; }
#pragma unroll
  for (int i = 0; i < 8; i++) w[b*8+i] = x[i] / s;
}

// weighted gyromidpoint via Klein model; one wave per batch row
template<int NPL, bool BF16V, bool HASW>
__global__ __launch_bounds__(256) void midpoint_kernel(const void* __restrict__ vals,
    const float* __restrict__ wts, float* __restrict__ outp, int Lseq)
{
  const int wv = threadIdx.x >> 6, lane = threadIdx.x & 63;
  const int b = blockIdx.x*4 + wv;
  const int D = NPL*64;
  float num[NPL];
#pragma unroll
  for (int i = 0; i < NPL; i++) num[i] = 0.f;
  float den = 0.f;
  for (int l = 0; l < Lseq; l++){
    const long base = ((long)b*Lseq + l)*D;
    float v[NPL]; float s = 0.f;
#pragma unroll
    for (int i = 0; i < NPL; i++){
      v[i] = BF16V ? bf2f(((const unsigned short*)vals)[base + i*64+lane])
                   : ((const float*)vals)[base + i*64+lane];
      s += v[i]*v[i];
    }
    const float v2 = wred(s);
    const float f = 2.f/(1.f + v2);
    const float kl2 = v2*f*f;
    const float gamma = 1.f/sqrtf(fmaxf(1.f - kl2, EPS_));
    const float wgt = HASW ? wts[b*Lseq + l] : 1.f;
    const float wg = wgt*gamma;
#pragma unroll
    for (int i = 0; i < NPL; i++) num[i] += wg*(f*v[i]);
    den += wg;
  }
  den = fmaxf(den, EPS_);
  float x[NPL]; float s = 0.f;
#pragma unroll
  for (int i = 0; i < NPL; i++){ x[i] = num[i]/den; s += x[i]*x[i]; }
  const float k2 = wred(s);
  const float inv = 1.f/(1.f + sqrtf(fmaxf(1.f - k2, EPS_)));
#pragma unroll
  for (int i = 0; i < NPL; i++) outp[(long)b*D + i*64+lane] = x[i]*inv;
}

// mention w2s mobius_linear with tanh nonlinearity
__global__ __launch_bounds__(256) void mv_rowwise(const float* __restrict__ mx,
    const float* __restrict__ xsqn, const float* __restrict__ bb, float* __restrict__ outp)
{
  const int wv = threadIdx.x >> 6, lane = threadIdx.x & 63;
  const long r = blockIdx.x*4 + wv;
  float M[8];
#pragma unroll
  for (int i = 0; i < 8; i++) M[i] = mx[r*512 + i*64+lane];
  { const float n2 = wred(sq_part<8>(M)); float pn2; mt_project<8>(M, n2, xsqn[r], &pn2);
    float Bv[8];
#pragma unroll
    for (int i = 0; i < 8; i++) Bv[i] = bb[i*64+lane];
    const float b2 = wred(sq_part<8>(Bv));
    const float xy = wred(dot_part<8>(M, Bv));
    float O[8]; madd_vec<8>(M, pn2, Bv, b2, xy, O);
#pragma unroll
    for (int i = 0; i < 8; i++) M[i] = O[i];
  }
  float on2 = wred(sq_part<8>(M));
  project_vec<8>(M, &on2);
  { const float n = snorm(on2);
    const float fac = atanhf(clamp11(n))/n;
#pragma unroll
    for (int i = 0; i < 8; i++) M[i] = tanhf(fac*M[i]); }
  const float un2 = wred(sq_part<8>(M));
  { const float n = snorm(un2);
    const float fac = tanhf(n)/n;
    float en2 = fac*fac*un2;
#pragma unroll
    for (int i = 0; i < 8; i++) M[i] *= fac;
    project_vec<8>(M, &en2); }
#pragma unroll
  for (int i = 0; i < 8; i++) outp[r*512 + i*64+lane] = M[i];
}

// joint = project(madd(madd(madd(mt(jm),mt(jc)),mt(jch)),fc_bias))
__global__ __launch_bounds__(256) void final_rowwise(const float* __restrict__ jm,
    const float* __restrict__ jc, const float* __restrict__ jch,
    const float* __restrict__ mvec, const float* __restrict__ cvec,
    const float* __restrict__ chvec, const float* __restrict__ fcb,
    float* __restrict__ joint)
{
  const int wv = threadIdx.x >> 6, lane = threadIdx.x & 63;
  const long b = blockIdx.x*4 + wv;
  float s;
  s = 0.f; for (int i = 0; i < 8; i++){ const float v = mvec[b*512 + i*64+lane]; s += v*v; }
  const float mn2 = wred(s);
  s = 0.f; for (int i = 0; i < 8; i++){ const float v = cvec[b*512 + i*64+lane]; s += v*v; }
  const float cn2 = wred(s);
  s = 0.f; for (int i = 0; i < 4; i++){ const float v = chvec[b*256 + i*64+lane]; s += v*v; }
  const float chn2 = wred(s);
  float A[20];
#pragma unroll
  for (int i = 0; i < 20; i++) A[i] = jm[b*1280 + i*64+lane];
  float an2;
  { const float n2 = wred(sq_part<20>(A)); mt_project<20>(A, n2, mn2, &an2); }
  float T[20];
#pragma unroll
  for (int i = 0; i < 20; i++) T[i] = jc[b*1280 + i*64+lane];
  float tn2;
  { const float n2 = wred(sq_part<20>(T)); mt_project<20>(T, n2, cn2, &tn2); }
  { const float xy = wred(dot_part<20>(A, T));
    float O[20]; madd_vec<20>(A, an2, T, tn2, xy, O);
#pragma unroll
    for (int i = 0; i < 20; i++) A[i] = O[i];
    an2 = wred(sq_part<20>(A)); }
#pragma unroll
  for (int i = 0; i < 20; i++) T[i] = jch[b*1280 + i*64+lane];
  { const float n2 = wred(sq_part<20>(T)); mt_project<20>(T, n2, chn2, &tn2); }
  { const float xy = wred(dot_part<20>(A, T));
    float O[20]; madd_vec<20>(A, an2, T, tn2, xy, O);
#pragma unroll
    for (int i = 0; i < 20; i++) A[i] = O[i];
    an2 = wred(sq_part<20>(A)); }
#pragma unroll
  for (int i = 0; i < 20; i++) T[i] = fcb[i*64+lane];
  tn2 = wred(sq_part<20>(T));
  { const float xy = wred(dot_part<20>(A, T));
    float O[20]; madd_vec<20>(A, an2, T, tn2, xy, O);
#pragma unroll
    for (int i = 0; i < 20; i++) A[i] = O[i];
    an2 = wred(sq_part<20>(A)); }
  project_vec<20>(A, &an2);
#pragma unroll
  for (int i = 0; i < 20; i++) joint[b*1280 + i*64+lane] = A[i];
}

// hyperbolic MLR head
__global__ __launch_bounds__(256) void mlr_kernel(const float* __restrict__ joint,
    const float* __restrict__ P, const float* __restrict__ A, float* __restrict__ outp)
{
  const int wv = threadIdx.x >> 6, lane = threadIdx.x & 63;
  const int pair = blockIdx.x*4 + wv;
  const long b = pair >> 7, c = pair & 127;
  float Pv[20], J[20];
#pragma unroll
  for (int i = 0; i < 20; i++){
    Pv[i] = -P[c*1280 + i*64+lane];
    J[i]  = joint[b*1280 + i*64+lane];
  }
  const float p2 = wred(sq_part<20>(Pv));
  const float j2 = wred(sq_part<20>(J));
  const float xy = wred(dot_part<20>(Pv, J));
  float Z[20]; madd_vec<20>(Pv, p2, J, j2, xy, Z);
  float sza = 0.f, sz2 = 0.f, sa2 = 0.f;
#pragma unroll
  for (int i = 0; i < 20; i++){
    const float a = A[c*1280 + i*64+lane];
    sza += Z[i]*a; sz2 += Z[i]*Z[i]; sa2 += a*a;
  }
  float za = sza, z2 = sz2, a2 = sa2;
  wred3(za, z2, a2);
  const float an = sqrtf(fmaxf(a2, EPS_));
  const float v = 2.f*za / (fmaxf(1.f - z2, EPS_)*an);
  if (lane == 0) outp[pair] = 2.f*an*asinhf(v);
}

// ---------------------------------------------------------------------------
extern "C" void kernel_launch(void* const* d_in, const int* in_sizes, int n_in,
                              void* d_out, int out_size, void* d_ws, size_t ws_size,
                              hipStream_t stream)
{
  (void)in_sizes; (void)n_in; (void)out_size;
  const int*   context   = (const int*)  d_in[0];
  const int*   ctx_position=(const int*) d_in[1];
  const int*   mentions  = (const int*)  d_in[2];
  const int*   mchars    = (const int*)  d_in[3];
  const float* word_lut  = (const float*)d_in[4];
  const float* char_lut  = (const float*)d_in[5];
  const float* gf_Wih    = (const float*)d_in[6];
  const float* gf_Whh    = (const float*)d_in[7];
  const float* gf_b      = (const float*)d_in[8];
  const float* gb_Wih    = (const float*)d_in[9];
  const float* gb_Whh    = (const float*)d_in[10];
  const float* gb_b      = (const float*)d_in[11];
  const float* w2s_W     = (const float*)d_in[12];
  const float* w2s_b     = (const float*)d_in[13];
  const float* men_pos   = (const float*)d_in[14];
  const float* men_Wq    = (const float*)d_in[15];
  const float* men_bq    = (const float*)d_in[16];
  const float* men_Wk    = (const float*)d_in[17];
  const float* men_bk    = (const float*)d_in[18];
  const float* men_beta  = (const float*)d_in[19];
  const float* char_W    = (const float*)d_in[20];
  const float* char_U    = (const float*)d_in[21];
  const float* char_b    = (const float*)d_in[22];
  const float* cc_Wa     = (const float*)d_in[23];
  const float* cc_Wb     = (const float*)d_in[24];
  const float* cc_bias   = (const float*)d_in[25];
  const float* ctx_pos_t = (const float*)d_in[26];
  const float* ctx_Wq    = (const float*)d_in[27];
  const float* ctx_bq    = (const float*)d_in[28];
  const float* ctx_Wk    = (const float*)d_in[29];
  const float* ctx_bk    = (const float*)d_in[30];
  const float* ctx_beta  = (const float*)d_in[31];
  const float* fc_Wm     = (const float*)d_in[32];
  const float* fc_Wc     = (const float*)d_in[33];
  const float* fc_Wch    = (const float*)d_in[34];
  const float* fc_bias   = (const float*)d_in[35];
  const float* mlr_p     = (const float*)d_in[36];
  const float* mlr_a     = (const float*)d_in[37];
  float* out = (float*)d_out;

  // ---- workspace bump allocator ----
  char* wsb = (char*)d_ws;
  size_t off = 0;
  auto alloc = [&](size_t bytes) -> void* {
    void* p = wsb + off;
    off += (bytes + 255) & ~(size_t)255;
    return p;
  };
  float* WtIH = (float*)alloc(2UL*300*768*4);
  float* WtHH = (float*)alloc(2UL*256*768*4);
  float* WrzG = (float*)alloc(2UL*256*512*4);     // phase1 slabs (r|z)
  float* WhG  = (float*)alloc(2UL*256*256*4);     // phase2 slab (h)
  int*   ctxidx = (int*)alloc(32768UL*4);
  int*   chidx  = (int*)alloc(4096UL*4);
  float* xsqn   = (float*)alloc(32768UL*4);
  float* msqn   = (float*)alloc(2048UL*4);
  float* chsqn  = (float*)alloc(4096UL*4);
  unsigned short* xg = (unsigned short*)alloc(2UL*32768*768*2);
  float* xgn2 = (float*)alloc(2UL*32768*3*4);
  float* chn2d = (float*)alloc(4096UL*4);
  unsigned short* states_f = (unsigned short*)alloc(32768UL*256*2);
  unsigned short* states_b = (unsigned short*)alloc(32768UL*256*2);
  unsigned short* ctxv = (unsigned short*)alloc(32768UL*512*2);
  float* attn_sqn = (float*)alloc(32768UL*4);
  float* dctx = (float*)alloc(32768UL*4);
  float* wctx = (float*)alloc(32768UL*4);
  float* ctx_vec = (float*)alloc(256UL*512*4);
  float* mxbuf = (float*)alloc(2UL*8192*512*4);
  float* mv = (float*)alloc(2048UL*512*4);
  float* attn_embm = (float*)alloc(2048UL*512*4);
  float* amsqn = (float*)alloc(2048UL*4);
  float* dm = (float*)alloc(2048UL*4);
  float* wm = (float*)alloc(2048UL*4);
  float* mention_vec = (float*)alloc(256UL*512*4);
  unsigned short* xgc = (unsigned short*)alloc(4096UL*256*2);
  float* char_states = (float*)alloc(4096UL*256*4);
  float* char_vec = (float*)alloc(256UL*256*4);
  float* joint = (float*)alloc(256UL*1280*4);
  if (off > ws_size) return;
  float* attn_embc = (float*)xg;                   // overlay: xg dead after GRU
  float* mxh0 = mxbuf;
  float* mxh1 = mxbuf + 8192UL*512;

  // ---- weight transposes + split ----
  transpose_k<<<dim3(10,24),256,0,stream>>>(gf_Wih, WtIH,            768, 300);
  transpose_k<<<dim3(10,24),256,0,stream>>>(gb_Wih, WtIH + 300*768,  768, 300);
  transpose_k<<<dim3(8,24), 256,0,stream>>>(gf_Whh, WtHH,            768, 256);
  transpose_k<<<dim3(8,24), 256,0,stream>>>(gb_Whh, WtHH + 256*768,  768, 256);
  split_whh<<<1536,256,0,stream>>>(WtHH, WrzG, WhG);

  // ---- gather indices + input sqn ----
  build_idx<<<144,256,0,stream>>>(context, mchars, ctxidx, chidx);
  sqn_gather<<<8192,256,0,stream>>>(word_lut, ctxidx, 300, xsqn);
  sqn_gather<<<512, 256,0,stream>>>(word_lut, mentions, 300, msqn);
  sqn_gather<<<1024,256,0,stream>>>(char_lut, chidx, 256, chsqn);

  // ---- GRU input precompute: xg[dir] = mobius_matvec(emb, Wih^T), bf16 ----
  for (int d2 = 0; d2 < 2; d2++){
    const float* wih_t = WtIH + (size_t)d2*300*768;
    for (int c = 0; c < 4; c++){
      mm_kernel<1><<<dim3(6,64),256,0,stream>>>(word_lut, ctxidx + c*8192, wih_t,
                                                mxbuf, 8192, 768, 300);
      xg_transform<<<6144,256,0,stream>>>(mxbuf, xsqn + c*8192,
          xg + ((size_t)d2*32768 + (size_t)c*8192)*768,
          xgn2 + ((size_t)d2*32768 + (size_t)c*8192)*3, 3);
    }
  }

  // ---- bidirectional Mobius GRU (LDS-streamed weights) ----
  (void)hipFuncSetAttribute((const void*)gru_kernel,
      hipFuncAttributeMaxDynamicSharedMemorySize, GRU_LDS_BYTES);
  gru_kernel<<<128,256,GRU_LDS_BYTES,stream>>>(xg, xgn2, WrzG, WhG,
                                               gf_b, gb_b, states_f, states_b);

  // ---- mobius concat of directions -> ctx (bf16) ----
  for (int c = 0; c < 4; c++){
    mm_kernel<2><<<dim3(4,64),256,0,stream>>>(states_f + (size_t)c*8192*256, nullptr,
                                              cc_Wa, mxh0, 8192, 512, 256);
    mm_kernel<2><<<dim3(4,64),256,0,stream>>>(states_b + (size_t)c*8192*256, nullptr,
                                              cc_Wb, mxh1, 8192, 512, 256);
    cc_rowwise<<<2048,256,0,stream>>>(states_f, states_b, mxh0, mxh1, cc_bias,
                                      ctxv, c*8192);
  }

  // ---- context distance attention ----
  attn_add<<<8192,256,0,stream>>>(ctxv, ctx_position, ctx_pos_t, attn_embc, attn_sqn);
  for (int c = 0; c < 4; c++){
    mm_kernel<0><<<dim3(4,64),256,0,stream>>>(attn_embc + (size_t)c*8192*512, nullptr,
                                              ctx_Wq, mxh0, 8192, 512, 512);
    mm_kernel<0><<<dim3(4,64),256,0,stream>>>(attn_embc + (size_t)c*8192*512, nullptr,
                                              ctx_Wk, mxh1, 8192, 512, 512);
    qk_pdist<<<2048,256,0,stream>>>(mxh0, mxh1, attn_sqn + c*8192, ctx_bq, ctx_bk,
                                    dctx + c*8192);
  }
  softmax128<<<64,256,0,stream>>>(dctx, ctx_beta, wctx);
  midpoint_kernel<8,true,true><<<64,256,0,stream>>>(ctxv, wctx, ctx_vec, 128);

  // ---- mention encoder ----
  mm_kernel<1><<<dim3(4,16),256,0,stream>>>(word_lut, mentions, w2s_W, mxh0, 2048, 512, 300);
  mv_rowwise<<<512,256,0,stream>>>(mxh0, msqn, w2s_b, mv);
  attn_add_m<<<512,256,0,stream>>>(mv, mentions, men_pos, attn_embm, amsqn);
  mm_kernel<0><<<dim3(4,16),256,0,stream>>>(attn_embm, nullptr, men_Wq, mxh0, 2048, 512, 512);
  mm_kernel<0><<<dim3(4,16),256,0,stream>>>(attn_embm, nullptr, men_Wk, mxh1, 2048, 512, 512);
  qk_pdist<<<512,256,0,stream>>>(mxh0, mxh1, amsqn, men_bq, men_bk, dm);
  softmax8<<<1,256,0,stream>>>(dm, men_beta, wm);
  midpoint_kernel<8,false,true><<<64,256,0,stream>>>(mv, wm, mention_vec, 8);

  // ---- char encoder ----
  mm_kernel<1><<<dim3(2,32),256,0,stream>>>(char_lut, chidx, char_U, mxh0, 4096, 256, 256);
  xg_transform<<<1024,256,0,stream>>>(mxh0, chsqn, xgc, chn2d, 1);
  char_rnn<<<64,256,0,stream>>>(xgc, char_W, char_b, char_states);
  midpoint_kernel<4,false,false><<<64,256,0,stream>>>(char_states, nullptr, char_vec, 16);

  // ---- full mobius concat + MLR ----
  float* jm = mxh0;
  float* jc = mxh0 + 256UL*1280;
  float* jch = mxh0 + 2UL*256*1280;
  mm_kernel<0><<<dim3(10,2),256,0,stream>>>(mention_vec, nullptr, fc_Wm, jm, 256, 1280, 512);
  mm_kernel<0><<<dim3(10,2),256,0,stream>>>(ctx_vec,     nullptr, fc_Wc, jc, 256, 1280, 512);
  mm_kernel<0><<<dim3(10,2),256,0,stream>>>(char_vec,    nullptr, fc_Wch, jch, 256, 1280, 256);
  final_rowwise<<<64,256,0,stream>>>(jm, jc, jch, mention_vec, ctx_vec, char_vec,
                                     fc_bias, joint);
  mlr_kernel<<<8192,256,0,stream>>>(joint, mlr_p, mlr_a, out);
}

// Round 5
// 5167.970 us; speedup vs baseline: 1.8172x; 1.1268x over previous
//
#include <hip/hip_runtime.h>
#include <cstddef>
#include <cstdint>

// ---------------------------------------------------------------------------
// Hyperbolic (Poincare-ball) entity-typing forward pass, MI355X / gfx950.
// Round 5: GRU = round-4 structure with BF16 weight streaming (half bytes,
// 6 chunk-drains/step instead of 12). bf16 GRU weights measured-safe in r3
// (absmax identical to f32). Everything else unchanged from passing round 4.
// ---------------------------------------------------------------------------

#define EPS_  1e-15f
#define PMAX_ 0.99999f    // 1 - 1e-5

__device__ __forceinline__ float wred(float v){
#pragma unroll
  for (int o = 32; o; o >>= 1) v += __shfl_xor(v, o, 64);
  return v;
}
__device__ __forceinline__ void wred2(float& a, float& b){
#pragma unroll
  for (int o = 32; o; o >>= 1){ a += __shfl_xor(a, o, 64); b += __shfl_xor(b, o, 64); }
}
__device__ __forceinline__ void wred3(float& a, float& b, float& c){
#pragma unroll
  for (int o = 32; o; o >>= 1){
    a += __shfl_xor(a, o, 64); b += __shfl_xor(b, o, 64); c += __shfl_xor(c, o, 64);
  }
}
__device__ __forceinline__ void wred4(float& a, float& b, float& c, float& d){
#pragma unroll
  for (int o = 32; o; o >>= 1){
    a += __shfl_xor(a, o, 64); b += __shfl_xor(b, o, 64);
    c += __shfl_xor(c, o, 64); d += __shfl_xor(d, o, 64);
  }
}
__device__ __forceinline__ float wredmax(float v){
#pragma unroll
  for (int o = 32; o; o >>= 1) v = fmaxf(v, __shfl_xor(v, o, 64));
  return v;
}
__device__ __forceinline__ float snorm(float s){ return sqrtf(fmaxf(s, EPS_)); }
__device__ __forceinline__ float clamp11(float x){
  return fminf(fmaxf(x, -1.f + 1e-7f), 1.f - 1e-7f);
}
__device__ __forceinline__ float bf2f(unsigned short u){
  union { unsigned int i; float f; } v; v.i = ((unsigned int)u) << 16; return v.f;
}
__device__ __forceinline__ unsigned short f2bf(float f){
  union { float f; unsigned int i; } v; v.f = f;
  unsigned int x = v.i;
  x += 0x7fffu + ((x >> 16) & 1u);   // RNE
  return (unsigned short)(x >> 16);
}
__device__ __forceinline__ float bflo(unsigned u){
  union { unsigned i; float f; } v; v.i = u << 16; return v.f;
}
__device__ __forceinline__ float bfhi(unsigned u){
  union { unsigned i; float f; } v; v.i = u & 0xffff0000u; return v.f;
}

template<int N>
__device__ __forceinline__ float sq_part(const float* a){
  float s = 0.f;
#pragma unroll
  for (int i = 0; i < N; i++) s += a[i]*a[i];
  return s;
}
template<int N>
__device__ __forceinline__ float dot_part(const float* a, const float* b){
  float s = 0.f;
#pragma unroll
  for (int i = 0; i < N; i++) s += a[i]*b[i];
  return s;
}
template<int N>
__device__ __forceinline__ void madd_vec(const float* x, float x2, const float* y,
                                         float y2, float xy, float* o){
  const float c1 = 1.f + 2.f*xy + y2;
  const float c2 = 1.f - x2;
  const float inv = 1.f / fmaxf(1.f + 2.f*xy + x2*y2, EPS_);
#pragma unroll
  for (int i = 0; i < N; i++) o[i] = (c1*x[i] + c2*y[i]) * inv;
}
template<int N>
__device__ __forceinline__ void mt_project(float* v, float mxn2, float xn2, float* n2out){
  const float xn  = snorm(xn2);
  const float mxn = snorm(mxn2);
  const float t   = tanhf(mxn/xn * atanhf(clamp11(xn)));
  float sc = t/mxn;
  float n2 = sc*sc*mxn2;
  const float n = snorm(n2);
  if (n > PMAX_){ const float s = PMAX_/n; sc *= s; n2 *= s*s; }
#pragma unroll
  for (int i = 0; i < N; i++) v[i] *= sc;
  *n2out = n2;
}
__device__ __forceinline__ void mt_scale(float mxn2, float xn, float art,
                                         float* sc, float* n2){
  const float mxn = snorm(mxn2);
  const float t   = tanhf(mxn/xn * art);
  float s  = t/mxn;
  float nn = t*t;
  const float n = snorm(nn);
  if (n > PMAX_){ const float f = PMAX_/n; s *= f; nn *= f*f; }
  *sc = s; *n2 = nn;
}
template<int N>
__device__ __forceinline__ void project_vec(float* v, float* n2io){
  float n2 = *n2io;
  const float n = snorm(n2);
  if (n > PMAX_){
    const float s = PMAX_/n;
#pragma unroll
    for (int i = 0; i < N; i++) v[i] *= s;
    n2 *= s*s;
  }
  *n2io = n2;
}

// async 16B global->LDS: linear wave-uniform-base + lane*16
__device__ __forceinline__ void gll16(const void* g, void* l){
  __builtin_amdgcn_global_load_lds(
      (const __attribute__((address_space(1))) void*)g,
      (__attribute__((address_space(3))) void*)l, 16, 0, 0);
}
// stage 64KB (256 thr x 16 x 16B), linear layout
__device__ __forceinline__ void stage64k(const void* gsrc, float* lbase, int w, int lane){
#pragma unroll
  for (int i = 0; i < 16; i++){
    const char* g = (const char*)gsrc + (size_t)((i*4 + w)*64 + lane)*16;
    char* l = (char*)lbase + (size_t)((i*4 + w)*64)*16;
    gll16(g, l);
  }
}

// ---------------------------------------------------------------------------
// Generic tiled f32 GEMM: C[M,N] = A[M,K] @ B[K,N].
// AMODE: 0 = f32 direct, 1 = f32 row-gathered via idx (A = lut), 2 = bf16 direct.
// ---------------------------------------------------------------------------
template<int AMODE>
__global__ __launch_bounds__(256) void mm_kernel(const void* __restrict__ Aptr,
    const int* __restrict__ idx, const float* __restrict__ Bm,
    float* __restrict__ Cm, int M, int N, int K)
{
  __shared__ __align__(16) float As[8][128];
  __shared__ __align__(16) float Bs[8][132];
  const int tid = threadIdx.x;
  const int n0 = blockIdx.x * 128;
  const int m0 = blockIdx.y * 128;
  const int tr = tid >> 4, tc = tid & 15;
  const int sm = tid & 127, sk = (tid >> 7) * 4;
  const int bk = tid >> 5,  bn = (tid & 31) * 4;
  long arow;
  if constexpr (AMODE == 1) arow = (long)idx[m0 + sm] * K;
  else                      arow = (long)(m0 + sm) * K;
  float acc[8][8];
#pragma unroll
  for (int i = 0; i < 8; i++)
#pragma unroll
    for (int j = 0; j < 8; j++) acc[i][j] = 0.f;

  for (int k0 = 0; k0 < K; k0 += 8){
    float av[4], bv[4];
    if constexpr (AMODE == 2){
      const unsigned short* A = (const unsigned short*)Aptr;
      const ushort4 u = *reinterpret_cast<const ushort4*>(A + arow + k0 + sk);
      av[0]=bf2f(u.x); av[1]=bf2f(u.y); av[2]=bf2f(u.z); av[3]=bf2f(u.w);
    } else {
      const float* A = (const float*)Aptr;
      if (k0 + sk + 3 < K){
        const float4 f = *reinterpret_cast<const float4*>(A + arow + k0 + sk);
        av[0]=f.x; av[1]=f.y; av[2]=f.z; av[3]=f.w;
      } else {
#pragma unroll
        for (int i = 0; i < 4; i++){
          const int kk = k0 + sk + i;
          av[i] = (kk < K) ? A[arow + kk] : 0.f;
        }
      }
    }
    {
      const int kb = k0 + bk;
      if (kb < K){
        const float4 f = *reinterpret_cast<const float4*>(Bm + (long)kb*N + n0 + bn);
        bv[0]=f.x; bv[1]=f.y; bv[2]=f.z; bv[3]=f.w;
      } else { bv[0]=bv[1]=bv[2]=bv[3]=0.f; }
    }
    __syncthreads();
    As[sk+0][sm]=av[0]; As[sk+1][sm]=av[1]; As[sk+2][sm]=av[2]; As[sk+3][sm]=av[3];
    *reinterpret_cast<float4*>(&Bs[bk][bn]) = make_float4(bv[0],bv[1],bv[2],bv[3]);
    __syncthreads();
#pragma unroll
    for (int k = 0; k < 8; k++){
      float a[8], bb[8];
      *(float4*)&a[0]  = *(const float4*)&As[k][tr*8];
      *(float4*)&a[4]  = *(const float4*)&As[k][tr*8+4];
      *(float4*)&bb[0] = *(const float4*)&Bs[k][tc*8];
      *(float4*)&bb[4] = *(const float4*)&Bs[k][tc*8+4];
#pragma unroll
      for (int i = 0; i < 8; i++)
#pragma unroll
        for (int j = 0; j < 8; j++) acc[i][j] += a[i]*bb[j];
    }
  }
#pragma unroll
  for (int i = 0; i < 8; i++){
    const long row = m0 + tr*8 + i;
    *(float4*)(Cm + row*N + n0 + tc*8)     = make_float4(acc[i][0],acc[i][1],acc[i][2],acc[i][3]);
    *(float4*)(Cm + row*N + n0 + tc*8 + 4) = make_float4(acc[i][4],acc[i][5],acc[i][6],acc[i][7]);
  }
}

// ---------------------------------------------------------------------------
// 32x32 LDS-tiled transpose: dst[k*R + j] = src[j*Kc + k]
// ---------------------------------------------------------------------------
__global__ __launch_bounds__(256) void transpose_k(const float* __restrict__ src,
    float* __restrict__ dst, int R, int Kc)
{
  __shared__ float t[32][33];
  const int bx = blockIdx.x * 32;   // k dim
  const int by = blockIdx.y * 32;   // j dim
  const int tx = threadIdx.x & 31, ty = threadIdx.x >> 5;
#pragma unroll
  for (int i = 0; i < 32; i += 8){
    const int j = by + ty + i, k = bx + tx;
    t[ty+i][tx] = (j < R && k < Kc) ? src[(long)j*Kc + k] : 0.f;
  }
  __syncthreads();
#pragma unroll
  for (int i = 0; i < 32; i += 8){
    const int k = bx + ty + i, j = by + tx;
    if (k < Kc && j < R) dst[(long)k*R + j] = t[tx][ty+i];
  }
}

// split+pack WtHH [2][256][768] (r|h|z) f32 -> Wrz16 [2][256][512] (r|z) bf16,
// Wh16 [2][256][256] bf16
__global__ void pack_whh16(const float* __restrict__ WtHH,
                           unsigned short* __restrict__ Wrz16,
                           unsigned short* __restrict__ Wh16)
{
  const int tid = blockIdx.x*256 + threadIdx.x;    // 0 .. 393215
  if (tid < 2*256*768){
    const int col = tid % 768, rk = tid / 768;     // rk = dir*256 + k
    const unsigned short v = f2bf(WtHH[tid]);
    if (col < 256)       Wrz16[(long)rk*512 + col] = v;
    else if (col < 512)  Wh16 [(long)rk*256 + (col - 256)] = v;
    else                 Wrz16[(long)rk*512 + 256 + (col - 512)] = v;
  }
}

// build gather-index arrays: ctxidx[t*256+b]=context[b*128+t]; chidx[t*256+b]=mchars[b*16+t]
__global__ void build_idx(const int* __restrict__ context, const int* __restrict__ mchars,
                          int* __restrict__ ctxidx, int* __restrict__ chidx)
{
  const int tid = blockIdx.x*256 + threadIdx.x;
  if (tid < 32768){
    const int t = tid >> 8, b = tid & 255;
    ctxidx[tid] = context[b*128 + t];
  } else if (tid < 32768 + 4096){
    const int o = tid - 32768;
    const int t = o >> 8, b = o & 255;
    chidx[o] = mchars[b*16 + t];
  }
}

// out[r] = sum_k lut[idx[r]][k]^2   (one wave per row)
__global__ __launch_bounds__(256) void sqn_gather(const float* __restrict__ lut,
    const int* __restrict__ idx, int K, float* __restrict__ outp)
{
  const int wv = threadIdx.x >> 6, lane = threadIdx.x & 63;
  const int r = blockIdx.x*4 + wv;
  const float* row = lut + (long)idx[r]*K;
  float s = 0.f;
  for (int k = lane; k < K; k += 64) s += row[k]*row[k];
  s = wred(s);
  if (lane == 0) outp[r] = s;
}

// mobius_matvec tail transform applied per (row, gate); out bf16 + |out_bf16|^2
__global__ __launch_bounds__(256) void xg_transform(const float* __restrict__ mx,
    const float* __restrict__ xsqn, unsigned short* __restrict__ outp,
    float* __restrict__ n2o, int G)
{
  const int wv = threadIdx.x >> 6, lane = threadIdx.x & 63;
  const int wg = blockIdx.x*4 + wv;
  const int row = wg / G, g = wg - row*G;
  const long base = (long)row*(G*256) + g*256;
  float M[4];
#pragma unroll
  for (int i = 0; i < 4; i++) M[i] = mx[base + i*64 + lane];
  const float mxn2 = wred(sq_part<4>(M));
  float pn2; mt_project<4>(M, mxn2, xsqn[row], &pn2);
  float s = 0.f;
#pragma unroll
  for (int i = 0; i < 4; i++){
    const unsigned short u = f2bf(M[i]);
    outp[base + i*64 + lane] = u;
    const float rv = bf2f(u);
    s += rv*rv;
  }
  s = wred(s);
  if (lane == 0) n2o[wg] = s;
}

// ---------------------------------------------------------------------------
// Mobius GRU v5: 128 blocks x 256 thr; 4 rows/block (row = wave for chains).
// BF16 weights streamed L2->LDS via global_load_lds, 64KB chunks:
// phase1 Wrz 256KB -> 4 chunks; phase2 Wh 128KB -> 2 chunks.
// Phase1 wave roles: gate g=w>>1 (0:r,1:z), j-half jh=w&1, 2 cols/lane (1 u32).
// Phase2 wave roles: k-half kh=w>>1, j-half jh=w&1.
// LDS: wbuf 2x64KB | hs 4K | pr 4K | pz 4K | rhb 4K = 144KB (dynamic).
// ---------------------------------------------------------------------------
#define GRU_LDS_BYTES 147456

__global__ __launch_bounds__(256,1) void gru_kernel(
    const unsigned short* __restrict__ xg,     // [2][32768][768] bf16
    const float* __restrict__ xgn2,            // [2][32768][3]
    const unsigned short* __restrict__ Wrz16,  // [2][256][512] bf16
    const unsigned short* __restrict__ Wh16,   // [2][256][256] bf16
    const float* __restrict__ bias_f, const float* __restrict__ bias_b,
    unsigned short* __restrict__ states_f, unsigned short* __restrict__ states_b)
{
  extern __shared__ __align__(16) char smem[];
  float* wbuf = (float*)smem;                    // 2 x 16384 f32-slots (64KB each)
  float* hs   = (float*)(smem + 131072);         // [4][256]
  float* pr   = (float*)(smem + 135168);         // [4][256]
  float* pz   = (float*)(smem + 139264);         // [4][256]
  float* rhb  = (float*)(smem + 143360);         // [4][256]

  const int bid = blockIdx.x;
  const int dir = bid >> 6;
  const int b0  = (bid & 63) * 4;
  const int tid = threadIdx.x;
  const int w = tid >> 6, lane = tid & 63;
  const int j0 = lane << 2;

  const unsigned short* xgd = xg + (long)dir*32768*768;
  const float* xnd = xgn2 + (long)dir*32768*3;
  const unsigned short* wrz_d = Wrz16 + (long)dir*256*512;
  const unsigned short* wh_d  = Wh16  + (long)dir*256*256;
  const float* bias = dir ? bias_b : bias_f;
  unsigned short* states = dir ? states_b : states_f;

  // FMA-role constants
  const int g   = w >> 1;            // phase1 gate: 0=r, 1=z
  const int jh  = w & 1;
  const int jj  = jh*128 + lane*2;   // gate-local element col pair base
  const int ci  = g*128 + jh*64 + lane;  // phase1 u32 col index (512 cols -> 256 u32)
  const int ci2 = jh*64 + lane;          // phase2 u32 col index (256 cols -> 128 u32)
  const int kh  = w >> 1;            // phase2 k-half

  // row-role (this wave owns batch row brow)
  const int brow = b0 + w;
  float br4[4], bh4[4], bz4[4];
#pragma unroll
  for (int i = 0; i < 4; i++){
    br4[i] = bias[      j0+i];
    bh4[i] = bias[256 + j0+i];
    bz4[i] = bias[512 + j0+i];
  }
  float br2 = sq_part<4>(br4), bh2 = sq_part<4>(bh4), bz2 = sq_part<4>(bz4);
  wred3(br2, bh2, bz2);

  float h[4] = {0.f,0.f,0.f,0.f};
  float hn2 = 0.f;
  *(float4*)&hs[w*256 + j0] = make_float4(0.f,0.f,0.f,0.f);
  __syncthreads();

  int cb = 0;
  stage64k(wrz_d, wbuf, w, lane);    // Wrz chunk 0 -> buf 0

  for (int t = 0; t < 128; t++){
    const int tt = dir ? (127 - t) : t;
    const long rx = (long)tt*256 + brow;
    const unsigned short* xr = xgd + rx*768;
    float xgr[4], xgh[4], xgz[4];
    { const ushort4 u = *(const ushort4*)(xr + j0);       xgr[0]=bf2f(u.x); xgr[1]=bf2f(u.y); xgr[2]=bf2f(u.z); xgr[3]=bf2f(u.w); }
    { const ushort4 u = *(const ushort4*)(xr + 256 + j0); xgh[0]=bf2f(u.x); xgh[1]=bf2f(u.y); xgh[2]=bf2f(u.z); xgh[3]=bf2f(u.w); }
    { const ushort4 u = *(const ushort4*)(xr + 512 + j0); xgz[0]=bf2f(u.x); xgz[1]=bf2f(u.y); xgz[2]=bf2f(u.z); xgz[3]=bf2f(u.w); }
    const float y2r = xnd[rx*3 + 0];
    const float y2h = xnd[rx*3 + 1];
    const float y2z = xnd[rx*3 + 2];

    // ===== phase 1: r/z matvec (4 bf16 chunks of 64 k-rows x 512 cols) =====
    float a00=0.f,a01=0.f,a10=0.f,a11=0.f,a20=0.f,a21=0.f,a30=0.f,a31=0.f;
#pragma unroll 1
    for (int c = 0; c < 4; c++){
      __syncthreads();                          // stage(c) landed, other buf free
      if (c < 3) stage64k((const char*)wrz_d + (size_t)(c+1)*65536,
                          wbuf + (cb^1)*16384, w, lane);
      const unsigned* wb = (const unsigned*)(wbuf + cb*16384);  // [64][256] u32
      const int kb = c*64;
#pragma unroll
      for (int kq = 0; kq < 16; kq++){
        const float4 hb0 = *(const float4*)&hs[0*256 + kb + kq*4];
        const float4 hb1 = *(const float4*)&hs[1*256 + kb + kq*4];
        const float4 hb2 = *(const float4*)&hs[2*256 + kb + kq*4];
        const float4 hb3 = *(const float4*)&hs[3*256 + kb + kq*4];
#pragma unroll
        for (int q = 0; q < 4; q++){
          const unsigned wv = wb[(kq*4 + q)*256 + ci];
          const float w0 = bflo(wv), w1 = bfhi(wv);
          const float h0 = (&hb0.x)[q], h1 = (&hb1.x)[q];
          const float h2 = (&hb2.x)[q], h3 = (&hb3.x)[q];
          a00 += h0*w0; a01 += h0*w1;
          a10 += h1*w0; a11 += h1*w1;
          a20 += h2*w0; a21 += h2*w1;
          a30 += h3*w0; a31 += h3*w1;
        }
      }
      cb ^= 1;
    }
    {
      float* dst = g ? pz : pr;
      *(float2*)&dst[0*256 + jj] = make_float2(a00, a01);
      *(float2*)&dst[1*256 + jj] = make_float2(a10, a11);
      *(float2*)&dst[2*256 + jj] = make_float2(a20, a21);
      *(float2*)&dst[3*256 + jj] = make_float2(a30, a31);
    }
    __syncthreads();                            // B_a: full sums visible
    stage64k(wh_d, wbuf + (cb^1)*16384, w, lane);   // prefetch Wh chunk0
    cb ^= 1;

    // ================= gate chain (row = w) =================
    float az[4], ar[4];
    *(float4*)az = *(const float4*)&pz[w*256 + j0];
    *(float4*)ar = *(const float4*)&pr[w*256 + j0];
    const float xn_h  = snorm(hn2);
    const float art_h = atanhf(clamp11(xn_h));
    float pz2 = sq_part<4>(az), pr2 = sq_part<4>(ar);
    wred2(pz2, pr2);
    float scz, n2z; mt_scale(pz2, xn_h, art_h, &scz, &n2z);
    float scr, n2r; mt_scale(pr2, xn_h, art_h, &scr, &n2r);
    float pzv[4], prv[4];
#pragma unroll
    for (int i = 0; i < 4; i++){ pzv[i] = az[i]*scz; prv[i] = ar[i]*scr; }
    float xyz = dot_part<4>(pzv, xgz), xyr = dot_part<4>(prv, xgr);
    wred2(xyz, xyr);
    float m1z[4]; madd_vec<4>(pzv, n2z, xgz, y2z, xyz, m1z);
    float m1r[4]; madd_vec<4>(prv, n2r, xgr, y2r, xyr, m1r);
    float m1n2z = sq_part<4>(m1z), xybz = dot_part<4>(m1z, bz4);
    float m1n2r = sq_part<4>(m1r), xybr = dot_part<4>(m1r, br4);
    wred4(m1n2z, xybz, m1n2r, xybr);
    float m2z[4]; madd_vec<4>(m1z, m1n2z, bz4, bz2, xybz, m2z);
    float m2r[4]; madd_vec<4>(m1r, m1n2r, br4, br2, xybr, m2r);
    float m2n2z = sq_part<4>(m2z), m2n2r = sq_part<4>(m2r);
    wred2(m2n2z, m2n2r);
    float z[4], r[4];
    {
      const float nz = snorm(m2n2z), fz = atanhf(clamp11(nz))/nz;
      const float nr = snorm(m2n2r), fr = atanhf(clamp11(nr))/nr;
#pragma unroll
      for (int i = 0; i < 4; i++){
        z[i] = 1.f/(1.f + expf(-fz*m2z[i]));
        r[i] = 1.f/(1.f + expf(-fr*m2r[i]));
      }
    }
    float rh[4]; float wx2 = 0.f;
#pragma unroll
    for (int i = 0; i < 4; i++){ rh[i] = r[i]*h[i]; wx2 += rh[i]*rh[i]; }
    wx2 = wred(wx2);
    float rhn2, scrh;
    {
      const float wxn = snorm(wx2);
      const float trh = tanhf(wxn/xn_h * art_h);
      scrh = trh/wxn; rhn2 = trh*trh;
      const float n = snorm(rhn2);
      if (n > PMAX_){ const float f = PMAX_/n; scrh *= f; rhn2 *= f*f; }
    }
#pragma unroll
    for (int i = 0; i < 4; i++) rh[i] *= scrh;
    *(float4*)&rhb[w*256 + j0] = make_float4(rh[0],rh[1],rh[2],rh[3]);

    // ===== phase 2: h-gate matvec (2 bf16 chunks of 128 k-rows x 256 cols) =====
    float c00=0.f,c01=0.f,c10=0.f,c11=0.f,c20=0.f,c21=0.f,c30=0.f,c31=0.f;
#pragma unroll 1
    for (int c = 0; c < 2; c++){
      __syncthreads();                          // B_b (c==0): rhb ready + chunk landed
      if (c < 1) stage64k((const char*)wh_d + 65536, wbuf + (cb^1)*16384, w, lane);
      const unsigned* wb = (const unsigned*)(wbuf + cb*16384);  // [128][128] u32
      const int kb = c*128 + kh*64;             // global k base for this wave
#pragma unroll
      for (int kq = 0; kq < 16; kq++){
        const float4 hb0 = *(const float4*)&rhb[0*256 + kb + kq*4];
        const float4 hb1 = *(const float4*)&rhb[1*256 + kb + kq*4];
        const float4 hb2 = *(const float4*)&rhb[2*256 + kb + kq*4];
        const float4 hb3 = *(const float4*)&rhb[3*256 + kb + kq*4];
#pragma unroll
        for (int q = 0; q < 4; q++){
          const unsigned wv = wb[(kh*64 + kq*4 + q)*128 + ci2];
          const float w0 = bflo(wv), w1 = bfhi(wv);
          const float h0 = (&hb0.x)[q], h1 = (&hb1.x)[q];
          const float h2 = (&hb2.x)[q], h3 = (&hb3.x)[q];
          c00 += h0*w0; c01 += h0*w1;
          c10 += h1*w0; c11 += h1*w1;
          c20 += h2*w0; c21 += h2*w1;
          c30 += h3*w0; c31 += h3*w1;
        }
      }
      cb ^= 1;
    }
    {
      float* dst = kh ? pz : pr;                // k-half partials
      *(float2*)&dst[0*256 + jj] = make_float2(c00, c01);
      *(float2*)&dst[1*256 + jj] = make_float2(c10, c11);
      *(float2*)&dst[2*256 + jj] = make_float2(c20, c21);
      *(float2*)&dst[3*256 + jj] = make_float2(c30, c31);
    }
    __syncthreads();                            // B_c
    if (t < 127){                               // prefetch next step's Wrz chunk0
      stage64k(wrz_d, wbuf + (cb^1)*16384, w, lane);
      cb ^= 1;
    }

    // ================= h-update chain (row = w) =================
    float ah[4];
    {
      float4 p0 = *(const float4*)&pr[w*256 + j0];
      float4 p1 = *(const float4*)&pz[w*256 + j0];
      ah[0] = p0.x + p1.x; ah[1] = p0.y + p1.y; ah[2] = p0.z + p1.z; ah[3] = p0.w + p1.w;
    }
    const float rxn  = snorm(rhn2);
    const float artr = atanhf(clamp11(rxn));
    float mx2 = sq_part<4>(ah), xyraw = dot_part<4>(ah, xgh);
    wred2(mx2, xyraw);
    float sch, pn2; mt_scale(mx2, rxn, artr, &sch, &pn2);
#pragma unroll
    for (int i = 0; i < 4; i++) ah[i] *= sch;
    const float xy = xyraw * sch;
    float m1[4]; madd_vec<4>(ah, pn2, xgh, y2h, xy, m1);
    float m1n2 = sq_part<4>(m1), xyb = dot_part<4>(m1, bh4);
    wred2(m1n2, xyb);
    float ht[4]; madd_vec<4>(m1, m1n2, bh4, bh2, xyb, ht);
    float htn2 = sq_part<4>(ht);
    float nh[4];
#pragma unroll
    for (int i = 0; i < 4; i++) nh[i] = -h[i];
    float xyd = dot_part<4>(nh, ht);
    wred2(htn2, xyd);
    float dl[4]; madd_vec<4>(nh, hn2, ht, htn2, xyd, dl);
    float pw[4]; float dln2 = 0.f, wz2 = 0.f, xyhr = 0.f;
#pragma unroll
    for (int i = 0; i < 4; i++){
      dln2 += dl[i]*dl[i];
      pw[i] = z[i]*dl[i];
      wz2  += pw[i]*pw[i];
      xyhr += h[i]*pw[i];
    }
    wred3(dln2, wz2, xyhr);
    float pwn2, scpw;
    {
      const float dn   = snorm(dln2);
      const float artd = atanhf(clamp11(dn));
      const float wzn  = snorm(wz2);
      const float tpw  = tanhf(wzn/dn * artd);
      scpw = tpw/wzn; pwn2 = tpw*tpw;
      const float n = snorm(pwn2);
      if (n > PMAX_){ const float f = PMAX_/n; scpw *= f; pwn2 *= f*f; }
    }
#pragma unroll
    for (int i = 0; i < 4; i++) pw[i] *= scpw;
    const float xyh = xyhr * scpw;
    float hnew[4]; madd_vec<4>(h, hn2, pw, pwn2, xyh, hnew);
#pragma unroll
    for (int i = 0; i < 4; i++) h[i] = hnew[i];
    hn2 = wred(sq_part<4>(h));
    *(float4*)&hs[w*256 + j0] = make_float4(h[0],h[1],h[2],h[3]);
    unsigned short* srow = states + ((long)brow*128 + tt)*256 + j0;
    ushort4 su; su.x=f2bf(h[0]); su.y=f2bf(h[1]); su.z=f2bf(h[2]); su.w=f2bf(h[3]);
    *(ushort4*)srow = su;
    __syncthreads();                            // B_d: hs ready for next step
  }
}

// ---------------------------------------------------------------------------
// Char Mobius-RNN: h = project(madd(madd(matvec(h, W), xg), b)), 16 steps.
// ---------------------------------------------------------------------------
__global__ __launch_bounds__(256) void char_rnn(
    const unsigned short* __restrict__ xgc,
    const float* __restrict__ Wc,
    const float* __restrict__ cb,
    float* __restrict__ cstates)
{
  const int wv = threadIdx.x >> 6, lane = threadIdx.x & 63;
  const int b = blockIdx.x*4 + wv;
  const int j0 = lane << 2;
  __shared__ __align__(16) float hs[4][256];
  float h[4] = {0.f,0.f,0.f,0.f};
  float hn2 = 0.f;
#pragma unroll
  for (int i = 0; i < 4; i++) hs[wv][j0+i] = 0.f;
  float cbv[4];
#pragma unroll
  for (int i = 0; i < 4; i++) cbv[i] = cb[j0+i];
  const float cb2 = wred(sq_part<4>(cbv));
  for (int t = 0; t < 16; t++){
    __syncthreads();
    const unsigned short* xr = xgc + ((long)t*256 + b)*256;
    float xgv[4];
    { const ushort4 u = *(const ushort4*)(xr + j0); xgv[0]=bf2f(u.x); xgv[1]=bf2f(u.y); xgv[2]=bf2f(u.z); xgv[3]=bf2f(u.w); }
    float a[4]={0.f,0.f,0.f,0.f};
#pragma unroll 2
    for (int k0 = 0; k0 < 256; k0 += 4){
      const float4 hk = *(const float4*)&hs[wv][k0];
#pragma unroll
      for (int kk = 0; kk < 4; kk++){
        const float hv = (&hk.x)[kk];
        const float4 w4 = *(const float4*)(Wc + (long)(k0+kk)*256 + j0);
        a[0] += hv*w4.x; a[1] += hv*w4.y; a[2] += hv*w4.z; a[3] += hv*w4.w;
      }
    }
    const float mxn2 = wred(sq_part<4>(a));
    float pn2; mt_project<4>(a, mxn2, hn2, &pn2);
    const float y2 = wred(sq_part<4>(xgv));
    const float xy = wred(dot_part<4>(a, xgv));
    float m1[4]; madd_vec<4>(a, pn2, xgv, y2, xy, m1);
    const float m1n2 = wred(sq_part<4>(m1));
    const float xyb  = wred(dot_part<4>(m1, cbv));
    float m2[4]; madd_vec<4>(m1, m1n2, cbv, cb2, xyb, m2);
    float m2n2 = wred(sq_part<4>(m2));
    project_vec<4>(m2, &m2n2);
#pragma unroll
    for (int i = 0; i < 4; i++) h[i] = m2[i];
    hn2 = m2n2;
    *(float4*)&hs[wv][j0] = make_float4(h[0],h[1],h[2],h[3]);
    *(float4*)(cstates + ((long)b*16 + t)*256 + j0) = make_float4(h[0],h[1],h[2],h[3]);
  }
}

// ---------------------------------------------------------------------------
// cc concat: ctx = project(madd(madd(mt(mxa,|sf|), mt(mxb,|sb|)), cc_bias)), bf16 out
// ---------------------------------------------------------------------------
__global__ __launch_bounds__(256) void cc_rowwise(const unsigned short* __restrict__ sf,
    const unsigned short* __restrict__ sb, const float* __restrict__ mxa,
    const float* __restrict__ mxb, const float* __restrict__ ccb,
    unsigned short* __restrict__ ctxo, int rowoff)
{
  const int wv = threadIdx.x >> 6, lane = threadIdx.x & 63;
  const int rloc = blockIdx.x*4 + wv;
  const long r = rowoff + rloc;
  float s = 0.f;
#pragma unroll
  for (int i = 0; i < 4; i++){ const float v = bf2f(sf[r*256 + i*64+lane]); s += v*v; }
  const float sfn2 = wred(s);
  s = 0.f;
#pragma unroll
  for (int i = 0; i < 4; i++){ const float v = bf2f(sb[r*256 + i*64+lane]); s += v*v; }
  const float sbn2 = wred(s);
  float A[8], Bv[8];
#pragma unroll
  for (int i = 0; i < 8; i++){ A[i]  = mxa[(long)rloc*512 + i*64+lane];
                               Bv[i] = mxb[(long)rloc*512 + i*64+lane]; }
  float pan2, pbn2;
  { const float n2 = wred(sq_part<8>(A));  mt_project<8>(A,  n2, sfn2, &pan2); }
  { const float n2 = wred(sq_part<8>(Bv)); mt_project<8>(Bv, n2, sbn2, &pbn2); }
  const float xy = wred(dot_part<8>(A, Bv));
  float M1[8]; madd_vec<8>(A, pan2, Bv, pbn2, xy, M1);
  const float m1n2 = wred(sq_part<8>(M1));
  float Cb[8];
#pragma unroll
  for (int i = 0; i < 8; i++) Cb[i] = ccb[i*64+lane];
  const float cb2 = wred(sq_part<8>(Cb));
  const float xyb = wred(dot_part<8>(M1, Cb));
  float M2[8]; madd_vec<8>(M1, m1n2, Cb, cb2, xyb, M2);
  float m2n2 = wred(sq_part<8>(M2));
  project_vec<8>(M2, &m2n2);
#pragma unroll
  for (int i = 0; i < 8; i++) ctxo[r*512 + i*64+lane] = f2bf(M2[i]);
}

// attn_emb = madd(ctx(bf16), pe) -> f32 + sqn
__global__ __launch_bounds__(256) void attn_add(const unsigned short* __restrict__ ctxv,
    const int* __restrict__ pos, const float* __restrict__ pet,
    float* __restrict__ oemb, float* __restrict__ osqn)
{
  const int wv = threadIdx.x >> 6, lane = threadIdx.x & 63;
  const long r = blockIdx.x*4 + wv;
  float X[8];
#pragma unroll
  for (int i = 0; i < 8; i++) X[i] = bf2f(ctxv[r*512 + i*64+lane]);
  const float x2 = wred(sq_part<8>(X));
  const int p = pos[r];
  float Y[8];
#pragma unroll
  for (int i = 0; i < 8; i++) Y[i] = pet[(long)p*512 + i*64+lane];
  const float y2 = wred(sq_part<8>(Y));
  const float xy = wred(dot_part<8>(X, Y));
  float O[8]; madd_vec<8>(X, x2, Y, y2, xy, O);
#pragma unroll
  for (int i = 0; i < 8; i++) oemb[r*512 + i*64+lane] = O[i];
  const float on2 = wred(sq_part<8>(O));
  if (lane == 0) osqn[r] = on2;
}

// mention variant: pos_idx = mentions>0 ? i+1 : 0 ; values f32
__global__ __launch_bounds__(256) void attn_add_m(const float* __restrict__ mvv,
    const int* __restrict__ mentions, const float* __restrict__ pet,
    float* __restrict__ oemb, float* __restrict__ osqn)
{
  const int wv = threadIdx.x >> 6, lane = threadIdx.x & 63;
  const long r = blockIdx.x*4 + wv;
  float X[8];
#pragma unroll
  for (int i = 0; i < 8; i++) X[i] = mvv[r*512 + i*64+lane];
  const float x2 = wred(sq_part<8>(X));
  const int men = mentions[r];
  const int p = (men > 0) ? (int)(r & 7) + 1 : 0;
  float Y[8];
#pragma unroll
  for (int i = 0; i < 8; i++) Y[i] = pet[(long)p*512 + i*64+lane];
  const float y2 = wred(sq_part<8>(Y));
  const float xy = wred(dot_part<8>(X, Y));
  float O[8]; madd_vec<8>(X, x2, Y, y2, xy, O);
#pragma unroll
  for (int i = 0; i < 8; i++) oemb[r*512 + i*64+lane] = O[i];
  const float on2 = wred(sq_part<8>(O));
  if (lane == 0) osqn[r] = on2;
}

// q = project(madd(mt(mxq,|emb|), bq)); k likewise; d = 2*artanh(|madd(-q,k)|)
__global__ __launch_bounds__(256) void qk_pdist(const float* __restrict__ mxq,
    const float* __restrict__ mxk, const float* __restrict__ sqn,
    const float* __restrict__ bq, const float* __restrict__ bk,
    float* __restrict__ dout)
{
  const int wv = threadIdx.x >> 6, lane = threadIdx.x & 63;
  const int r = blockIdx.x*4 + wv;
  const float xn2 = sqn[r];
  float Q[8];
#pragma unroll
  for (int i = 0; i < 8; i++) Q[i] = mxq[(long)r*512 + i*64+lane];
  { const float n2 = wred(sq_part<8>(Q)); float pn2; mt_project<8>(Q, n2, xn2, &pn2);
    float Bq[8];
#pragma unroll
    for (int i = 0; i < 8; i++) Bq[i] = bq[i*64+lane];
    const float b2 = wred(sq_part<8>(Bq));
    const float xy = wred(dot_part<8>(Q, Bq));
    float O[8]; madd_vec<8>(Q, pn2, Bq, b2, xy, O);
#pragma unroll
    for (int i = 0; i < 8; i++) Q[i] = O[i];
  }
  float qn2 = wred(sq_part<8>(Q));
  project_vec<8>(Q, &qn2);
  float Kv[8];
#pragma unroll
  for (int i = 0; i < 8; i++) Kv[i] = mxk[(long)r*512 + i*64+lane];
  { const float n2 = wred(sq_part<8>(Kv)); float pn2; mt_project<8>(Kv, n2, xn2, &pn2);
    float Bk[8];
#pragma unroll
    for (int i = 0; i < 8; i++) Bk[i] = bk[i*64+lane];
    const float b2 = wred(sq_part<8>(Bk));
    const float xy = wred(dot_part<8>(Kv, Bk));
    float O[8]; madd_vec<8>(Kv, pn2, Bk, b2, xy, O);
#pragma unroll
    for (int i = 0; i < 8; i++) Kv[i] = O[i];
  }
  float kn2 = wred(sq_part<8>(Kv));
  project_vec<8>(Kv, &kn2);
  float NQ[8];
#pragma unroll
  for (int i = 0; i < 8; i++) NQ[i] = -Q[i];
  const float xy = wred(dot_part<8>(NQ, Kv));
  float Z[8]; madd_vec<8>(NQ, qn2, Kv, kn2, xy, Z);
  const float zn2 = wred(sq_part<8>(Z));
  const float d = 2.f * atanhf(clamp11(snorm(zn2)));
  if (lane == 0) dout[r] = d;
}

__global__ __launch_bounds__(256) void softmax128(const float* __restrict__ d,
    const float* __restrict__ beta, float* __restrict__ w)
{
  const int wv = threadIdx.x >> 6, lane = threadIdx.x & 63;
  const int b = blockIdx.x*4 + wv;
  const float bt = beta[0];
  const float x0 = -bt * d[b*128 + lane];
  const float x1 = -bt * d[b*128 + 64 + lane];
  const float m = wredmax(fmaxf(x0, x1));
  const float e0 = expf(x0 - m), e1 = expf(x1 - m);
  const float s = wred(e0 + e1);
  w[b*128 + lane]      = e0 / s;
  w[b*128 + 64 + lane] = e1 / s;
}

__global__ void softmax8(const float* __restrict__ d, const float* __restrict__ beta,
                         float* __restrict__ w)
{
  const int b = threadIdx.x;   // 256
  const float bt = beta[0];
  float x[8]; float m = -1e30f;
#pragma unroll
  for (int i = 0; i < 8; i++){ x[i] = -bt * d[b*8+i]; m = fmaxf(m, x[i]); }
  float s = 0.f;
#pragma unroll
  for (int i = 0; i < 8; i++){ x[i] = expf(x[i]-m); s += x[i]; }
#pragma unroll
  for (int i = 0; i < 8; i++) w[b*8+i] = x[i] / s;
}

// weighted gyromidpoint via Klein model; one wave per batch row
template<int NPL, bool BF16V, bool HASW>
__global__ __launch_bounds__(256) void midpoint_kernel(const void* __restrict__ vals,
    const float* __restrict__ wts, float* __restrict__ outp, int Lseq)
{
  const int wv = threadIdx.x >> 6, lane = threadIdx.x & 63;
  const int b = blockIdx.x*4 + wv;
  const int D = NPL*64;
  float num[NPL];
#pragma unroll
  for (int i = 0; i < NPL; i++) num[i] = 0.f;
  float den = 0.f;
  for (int l = 0; l < Lseq; l++){
    const long base = ((long)b*Lseq + l)*D;
    float v[NPL]; float s = 0.f;
#pragma unroll
    for (int i = 0; i < NPL; i++){
      v[i] = BF16V ? bf2f(((const unsigned short*)vals)[base + i*64+lane])
                   : ((const float*)vals)[base + i*64+lane];
      s += v[i]*v[i];
    }
    const float v2 = wred(s);
    const float f = 2.f/(1.f + v2);
    const float kl2 = v2*f*f;
    const float gamma = 1.f/sqrtf(fmaxf(1.f - kl2, EPS_));
    const float wgt = HASW ? wts[b*Lseq + l] : 1.f;
    const float wg = wgt*gamma;
#pragma unroll
    for (int i = 0; i < NPL; i++) num[i] += wg*(f*v[i]);
    den += wg;
  }
  den = fmaxf(den, EPS_);
  float x[NPL]; float s = 0.f;
#pragma unroll
  for (int i = 0; i < NPL; i++){ x[i] = num[i]/den; s += x[i]*x[i]; }
  const float k2 = wred(s);
  const float inv = 1.f/(1.f + sqrtf(fmaxf(1.f - k2, EPS_)));
#pragma unroll
  for (int i = 0; i < NPL; i++) outp[(long)b*D + i*64+lane] = x[i]*inv;
}

// mention w2s mobius_linear with tanh nonlinearity
__global__ __launch_bounds__(256) void mv_rowwise(const float* __restrict__ mx,
    const float* __restrict__ xsqn, const float* __restrict__ bb, float* __restrict__ outp)
{
  const int wv = threadIdx.x >> 6, lane = threadIdx.x & 63;
  const long r = blockIdx.x*4 + wv;
  float M[8];
#pragma unroll
  for (int i = 0; i < 8; i++) M[i] = mx[r*512 + i*64+lane];
  { const float n2 = wred(sq_part<8>(M)); float pn2; mt_project<8>(M, n2, xsqn[r], &pn2);
    float Bv[8];
#pragma unroll
    for (int i = 0; i < 8; i++) Bv[i] = bb[i*64+lane];
    const float b2 = wred(sq_part<8>(Bv));
    const float xy = wred(dot_part<8>(M, Bv));
    float O[8]; madd_vec<8>(M, pn2, Bv, b2, xy, O);
#pragma unroll
    for (int i = 0; i < 8; i++) M[i] = O[i];
  }
  float on2 = wred(sq_part<8>(M));
  project_vec<8>(M, &on2);
  { const float n = snorm(on2);
    const float fac = atanhf(clamp11(n))/n;
#pragma unroll
    for (int i = 0; i < 8; i++) M[i] = tanhf(fac*M[i]); }
  const float un2 = wred(sq_part<8>(M));
  { const float n = snorm(un2);
    const float fac = tanhf(n)/n;
    float en2 = fac*fac*un2;
#pragma unroll
    for (int i = 0; i < 8; i++) M[i] *= fac;
    project_vec<8>(M, &en2); }
#pragma unroll
  for (int i = 0; i < 8; i++) outp[r*512 + i*64+lane] = M[i];
}

// joint = project(madd(madd(madd(mt(jm),mt(jc)),mt(jch)),fc_bias))
__global__ __launch_bounds__(256) void final_rowwise(const float* __restrict__ jm,
    const float* __restrict__ jc, const float* __restrict__ jch,
    const float* __restrict__ mvec, const float* __restrict__ cvec,
    const float* __restrict__ chvec, const float* __restrict__ fcb,
    float* __restrict__ joint)
{
  const int wv = threadIdx.x >> 6, lane = threadIdx.x & 63;
  const long b = blockIdx.x*4 + wv;
  float s;
  s = 0.f; for (int i = 0; i < 8; i++){ const float v = mvec[b*512 + i*64+lane]; s += v*v; }
  const float mn2 = wred(s);
  s = 0.f; for (int i = 0; i < 8; i++){ const float v = cvec[b*512 + i*64+lane]; s += v*v; }
  const float cn2 = wred(s);
  s = 0.f; for (int i = 0; i < 4; i++){ const float v = chvec[b*256 + i*64+lane]; s += v*v; }
  const float chn2 = wred(s);
  float A[20];
#pragma unroll
  for (int i = 0; i < 20; i++) A[i] = jm[b*1280 + i*64+lane];
  float an2;
  { const float n2 = wred(sq_part<20>(A)); mt_project<20>(A, n2, mn2, &an2); }
  float T[20];
#pragma unroll
  for (int i = 0; i < 20; i++) T[i] = jc[b*1280 + i*64+lane];
  float tn2;
  { const float n2 = wred(sq_part<20>(T)); mt_project<20>(T, n2, cn2, &tn2); }
  { const float xy = wred(dot_part<20>(A, T));
    float O[20]; madd_vec<20>(A, an2, T, tn2, xy, O);
#pragma unroll
    for (int i = 0; i < 20; i++) A[i] = O[i];
    an2 = wred(sq_part<20>(A)); }
#pragma unroll
  for (int i = 0; i < 20; i++) T[i] = jch[b*1280 + i*64+lane];
  { const float n2 = wred(sq_part<20>(T)); mt_project<20>(T, n2, chn2, &tn2); }
  { const float xy = wred(dot_part<20>(A, T));
    float O[20]; madd_vec<20>(A, an2, T, tn2, xy, O);
#pragma unroll
    for (int i = 0; i < 20; i++) A[i] = O[i];
    an2 = wred(sq_part<20>(A)); }
#pragma unroll
  for (int i = 0; i < 20; i++) T[i] = fcb[i*64+lane];
  tn2 = wred(sq_part<20>(T));
  { const float xy = wred(dot_part<20>(A, T));
    float O[20]; madd_vec<20>(A, an2, T, tn2, xy, O);
#pragma unroll
    for (int i = 0; i < 20; i++) A[i] = O[i];
    an2 = wred(sq_part<20>(A)); }
  project_vec<20>(A, &an2);
#pragma unroll
  for (int i = 0; i < 20; i++) joint[b*1280 + i*64+lane] = A[i];
}

// hyperbolic MLR head
__global__ __launch_bounds__(256) void mlr_kernel(const float* __restrict__ joint,
    const float* __restrict__ P, const float* __restrict__ A, float* __restrict__ outp)
{
  const int wv = threadIdx.x >> 6, lane = threadIdx.x & 63;
  const int pair = blockIdx.x*4 + wv;
  const long b = pair >> 7, c = pair & 127;
  float Pv[20], J[20];
#pragma unroll
  for (int i = 0; i < 20; i++){
    Pv[i] = -P[c*1280 + i*64+lane];
    J[i]  = joint[b*1280 + i*64+lane];
  }
  const float p2 = wred(sq_part<20>(Pv));
  const float j2 = wred(sq_part<20>(J));
  const float xy = wred(dot_part<20>(Pv, J));
  float Z[20]; madd_vec<20>(Pv, p2, J, j2, xy, Z);
  float sza = 0.f, sz2 = 0.f, sa2 = 0.f;
#pragma unroll
  for (int i = 0; i < 20; i++){
    const float a = A[c*1280 + i*64+lane];
    sza += Z[i]*a; sz2 += Z[i]*Z[i]; sa2 += a*a;
  }
  float za = sza, z2 = sz2, a2 = sa2;
  wred3(za, z2, a2);
  const float an = sqrtf(fmaxf(a2, EPS_));
  const float v = 2.f*za / (fmaxf(1.f - z2, EPS_)*an);
  if (lane == 0) outp[pair] = 2.f*an*asinhf(v);
}

// ---------------------------------------------------------------------------
extern "C" void kernel_launch(void* const* d_in, const int* in_sizes, int n_in,
                              void* d_out, int out_size, void* d_ws, size_t ws_size,
                              hipStream_t stream)
{
  (void)in_sizes; (void)n_in; (void)out_size;
  const int*   context   = (const int*)  d_in[0];
  const int*   ctx_position=(const int*) d_in[1];
  const int*   mentions  = (const int*)  d_in[2];
  const int*   mchars    = (const int*)  d_in[3];
  const float* word_lut  = (const float*)d_in[4];
  const float* char_lut  = (const float*)d_in[5];
  const float* gf_Wih    = (const float*)d_in[6];
  const float* gf_Whh    = (const float*)d_in[7];
  const float* gf_b      = (const float*)d_in[8];
  const float* gb_Wih    = (const float*)d_in[9];
  const float* gb_Whh    = (const float*)d_in[10];
  const float* gb_b      = (const float*)d_in[11];
  const float* w2s_W     = (const float*)d_in[12];
  const float* w2s_b     = (const float*)d_in[13];
  const float* men_pos   = (const float*)d_in[14];
  const float* men_Wq    = (const float*)d_in[15];
  const float* men_bq    = (const float*)d_in[16];
  const float* men_Wk    = (const float*)d_in[17];
  const float* men_bk    = (const float*)d_in[18];
  const float* men_beta  = (const float*)d_in[19];
  const float* char_W    = (const float*)d_in[20];
  const float* char_U    = (const float*)d_in[21];
  const float* char_b    = (const float*)d_in[22];
  const float* cc_Wa     = (const float*)d_in[23];
  const float* cc_Wb     = (const float*)d_in[24];
  const float* cc_bias   = (const float*)d_in[25];
  const float* ctx_pos_t = (const float*)d_in[26];
  const float* ctx_Wq    = (const float*)d_in[27];
  const float* ctx_bq    = (const float*)d_in[28];
  const float* ctx_Wk    = (const float*)d_in[29];
  const float* ctx_bk    = (const float*)d_in[30];
  const float* ctx_beta  = (const float*)d_in[31];
  const float* fc_Wm     = (const float*)d_in[32];
  const float* fc_Wc     = (const float*)d_in[33];
  const float* fc_Wch    = (const float*)d_in[34];
  const float* fc_bias   = (const float*)d_in[35];
  const float* mlr_p     = (const float*)d_in[36];
  const float* mlr_a     = (const float*)d_in[37];
  float* out = (float*)d_out;

  // ---- workspace bump allocator ----
  char* wsb = (char*)d_ws;
  size_t off = 0;
  auto alloc = [&](size_t bytes) -> void* {
    void* p = wsb + off;
    off += (bytes + 255) & ~(size_t)255;
    return p;
  };
  float* WtIH = (float*)alloc(2UL*300*768*4);
  float* WtHH = (float*)alloc(2UL*256*768*4);
  unsigned short* Wrz16 = (unsigned short*)alloc(2UL*256*512*2);  // bf16 (r|z)
  unsigned short* Wh16  = (unsigned short*)alloc(2UL*256*256*2);  // bf16 (h)
  int*   ctxidx = (int*)alloc(32768UL*4);
  int*   chidx  = (int*)alloc(4096UL*4);
  float* xsqn   = (float*)alloc(32768UL*4);
  float* msqn   = (float*)alloc(2048UL*4);
  float* chsqn  = (float*)alloc(4096UL*4);
  unsigned short* xg = (unsigned short*)alloc(2UL*32768*768*2);
  float* xgn2 = (float*)alloc(2UL*32768*3*4);
  float* chn2d = (float*)alloc(4096UL*4);
  unsigned short* states_f = (unsigned short*)alloc(32768UL*256*2);
  unsigned short* states_b = (unsigned short*)alloc(32768UL*256*2);
  unsigned short* ctxv = (unsigned short*)alloc(32768UL*512*2);
  float* attn_sqn = (float*)alloc(32768UL*4);
  float* dctx = (float*)alloc(32768UL*4);
  float* wctx = (float*)alloc(32768UL*4);
  float* ctx_vec = (float*)alloc(256UL*512*4);
  float* mxbuf = (float*)alloc(2UL*8192*512*4);
  float* mv = (float*)alloc(2048UL*512*4);
  float* attn_embm = (float*)alloc(2048UL*512*4);
  float* amsqn = (float*)alloc(2048UL*4);
  float* dm = (float*)alloc(2048UL*4);
  float* wm = (float*)alloc(2048UL*4);
  float* mention_vec = (float*)alloc(256UL*512*4);
  unsigned short* xgc = (unsigned short*)alloc(4096UL*256*2);
  float* char_states = (float*)alloc(4096UL*256*4);
  float* char_vec = (float*)alloc(256UL*256*4);
  float* joint = (float*)alloc(256UL*1280*4);
  if (off > ws_size) return;
  float* attn_embc = (float*)xg;                   // overlay: xg dead after GRU
  float* mxh0 = mxbuf;
  float* mxh1 = mxbuf + 8192UL*512;

  // ---- weight transposes + bf16 split/pack ----
  transpose_k<<<dim3(10,24),256,0,stream>>>(gf_Wih, WtIH,            768, 300);
  transpose_k<<<dim3(10,24),256,0,stream>>>(gb_Wih, WtIH + 300*768,  768, 300);
  transpose_k<<<dim3(8,24), 256,0,stream>>>(gf_Whh, WtHH,            768, 256);
  transpose_k<<<dim3(8,24), 256,0,stream>>>(gb_Whh, WtHH + 256*768,  768, 256);
  pack_whh16<<<1536,256,0,stream>>>(WtHH, Wrz16, Wh16);

  // ---- gather indices + input sqn ----
  build_idx<<<144,256,0,stream>>>(context, mchars, ctxidx, chidx);
  sqn_gather<<<8192,256,0,stream>>>(word_lut, ctxidx, 300, xsqn);
  sqn_gather<<<512, 256,0,stream>>>(word_lut, mentions, 300, msqn);
  sqn_gather<<<1024,256,0,stream>>>(char_lut, chidx, 256, chsqn);

  // ---- GRU input precompute: xg[dir] = mobius_matvec(emb, Wih^T), bf16 ----
  for (int d2 = 0; d2 < 2; d2++){
    const float* wih_t = WtIH + (size_t)d2*300*768;
    for (int c = 0; c < 4; c++){
      mm_kernel<1><<<dim3(6,64),256,0,stream>>>(word_lut, ctxidx + c*8192, wih_t,
                                                mxbuf, 8192, 768, 300);
      xg_transform<<<6144,256,0,stream>>>(mxbuf, xsqn + c*8192,
          xg + ((size_t)d2*32768 + (size_t)c*8192)*768,
          xgn2 + ((size_t)d2*32768 + (size_t)c*8192)*3, 3);
    }
  }

  // ---- bidirectional Mobius GRU (LDS-streamed bf16 weights) ----
  (void)hipFuncSetAttribute((const void*)gru_kernel,
      hipFuncAttributeMaxDynamicSharedMemorySize, GRU_LDS_BYTES);
  gru_kernel<<<128,256,GRU_LDS_BYTES,stream>>>(xg, xgn2, Wrz16, Wh16,
                                               gf_b, gb_b, states_f, states_b);

  // ---- mobius concat of directions -> ctx (bf16) ----
  for (int c = 0; c < 4; c++){
    mm_kernel<2><<<dim3(4,64),256,0,stream>>>(states_f + (size_t)c*8192*256, nullptr,
                                              cc_Wa, mxh0, 8192, 512, 256);
    mm_kernel<2><<<dim3(4,64),256,0,stream>>>(states_b + (size_t)c*8192*256, nullptr,
                                              cc_Wb, mxh1, 8192, 512, 256);
    cc_rowwise<<<2048,256,0,stream>>>(states_f, states_b, mxh0, mxh1, cc_bias,
                                      ctxv, c*8192);
  }

  // ---- context distance attention ----
  attn_add<<<8192,256,0,stream>>>(ctxv, ctx_position, ctx_pos_t, attn_embc, attn_sqn);
  for (int c = 0; c < 4; c++){
    mm_kernel<0><<<dim3(4,64),256,0,stream>>>(attn_embc + (size_t)c*8192*512, nullptr,
                                              ctx_Wq, mxh0, 8192, 512, 512);
    mm_kernel<0><<<dim3(4,64),256,0,stream>>>(attn_embc + (size_t)c*8192*512, nullptr,
                                              ctx_Wk, mxh1, 8192, 512, 512);
    qk_pdist<<<2048,256,0,stream>>>(mxh0, mxh1, attn_sqn + c*8192, ctx_bq, ctx_bk,
                                    dctx + c*8192);
  }
  softmax128<<<64,256,0,stream>>>(dctx, ctx_beta, wctx);
  midpoint_kernel<8,true,true><<<64,256,0,stream>>>(ctxv, wctx, ctx_vec, 128);

  // ---- mention encoder ----
  mm_kernel<1><<<dim3(4,16),256,0,stream>>>(word_lut, mentions, w2s_W, mxh0, 2048, 512, 300);
  mv_rowwise<<<512,256,0,stream>>>(mxh0, msqn, w2s_b, mv);
  attn_add_m<<<512,256,0,stream>>>(mv, mentions, men_pos, attn_embm, amsqn);
  mm_kernel<0><<<dim3(4,16),256,0,stream>>>(attn_embm, nullptr, men_Wq, mxh0, 2048, 512, 512);
  mm_kernel<0><<<dim3(4,16),256,0,stream>>>(attn_embm, nullptr, men_Wk, mxh1, 2048, 512, 512);
  qk_pdist<<<512,256,0,stream>>>(mxh0, mxh1, amsqn, men_bq, men_bk, dm);
  softmax8<<<1,256,0,stream>>>(dm, men_beta, wm);
  midpoint_kernel<8,false,true><<<64,256,0,stream>>>(mv, wm, mention_vec, 8);

  // ---- char encoder ----
  mm_kernel<1><<<dim3(2,32),256,0,stream>>>(char_lut, chidx, char_U, mxh0, 4096, 256, 256);
  xg_transform<<<1024,256,0,stream>>>(mxh0, chsqn, xgc, chn2d, 1);
  char_rnn<<<64,256,0,stream>>>(xgc, char_W, char_b, char_states);
  midpoint_kernel<4,false,false><<<64,256,0,stream>>>(char_states, nullptr, char_vec, 16);

  // ---- full mobius concat + MLR ----
  float* jm = mxh0;
  float* jc = mxh0 + 256UL*1280;
  float* jch = mxh0 + 2UL*256*1280;
  mm_kernel<0><<<dim3(10,2),256,0,stream>>>(mention_vec, nullptr, fc_Wm, jm, 256, 1280, 512);
  mm_kernel<0><<<dim3(10,2),256,0,stream>>>(ctx_vec,     nullptr, fc_Wc, jc, 256, 1280, 512);
  mm_kernel<0><<<dim3(10,2),256,0,stream>>>(char_vec,    nullptr, fc_Wch, jch, 256, 1280, 256);
  final_rowwise<<<64,256,0,stream>>>(jm, jc, jch, mention_vec, ctx_vec, char_vec,
                                     fc_bias, joint);
  mlr_kernel<<<8192,256,0,stream>>>(joint, mlr_p, mlr_a, out);
}

// Round 6
// 4539.734 us; speedup vs baseline: 2.0687x; 1.1384x over previous
//
#include <hip/hip_runtime.h>
#include <cstddef>
#include <cstdint>

// ---------------------------------------------------------------------------
// Hyperbolic (Poincare-ball) entity-typing forward pass, MI355X / gfx950.
// Round 6: GRU v6c — 256 blocks x 2 rows (all CUs), (gate,k)-split FMA roles
// with uint2 (b64) weight reads (3x fewer LDS-read cycles), LDS partial-sum
// buffer; chains identical math to round-5 (passed, absmax 3.8e-6).
// Plus midpoint_wide: 256-block x 8-wave ctx gyromidpoint.
// ---------------------------------------------------------------------------

#define EPS_  1e-15f
#define PMAX_ 0.99999f    // 1 - 1e-5

__device__ __forceinline__ float wred(float v){
#pragma unroll
  for (int o = 32; o; o >>= 1) v += __shfl_xor(v, o, 64);
  return v;
}
__device__ __forceinline__ void wred2(float& a, float& b){
#pragma unroll
  for (int o = 32; o; o >>= 1){ a += __shfl_xor(a, o, 64); b += __shfl_xor(b, o, 64); }
}
__device__ __forceinline__ void wred3(float& a, float& b, float& c){
#pragma unroll
  for (int o = 32; o; o >>= 1){
    a += __shfl_xor(a, o, 64); b += __shfl_xor(b, o, 64); c += __shfl_xor(c, o, 64);
  }
}
__device__ __forceinline__ void wred4(float& a, float& b, float& c, float& d){
#pragma unroll
  for (int o = 32; o; o >>= 1){
    a += __shfl_xor(a, o, 64); b += __shfl_xor(b, o, 64);
    c += __shfl_xor(c, o, 64); d += __shfl_xor(d, o, 64);
  }
}
__device__ __forceinline__ float wredmax(float v){
#pragma unroll
  for (int o = 32; o; o >>= 1) v = fmaxf(v, __shfl_xor(v, o, 64));
  return v;
}
__device__ __forceinline__ float snorm(float s){ return sqrtf(fmaxf(s, EPS_)); }
__device__ __forceinline__ float clamp11(float x){
  return fminf(fmaxf(x, -1.f + 1e-7f), 1.f - 1e-7f);
}
__device__ __forceinline__ float bf2f(unsigned short u){
  union { unsigned int i; float f; } v; v.i = ((unsigned int)u) << 16; return v.f;
}
__device__ __forceinline__ unsigned short f2bf(float f){
  union { float f; unsigned int i; } v; v.f = f;
  unsigned int x = v.i;
  x += 0x7fffu + ((x >> 16) & 1u);   // RNE
  return (unsigned short)(x >> 16);
}
__device__ __forceinline__ float bflo(unsigned u){
  union { unsigned i; float f; } v; v.i = u << 16; return v.f;
}
__device__ __forceinline__ float bfhi(unsigned u){
  union { unsigned i; float f; } v; v.i = u & 0xffff0000u; return v.f;
}

template<int N>
__device__ __forceinline__ float sq_part(const float* a){
  float s = 0.f;
#pragma unroll
  for (int i = 0; i < N; i++) s += a[i]*a[i];
  return s;
}
template<int N>
__device__ __forceinline__ float dot_part(const float* a, const float* b){
  float s = 0.f;
#pragma unroll
  for (int i = 0; i < N; i++) s += a[i]*b[i];
  return s;
}
template<int N>
__device__ __forceinline__ void madd_vec(const float* x, float x2, const float* y,
                                         float y2, float xy, float* o){
  const float c1 = 1.f + 2.f*xy + y2;
  const float c2 = 1.f - x2;
  const float inv = 1.f / fmaxf(1.f + 2.f*xy + x2*y2, EPS_);
#pragma unroll
  for (int i = 0; i < N; i++) o[i] = (c1*x[i] + c2*y[i]) * inv;
}
template<int N>
__device__ __forceinline__ void mt_project(float* v, float mxn2, float xn2, float* n2out){
  const float xn  = snorm(xn2);
  const float mxn = snorm(mxn2);
  const float t   = tanhf(mxn/xn * atanhf(clamp11(xn)));
  float sc = t/mxn;
  float n2 = sc*sc*mxn2;
  const float n = snorm(n2);
  if (n > PMAX_){ const float s = PMAX_/n; sc *= s; n2 *= s*s; }
#pragma unroll
  for (int i = 0; i < N; i++) v[i] *= sc;
  *n2out = n2;
}
__device__ __forceinline__ void mt_scale(float mxn2, float xn, float art,
                                         float* sc, float* n2){
  const float mxn = snorm(mxn2);
  const float t   = tanhf(mxn/xn * art);
  float s  = t/mxn;
  float nn = t*t;
  const float n = snorm(nn);
  if (n > PMAX_){ const float f = PMAX_/n; s *= f; nn *= f*f; }
  *sc = s; *n2 = nn;
}
template<int N>
__device__ __forceinline__ void project_vec(float* v, float* n2io){
  float n2 = *n2io;
  const float n = snorm(n2);
  if (n > PMAX_){
    const float s = PMAX_/n;
#pragma unroll
    for (int i = 0; i < N; i++) v[i] *= s;
    n2 *= s*s;
  }
  *n2io = n2;
}

// async 16B global->LDS: linear wave-uniform-base + lane*16
__device__ __forceinline__ void gll16(const void* g, void* l){
  __builtin_amdgcn_global_load_lds(
      (const __attribute__((address_space(1))) void*)g,
      (__attribute__((address_space(3))) void*)l, 16, 0, 0);
}
// stage 64KB (256 thr x 16 x 16B), linear layout
__device__ __forceinline__ void stage64k(const void* gsrc, float* lbase, int w, int lane){
#pragma unroll
  for (int i = 0; i < 16; i++){
    const char* g = (const char*)gsrc + (size_t)((i*4 + w)*64 + lane)*16;
    char* l = (char*)lbase + (size_t)((i*4 + w)*64)*16;
    gll16(g, l);
  }
}

// ---------------------------------------------------------------------------
// Generic tiled f32 GEMM: C[M,N] = A[M,K] @ B[K,N].
// AMODE: 0 = f32 direct, 1 = f32 row-gathered via idx (A = lut), 2 = bf16 direct.
// ---------------------------------------------------------------------------
template<int AMODE>
__global__ __launch_bounds__(256) void mm_kernel(const void* __restrict__ Aptr,
    const int* __restrict__ idx, const float* __restrict__ Bm,
    float* __restrict__ Cm, int M, int N, int K)
{
  __shared__ __align__(16) float As[8][128];
  __shared__ __align__(16) float Bs[8][132];
  const int tid = threadIdx.x;
  const int n0 = blockIdx.x * 128;
  const int m0 = blockIdx.y * 128;
  const int tr = tid >> 4, tc = tid & 15;
  const int sm = tid & 127, sk = (tid >> 7) * 4;
  const int bk = tid >> 5,  bn = (tid & 31) * 4;
  long arow;
  if constexpr (AMODE == 1) arow = (long)idx[m0 + sm] * K;
  else                      arow = (long)(m0 + sm) * K;
  float acc[8][8];
#pragma unroll
  for (int i = 0; i < 8; i++)
#pragma unroll
    for (int j = 0; j < 8; j++) acc[i][j] = 0.f;

  for (int k0 = 0; k0 < K; k0 += 8){
    float av[4], bv[4];
    if constexpr (AMODE == 2){
      const unsigned short* A = (const unsigned short*)Aptr;
      const ushort4 u = *reinterpret_cast<const ushort4*>(A + arow + k0 + sk);
      av[0]=bf2f(u.x); av[1]=bf2f(u.y); av[2]=bf2f(u.z); av[3]=bf2f(u.w);
    } else {
      const float* A = (const float*)Aptr;
      if (k0 + sk + 3 < K){
        const float4 f = *reinterpret_cast<const float4*>(A + arow + k0 + sk);
        av[0]=f.x; av[1]=f.y; av[2]=f.z; av[3]=f.w;
      } else {
#pragma unroll
        for (int i = 0; i < 4; i++){
          const int kk = k0 + sk + i;
          av[i] = (kk < K) ? A[arow + kk] : 0.f;
        }
      }
    }
    {
      const int kb = k0 + bk;
      if (kb < K){
        const float4 f = *reinterpret_cast<const float4*>(Bm + (long)kb*N + n0 + bn);
        bv[0]=f.x; bv[1]=f.y; bv[2]=f.z; bv[3]=f.w;
      } else { bv[0]=bv[1]=bv[2]=bv[3]=0.f; }
    }
    __syncthreads();
    As[sk+0][sm]=av[0]; As[sk+1][sm]=av[1]; As[sk+2][sm]=av[2]; As[sk+3][sm]=av[3];
    *reinterpret_cast<float4*>(&Bs[bk][bn]) = make_float4(bv[0],bv[1],bv[2],bv[3]);
    __syncthreads();
#pragma unroll
    for (int k = 0; k < 8; k++){
      float a[8], bb[8];
      *(float4*)&a[0]  = *(const float4*)&As[k][tr*8];
      *(float4*)&a[4]  = *(const float4*)&As[k][tr*8+4];
      *(float4*)&bb[0] = *(const float4*)&Bs[k][tc*8];
      *(float4*)&bb[4] = *(const float4*)&Bs[k][tc*8+4];
#pragma unroll
      for (int i = 0; i < 8; i++)
#pragma unroll
        for (int j = 0; j < 8; j++) acc[i][j] += a[i]*bb[j];
    }
  }
#pragma unroll
  for (int i = 0; i < 8; i++){
    const long row = m0 + tr*8 + i;
    *(float4*)(Cm + row*N + n0 + tc*8)     = make_float4(acc[i][0],acc[i][1],acc[i][2],acc[i][3]);
    *(float4*)(Cm + row*N + n0 + tc*8 + 4) = make_float4(acc[i][4],acc[i][5],acc[i][6],acc[i][7]);
  }
}

// ---------------------------------------------------------------------------
// 32x32 LDS-tiled transpose: dst[k*R + j] = src[j*Kc + k]
// ---------------------------------------------------------------------------
__global__ __launch_bounds__(256) void transpose_k(const float* __restrict__ src,
    float* __restrict__ dst, int R, int Kc)
{
  __shared__ float t[32][33];
  const int bx = blockIdx.x * 32;   // k dim
  const int by = blockIdx.y * 32;   // j dim
  const int tx = threadIdx.x & 31, ty = threadIdx.x >> 5;
#pragma unroll
  for (int i = 0; i < 32; i += 8){
    const int j = by + ty + i, k = bx + tx;
    t[ty+i][tx] = (j < R && k < Kc) ? src[(long)j*Kc + k] : 0.f;
  }
  __syncthreads();
#pragma unroll
  for (int i = 0; i < 32; i += 8){
    const int k = bx + ty + i, j = by + tx;
    if (k < Kc && j < R) dst[(long)k*R + j] = t[tx][ty+i];
  }
}

// split+pack WtHH [2][256][768] (r|h|z) f32 -> Wrz16 [2][256][512] (r|z) bf16,
// Wh16 [2][256][256] bf16
__global__ void pack_whh16(const float* __restrict__ WtHH,
                           unsigned short* __restrict__ Wrz16,
                           unsigned short* __restrict__ Wh16)
{
  const int tid = blockIdx.x*256 + threadIdx.x;    // 0 .. 393215
  if (tid < 2*256*768){
    const int col = tid % 768, rk = tid / 768;     // rk = dir*256 + k
    const unsigned short v = f2bf(WtHH[tid]);
    if (col < 256)       Wrz16[(long)rk*512 + col] = v;
    else if (col < 512)  Wh16 [(long)rk*256 + (col - 256)] = v;
    else                 Wrz16[(long)rk*512 + 256 + (col - 512)] = v;
  }
}

// build gather-index arrays: ctxidx[t*256+b]=context[b*128+t]; chidx[t*256+b]=mchars[b*16+t]
__global__ void build_idx(const int* __restrict__ context, const int* __restrict__ mchars,
                          int* __restrict__ ctxidx, int* __restrict__ chidx)
{
  const int tid = blockIdx.x*256 + threadIdx.x;
  if (tid < 32768){
    const int t = tid >> 8, b = tid & 255;
    ctxidx[tid] = context[b*128 + t];
  } else if (tid < 32768 + 4096){
    const int o = tid - 32768;
    const int t = o >> 8, b = o & 255;
    chidx[o] = mchars[b*16 + t];
  }
}

// out[r] = sum_k lut[idx[r]][k]^2   (one wave per row)
__global__ __launch_bounds__(256) void sqn_gather(const float* __restrict__ lut,
    const int* __restrict__ idx, int K, float* __restrict__ outp)
{
  const int wv = threadIdx.x >> 6, lane = threadIdx.x & 63;
  const int r = blockIdx.x*4 + wv;
  const float* row = lut + (long)idx[r]*K;
  float s = 0.f;
  for (int k = lane; k < K; k += 64) s += row[k]*row[k];
  s = wred(s);
  if (lane == 0) outp[r] = s;
}

// mobius_matvec tail transform applied per (row, gate); out bf16 + |out_bf16|^2
__global__ __launch_bounds__(256) void xg_transform(const float* __restrict__ mx,
    const float* __restrict__ xsqn, unsigned short* __restrict__ outp,
    float* __restrict__ n2o, int G)
{
  const int wv = threadIdx.x >> 6, lane = threadIdx.x & 63;
  const int wg = blockIdx.x*4 + wv;
  const int row = wg / G, g = wg - row*G;
  const long base = (long)row*(G*256) + g*256;
  float M[4];
#pragma unroll
  for (int i = 0; i < 4; i++) M[i] = mx[base + i*64 + lane];
  const float mxn2 = wred(sq_part<4>(M));
  float pn2; mt_project<4>(M, mxn2, xsqn[row], &pn2);
  float s = 0.f;
#pragma unroll
  for (int i = 0; i < 4; i++){
    const unsigned short u = f2bf(M[i]);
    outp[base + i*64 + lane] = u;
    const float rv = bf2f(u);
    s += rv*rv;
  }
  s = wred(s);
  if (lane == 0) n2o[wg] = s;
}

// ---------------------------------------------------------------------------
// Mobius GRU v6c: 256 blocks x 256 thr; 2 batch rows/block (all CUs busy).
// BF16 weights streamed L2->LDS via global_load_lds, 64KB chunks (4+2/step).
// Phase1 FMA roles: (gate g=w&1, k-half khf=w>>1); lane owns uint2 = 4 cols.
// Phase2 FMA roles: k-quarter qk=w; lane owns uint2 = 4 cols.
// Partial k-sums through 8KB LDS 'part' buffer.
// Chain roles: gate chain (crow=w>>1, cgate=w&1); update chain w<2 (row=w).
// LDS: wbuf 2x64KB | hs 2K | part 8K | rhb 2K | zb 2K | scal = ~142KB.
// ---------------------------------------------------------------------------
#define GRU_LDS_BYTES 145664

__global__ __launch_bounds__(256,1) void gru_kernel(
    const unsigned short* __restrict__ xg,     // [2][32768][768] bf16
    const float* __restrict__ xgn2,            // [2][32768][3]
    const unsigned short* __restrict__ Wrz16,  // [2][256][512] bf16
    const unsigned short* __restrict__ Wh16,   // [2][256][256] bf16
    const float* __restrict__ bias_f, const float* __restrict__ bias_b,
    unsigned short* __restrict__ states_f, unsigned short* __restrict__ states_b)
{
  extern __shared__ __align__(16) char smem[];
  float* wbuf = (float*)smem;                    // 2 x 16384 f32 slots (64KB each)
  float* hs   = (float*)(smem + 131072);         // [2][256]
  float* part = (float*)(smem + 133120);         // 2048 floats (8KB)
  float* rhb  = (float*)(smem + 141312);         // [2][256]
  float* zb   = (float*)(smem + 143360);         // [2][256]
  float* scal = (float*)(smem + 145408);         // [2][2]

  const int bid = blockIdx.x;                    // 0..255
  const int dir = bid >> 7;
  const int brow0 = (bid & 127) * 2;
  const int tid = threadIdx.x;
  const int w = tid >> 6, lane = tid & 63;
  const int j0 = lane << 2;

  const unsigned short* xgd = xg + (long)dir*32768*768;
  const float* xnd = xgn2 + (long)dir*32768*3;
  const unsigned short* wrz_d = Wrz16 + (long)dir*256*512;
  const unsigned short* wh_d  = Wh16  + (long)dir*256*256;
  const float* bias = dir ? bias_b : bias_f;
  unsigned short* states = dir ? states_b : states_f;

  // FMA roles
  const int fg  = w & 1;             // phase1 gate (0=r cols 0..255, 1=z)
  const int khf = w >> 1;            // phase1 k-half within 64-k chunk
  const int qk  = w;                 // phase2 k-quarter within 128-k chunk
  // chain roles
  const int crow  = w >> 1;          // gate-chain row
  const int cgate = w & 1;           // gate-chain gate (0=r, 1=z)

  float bg[4], bh4[4] = {0,0,0,0};
  float bg2, bh2 = 0.f;
#pragma unroll
  for (int i = 0; i < 4; i++) bg[i] = bias[(cgate ? 512 : 0) + j0 + i];
  bg2 = wred(sq_part<4>(bg));
  if (w < 2){
#pragma unroll
    for (int i = 0; i < 4; i++) bh4[i] = bias[256 + j0 + i];
    bh2 = wred(sq_part<4>(bh4));
  }

  float h[4] = {0.f,0.f,0.f,0.f};    // update-wave register state (w<2)
  float hn2 = 0.f;
  if (w < 2){
#pragma unroll
    for (int i = 0; i < 4; i++) hs[w*256 + j0 + i] = 0.f;
    if (lane == 0){ scal[w*2 + 0] = 0.f; scal[w*2 + 1] = 0.f; }
  }

  int cb = 0;
  stage64k(wrz_d, wbuf, w, lane);    // Wrz chunk 0 -> buf 0

  for (int t = 0; t < 128; t++){
    const int tt = dir ? (127 - t) : t;
    // ---- role input loads (prefetched before FMA walls) ----
    float xgv[4], y2g, xgh4[4] = {0,0,0,0}, y2h = 0.f;
    {
      const long rxg = (long)tt*256 + brow0 + crow;
      const ushort4 u = *(const ushort4*)(xgd + rxg*768 + (cgate ? 512 : 0) + j0);
      xgv[0]=bf2f(u.x); xgv[1]=bf2f(u.y); xgv[2]=bf2f(u.z); xgv[3]=bf2f(u.w);
      y2g = xnd[rxg*3 + (cgate ? 2 : 0)];
      if (w < 2){
        const long rxh = (long)tt*256 + brow0 + w;
        const ushort4 uh = *(const ushort4*)(xgd + rxh*768 + 256 + j0);
        xgh4[0]=bf2f(uh.x); xgh4[1]=bf2f(uh.y); xgh4[2]=bf2f(uh.z); xgh4[3]=bf2f(uh.w);
        y2h = xnd[rxh*3 + 1];
      }
    }

    // ===== phase 1: r/z matvec, 4 chunks of [64 k][512 cols] bf16 =====
    float s00=0.f,s01=0.f,s02=0.f,s03=0.f, s10=0.f,s11=0.f,s12=0.f,s13=0.f;
#pragma unroll 1
    for (int c = 0; c < 4; c++){
      __syncthreads();                          // chunk c landed, other buf free
      if (c < 3) stage64k((const char*)wrz_d + (size_t)(c+1)*65536,
                          wbuf + (cb^1)*16384, w, lane);
      const uint2* wb2 = (const uint2*)(wbuf + cb*16384);  // [64][128] uint2
      const int kb = c*64 + khf*32;
#pragma unroll
      for (int kq = 0; kq < 8; kq++){
        const float4 hb0 = *(const float4*)&hs[0*256 + kb + kq*4];
        const float4 hb1 = *(const float4*)&hs[1*256 + kb + kq*4];
#pragma unroll
        for (int q = 0; q < 4; q++){
          const uint2 wv = wb2[(khf*32 + kq*4 + q)*128 + fg*64 + lane];
          const float w0 = bflo(wv.x), w1 = bfhi(wv.x);
          const float w2 = bflo(wv.y), w3 = bfhi(wv.y);
          const float h0 = (&hb0.x)[q], h1 = (&hb1.x)[q];
          s00 += h0*w0; s01 += h0*w1; s02 += h0*w2; s03 += h0*w3;
          s10 += h1*w0; s11 += h1*w1; s12 += h1*w2; s13 += h1*w3;
        }
      }
      cb ^= 1;
    }
    {
      // part1 layout: [kh][row][512]; col = fg*256 + lane*4
      float* p1 = part + khf*1024 + fg*256 + j0;
      *(float4*)p1         = make_float4(s00,s01,s02,s03);
      *(float4*)(p1 + 512) = make_float4(s10,s11,s12,s13);
    }
    __syncthreads();                            // B_a: partials visible
    stage64k(wh_d, wbuf + (cb^1)*16384, w, lane);   // prefetch Wh chunk0
    cb ^= 1;

    // ===== gate chain: 4 waves, role (crow, cgate) =====
    {
      const float* pa = part + crow*512 + cgate*256 + j0;
      const float4 a0 = *(const float4*)pa;            // kh0 partial
      const float4 a1 = *(const float4*)(pa + 1024);   // kh1 partial
      float a[4] = { a0.x+a1.x, a0.y+a1.y, a0.z+a1.z, a0.w+a1.w };
      const float hn2v = scal[crow*2 + 0];
      const float xn_h = snorm(hn2v), art_h = atanhf(clamp11(xn_h));
      const float p2 = wred(sq_part<4>(a));
      float sc, n2; mt_scale(p2, xn_h, art_h, &sc, &n2);
#pragma unroll
      for (int i = 0; i < 4; i++) a[i] *= sc;
      const float xy = wred(dot_part<4>(a, xgv));
      float m1[4]; madd_vec<4>(a, n2, xgv, y2g, xy, m1);
      float m1n2 = sq_part<4>(m1), xyb = dot_part<4>(m1, bg);
      wred2(m1n2, xyb);
      float m2[4]; madd_vec<4>(m1, m1n2, bg, bg2, xyb, m2);
      const float m2n2 = wred(sq_part<4>(m2));
      const float nn = snorm(m2n2), fgc = atanhf(clamp11(nn))/nn;
      float g4[4];
#pragma unroll
      for (int i = 0; i < 4; i++) g4[i] = 1.f/(1.f + expf(-fgc*m2[i]));
      if (cgate == 0){                          // r-gate: compute rh = pwmul(r,h)
        float h4[4];
        *(float4*)h4 = *(const float4*)&hs[crow*256 + j0];
        float rh[4]; float wx2 = 0.f;
#pragma unroll
        for (int i = 0; i < 4; i++){ rh[i] = g4[i]*h4[i]; wx2 += rh[i]*rh[i]; }
        wx2 = wred(wx2);
        float rhn2, scrh;
        {
          const float wxn = snorm(wx2);
          const float trh = tanhf(wxn/xn_h * art_h);
          scrh = trh/wxn; rhn2 = trh*trh;
          const float n = snorm(rhn2);
          if (n > PMAX_){ const float f = PMAX_/n; scrh *= f; rhn2 *= f*f; }
        }
#pragma unroll
        for (int i = 0; i < 4; i++) rh[i] *= scrh;
        *(float4*)&rhb[crow*256 + j0] = make_float4(rh[0],rh[1],rh[2],rh[3]);
        if (lane == 0) scal[crow*2 + 1] = rhn2;
      } else {                                  // z-gate: publish z
        *(float4*)&zb[crow*256 + j0] = make_float4(g4[0],g4[1],g4[2],g4[3]);
      }
    }

    // ===== phase 2: h-gate matvec, 2 chunks of [128 k][256 cols] bf16 =====
    float r00=0.f,r01=0.f,r02=0.f,r03=0.f, r10=0.f,r11=0.f,r12=0.f,r13=0.f;
#pragma unroll 1
    for (int c = 0; c < 2; c++){
      __syncthreads();                          // c==0: rhb/zb ready + chunk landed
      if (c < 1) stage64k((const char*)wh_d + 65536, wbuf + (cb^1)*16384, w, lane);
      const uint2* wb2 = (const uint2*)(wbuf + cb*16384);  // [128][64] uint2
      const int kb = c*128 + qk*32;
#pragma unroll
      for (int kq = 0; kq < 8; kq++){
        const float4 hb0 = *(const float4*)&rhb[0*256 + kb + kq*4];
        const float4 hb1 = *(const float4*)&rhb[1*256 + kb + kq*4];
#pragma unroll
        for (int q = 0; q < 4; q++){
          const uint2 wv = wb2[(qk*32 + kq*4 + q)*64 + lane];
          const float w0 = bflo(wv.x), w1 = bfhi(wv.x);
          const float w2 = bflo(wv.y), w3 = bfhi(wv.y);
          const float h0 = (&hb0.x)[q], h1 = (&hb1.x)[q];
          r00 += h0*w0; r01 += h0*w1; r02 += h0*w2; r03 += h0*w3;
          r10 += h1*w0; r11 += h1*w1; r12 += h1*w2; r13 += h1*w3;
        }
      }
      cb ^= 1;
    }
    {
      // part2 layout: [q][row][256]
      float* p2 = part + qk*512 + j0;
      *(float4*)p2         = make_float4(r00,r01,r02,r03);
      *(float4*)(p2 + 256) = make_float4(r10,r11,r12,r13);
    }
    __syncthreads();                            // B_c
    if (t < 127){                               // prefetch next step's Wrz chunk0
      stage64k(wrz_d, wbuf + (cb^1)*16384, w, lane);
      cb ^= 1;
    }

    // ===== h-update chain: 2 waves, row = w =====
    if (w < 2){
      float ah[4];
      {
        const float4 p0 = *(const float4*)(part + 0*512 + w*256 + j0);
        const float4 p1 = *(const float4*)(part + 1*512 + w*256 + j0);
        const float4 p2 = *(const float4*)(part + 2*512 + w*256 + j0);
        const float4 p3 = *(const float4*)(part + 3*512 + w*256 + j0);
        ah[0] = (p0.x+p1.x)+(p2.x+p3.x);
        ah[1] = (p0.y+p1.y)+(p2.y+p3.y);
        ah[2] = (p0.z+p1.z)+(p2.z+p3.z);
        ah[3] = (p0.w+p1.w)+(p2.w+p3.w);
      }
      const float rhn2v = scal[w*2 + 1];
      const float rxn = snorm(rhn2v), artr = atanhf(clamp11(rxn));
      float mx2 = sq_part<4>(ah), xyraw = dot_part<4>(ah, xgh4);
      wred2(mx2, xyraw);
      float sch, pn2; mt_scale(mx2, rxn, artr, &sch, &pn2);
#pragma unroll
      for (int i = 0; i < 4; i++) ah[i] *= sch;
      const float xy = xyraw * sch;
      float m1[4]; madd_vec<4>(ah, pn2, xgh4, y2h, xy, m1);
      float m1n2 = sq_part<4>(m1), xyb = dot_part<4>(m1, bh4);
      wred2(m1n2, xyb);
      float ht[4]; madd_vec<4>(m1, m1n2, bh4, bh2, xyb, ht);
      float htn2 = sq_part<4>(ht);
      float nh[4];
#pragma unroll
      for (int i = 0; i < 4; i++) nh[i] = -h[i];
      float xyd = dot_part<4>(nh, ht);
      wred2(htn2, xyd);
      float dl[4]; madd_vec<4>(nh, hn2, ht, htn2, xyd, dl);
      float z4[4];
      *(float4*)z4 = *(const float4*)&zb[w*256 + j0];
      float pw[4]; float dln2 = 0.f, wz2 = 0.f, xyhr = 0.f;
#pragma unroll
      for (int i = 0; i < 4; i++){
        dln2 += dl[i]*dl[i];
        pw[i] = z4[i]*dl[i];
        wz2  += pw[i]*pw[i];
        xyhr += h[i]*pw[i];
      }
      wred3(dln2, wz2, xyhr);
      float pwn2, scpw;
      {
        const float dn   = snorm(dln2);
        const float artd = atanhf(clamp11(dn));
        const float wzn  = snorm(wz2);
        const float tpw  = tanhf(wzn/dn * artd);
        scpw = tpw/wzn; pwn2 = tpw*tpw;
        const float n = snorm(pwn2);
        if (n > PMAX_){ const float f = PMAX_/n; scpw *= f; pwn2 *= f*f; }
      }
#pragma unroll
      for (int i = 0; i < 4; i++) pw[i] *= scpw;
      const float xyh = xyhr * scpw;
      float hnew[4]; madd_vec<4>(h, hn2, pw, pwn2, xyh, hnew);
#pragma unroll
      for (int i = 0; i < 4; i++) h[i] = hnew[i];
      hn2 = wred(sq_part<4>(h));
      *(float4*)&hs[w*256 + j0] = make_float4(h[0],h[1],h[2],h[3]);
      if (lane == 0) scal[w*2 + 0] = hn2;
      unsigned short* srow = states + ((long)(brow0 + w)*128 + tt)*256 + j0;
      ushort4 su; su.x=f2bf(h[0]); su.y=f2bf(h[1]); su.z=f2bf(h[2]); su.w=f2bf(h[3]);
      *(ushort4*)srow = su;
    }
    // next iteration's first __syncthreads orders hs/scal writes vs reads
  }
}

// ---------------------------------------------------------------------------
// Char Mobius-RNN: h = project(madd(madd(matvec(h, W), xg), b)), 16 steps.
// ---------------------------------------------------------------------------
__global__ __launch_bounds__(256) void char_rnn(
    const unsigned short* __restrict__ xgc,
    const float* __restrict__ Wc,
    const float* __restrict__ cb,
    float* __restrict__ cstates)
{
  const int wv = threadIdx.x >> 6, lane = threadIdx.x & 63;
  const int b = blockIdx.x*4 + wv;
  const int j0 = lane << 2;
  __shared__ __align__(16) float hs[4][256];
  float h[4] = {0.f,0.f,0.f,0.f};
  float hn2 = 0.f;
#pragma unroll
  for (int i = 0; i < 4; i++) hs[wv][j0+i] = 0.f;
  float cbv[4];
#pragma unroll
  for (int i = 0; i < 4; i++) cbv[i] = cb[j0+i];
  const float cb2 = wred(sq_part<4>(cbv));
  for (int t = 0; t < 16; t++){
    __syncthreads();
    const unsigned short* xr = xgc + ((long)t*256 + b)*256;
    float xgv[4];
    { const ushort4 u = *(const ushort4*)(xr + j0); xgv[0]=bf2f(u.x); xgv[1]=bf2f(u.y); xgv[2]=bf2f(u.z); xgv[3]=bf2f(u.w); }
    float a[4]={0.f,0.f,0.f,0.f};
#pragma unroll 2
    for (int k0 = 0; k0 < 256; k0 += 4){
      const float4 hk = *(const float4*)&hs[wv][k0];
#pragma unroll
      for (int kk = 0; kk < 4; kk++){
        const float hv = (&hk.x)[kk];
        const float4 w4 = *(const float4*)(Wc + (long)(k0+kk)*256 + j0);
        a[0] += hv*w4.x; a[1] += hv*w4.y; a[2] += hv*w4.z; a[3] += hv*w4.w;
      }
    }
    const float mxn2 = wred(sq_part<4>(a));
    float pn2; mt_project<4>(a, mxn2, hn2, &pn2);
    const float y2 = wred(sq_part<4>(xgv));
    const float xy = wred(dot_part<4>(a, xgv));
    float m1[4]; madd_vec<4>(a, pn2, xgv, y2, xy, m1);
    const float m1n2 = wred(sq_part<4>(m1));
    const float xyb  = wred(dot_part<4>(m1, cbv));
    float m2[4]; madd_vec<4>(m1, m1n2, cbv, cb2, xyb, m2);
    float m2n2 = wred(sq_part<4>(m2));
    project_vec<4>(m2, &m2n2);
#pragma unroll
    for (int i = 0; i < 4; i++) h[i] = m2[i];
    hn2 = m2n2;
    *(float4*)&hs[wv][j0] = make_float4(h[0],h[1],h[2],h[3]);
    *(float4*)(cstates + ((long)b*16 + t)*256 + j0) = make_float4(h[0],h[1],h[2],h[3]);
  }
}

// ---------------------------------------------------------------------------
// cc concat: ctx = project(madd(madd(mt(mxa,|sf|), mt(mxb,|sb|)), cc_bias)), bf16 out
// ---------------------------------------------------------------------------
__global__ __launch_bounds__(256) void cc_rowwise(const unsigned short* __restrict__ sf,
    const unsigned short* __restrict__ sb, const float* __restrict__ mxa,
    const float* __restrict__ mxb, const float* __restrict__ ccb,
    unsigned short* __restrict__ ctxo, int rowoff)
{
  const int wv = threadIdx.x >> 6, lane = threadIdx.x & 63;
  const int rloc = blockIdx.x*4 + wv;
  const long r = rowoff + rloc;
  float s = 0.f;
#pragma unroll
  for (int i = 0; i < 4; i++){ const float v = bf2f(sf[r*256 + i*64+lane]); s += v*v; }
  const float sfn2 = wred(s);
  s = 0.f;
#pragma unroll
  for (int i = 0; i < 4; i++){ const float v = bf2f(sb[r*256 + i*64+lane]); s += v*v; }
  const float sbn2 = wred(s);
  float A[8], Bv[8];
#pragma unroll
  for (int i = 0; i < 8; i++){ A[i]  = mxa[(long)rloc*512 + i*64+lane];
                               Bv[i] = mxb[(long)rloc*512 + i*64+lane]; }
  float pan2, pbn2;
  { const float n2 = wred(sq_part<8>(A));  mt_project<8>(A,  n2, sfn2, &pan2); }
  { const float n2 = wred(sq_part<8>(Bv)); mt_project<8>(Bv, n2, sbn2, &pbn2); }
  const float xy = wred(dot_part<8>(A, Bv));
  float M1[8]; madd_vec<8>(A, pan2, Bv, pbn2, xy, M1);
  const float m1n2 = wred(sq_part<8>(M1));
  float Cb[8];
#pragma unroll
  for (int i = 0; i < 8; i++) Cb[i] = ccb[i*64+lane];
  const float cb2 = wred(sq_part<8>(Cb));
  const float xyb = wred(dot_part<8>(M1, Cb));
  float M2[8]; madd_vec<8>(M1, m1n2, Cb, cb2, xyb, M2);
  float m2n2 = wred(sq_part<8>(M2));
  project_vec<8>(M2, &m2n2);
#pragma unroll
  for (int i = 0; i < 8; i++) ctxo[r*512 + i*64+lane] = f2bf(M2[i]);
}

// attn_emb = madd(ctx(bf16), pe) -> f32 + sqn
__global__ __launch_bounds__(256) void attn_add(const unsigned short* __restrict__ ctxv,
    const int* __restrict__ pos, const float* __restrict__ pet,
    float* __restrict__ oemb, float* __restrict__ osqn)
{
  const int wv = threadIdx.x >> 6, lane = threadIdx.x & 63;
  const long r = blockIdx.x*4 + wv;
  float X[8];
#pragma unroll
  for (int i = 0; i < 8; i++) X[i] = bf2f(ctxv[r*512 + i*64+lane]);
  const float x2 = wred(sq_part<8>(X));
  const int p = pos[r];
  float Y[8];
#pragma unroll
  for (int i = 0; i < 8; i++) Y[i] = pet[(long)p*512 + i*64+lane];
  const float y2 = wred(sq_part<8>(Y));
  const float xy = wred(dot_part<8>(X, Y));
  float O[8]; madd_vec<8>(X, x2, Y, y2, xy, O);
#pragma unroll
  for (int i = 0; i < 8; i++) oemb[r*512 + i*64+lane] = O[i];
  const float on2 = wred(sq_part<8>(O));
  if (lane == 0) osqn[r] = on2;
}

// mention variant: pos_idx = mentions>0 ? i+1 : 0 ; values f32
__global__ __launch_bounds__(256) void attn_add_m(const float* __restrict__ mvv,
    const int* __restrict__ mentions, const float* __restrict__ pet,
    float* __restrict__ oemb, float* __restrict__ osqn)
{
  const int wv = threadIdx.x >> 6, lane = threadIdx.x & 63;
  const long r = blockIdx.x*4 + wv;
  float X[8];
#pragma unroll
  for (int i = 0; i < 8; i++) X[i] = mvv[r*512 + i*64+lane];
  const float x2 = wred(sq_part<8>(X));
  const int men = mentions[r];
  const int p = (men > 0) ? (int)(r & 7) + 1 : 0;
  float Y[8];
#pragma unroll
  for (int i = 0; i < 8; i++) Y[i] = pet[(long)p*512 + i*64+lane];
  const float y2 = wred(sq_part<8>(Y));
  const float xy = wred(dot_part<8>(X, Y));
  float O[8]; madd_vec<8>(X, x2, Y, y2, xy, O);
#pragma unroll
  for (int i = 0; i < 8; i++) oemb[r*512 + i*64+lane] = O[i];
  const float on2 = wred(sq_part<8>(O));
  if (lane == 0) osqn[r] = on2;
}

// q = project(madd(mt(mxq,|emb|), bq)); k likewise; d = 2*artanh(|madd(-q,k)|)
__global__ __launch_bounds__(256) void qk_pdist(const float* __restrict__ mxq,
    const float* __restrict__ mxk, const float* __restrict__ sqn,
    const float* __restrict__ bq, const float* __restrict__ bk,
    float* __restrict__ dout)
{
  const int wv = threadIdx.x >> 6, lane = threadIdx.x & 63;
  const int r = blockIdx.x*4 + wv;
  const float xn2 = sqn[r];
  float Q[8];
#pragma unroll
  for (int i = 0; i < 8; i++) Q[i] = mxq[(long)r*512 + i*64+lane];
  { const float n2 = wred(sq_part<8>(Q)); float pn2; mt_project<8>(Q, n2, xn2, &pn2);
    float Bq[8];
#pragma unroll
    for (int i = 0; i < 8; i++) Bq[i] = bq[i*64+lane];
    const float b2 = wred(sq_part<8>(Bq));
    const float xy = wred(dot_part<8>(Q, Bq));
    float O[8]; madd_vec<8>(Q, pn2, Bq, b2, xy, O);
#pragma unroll
    for (int i = 0; i < 8; i++) Q[i] = O[i];
  }
  float qn2 = wred(sq_part<8>(Q));
  project_vec<8>(Q, &qn2);
  float Kv[8];
#pragma unroll
  for (int i = 0; i < 8; i++) Kv[i] = mxk[(long)r*512 + i*64+lane];
  { const float n2 = wred(sq_part<8>(Kv)); float pn2; mt_project<8>(Kv, n2, xn2, &pn2);
    float Bk[8];
#pragma unroll
    for (int i = 0; i < 8; i++) Bk[i] = bk[i*64+lane];
    const float b2 = wred(sq_part<8>(Bk));
    const float xy = wred(dot_part<8>(Kv, Bk));
    float O[8]; madd_vec<8>(Kv, pn2, Bk, b2, xy, O);
#pragma unroll
    for (int i = 0; i < 8; i++) Kv[i] = O[i];
  }
  float kn2 = wred(sq_part<8>(Kv));
  project_vec<8>(Kv, &kn2);
  float NQ[8];
#pragma unroll
  for (int i = 0; i < 8; i++) NQ[i] = -Q[i];
  const float xy = wred(dot_part<8>(NQ, Kv));
  float Z[8]; madd_vec<8>(NQ, qn2, Kv, kn2, xy, Z);
  const float zn2 = wred(sq_part<8>(Z));
  const float d = 2.f * atanhf(clamp11(snorm(zn2)));
  if (lane == 0) dout[r] = d;
}

__global__ __launch_bounds__(256) void softmax128(const float* __restrict__ d,
    const float* __restrict__ beta, float* __restrict__ w)
{
  const int wv = threadIdx.x >> 6, lane = threadIdx.x & 63;
  const int b = blockIdx.x*4 + wv;
  const float bt = beta[0];
  const float x0 = -bt * d[b*128 + lane];
  const float x1 = -bt * d[b*128 + 64 + lane];
  const float m = wredmax(fmaxf(x0, x1));
  const float e0 = expf(x0 - m), e1 = expf(x1 - m);
  const float s = wred(e0 + e1);
  w[b*128 + lane]      = e0 / s;
  w[b*128 + 64 + lane] = e1 / s;
}

__global__ void softmax8(const float* __restrict__ d, const float* __restrict__ beta,
                         float* __restrict__ w)
{
  const int b = threadIdx.x;   // 256
  const float bt = beta[0];
  float x[8]; float m = -1e30f;
#pragma unroll
  for (int i = 0; i < 8; i++){ x[i] = -bt * d[b*8+i]; m = fmaxf(m, x[i]); }
  float s = 0.f;
#pragma unroll
  for (int i = 0; i < 8; i++){ x[i] = expf(x[i]-m); s += x[i]; }
#pragma unroll
  for (int i = 0; i < 8; i++) w[b*8+i] = x[i] / s;
}

// weighted gyromidpoint via Klein model; one wave per batch row (small Lseq)
template<int NPL, bool BF16V, bool HASW>
__global__ __launch_bounds__(256) void midpoint_kernel(const void* __restrict__ vals,
    const float* __restrict__ wts, float* __restrict__ outp, int Lseq)
{
  const int wv = threadIdx.x >> 6, lane = threadIdx.x & 63;
  const int b = blockIdx.x*4 + wv;
  const int D = NPL*64;
  float num[NPL];
#pragma unroll
  for (int i = 0; i < NPL; i++) num[i] = 0.f;
  float den = 0.f;
  for (int l = 0; l < Lseq; l++){
    const long base = ((long)b*Lseq + l)*D;
    float v[NPL]; float s = 0.f;
#pragma unroll
    for (int i = 0; i < NPL; i++){
      v[i] = BF16V ? bf2f(((const unsigned short*)vals)[base + i*64+lane])
                   : ((const float*)vals)[base + i*64+lane];
      s += v[i]*v[i];
    }
    const float v2 = wred(s);
    const float f = 2.f/(1.f + v2);
    const float kl2 = v2*f*f;
    const float gamma = 1.f/sqrtf(fmaxf(1.f - kl2, EPS_));
    const float wgt = HASW ? wts[b*Lseq + l] : 1.f;
    const float wg = wgt*gamma;
#pragma unroll
    for (int i = 0; i < NPL; i++) num[i] += wg*(f*v[i]);
    den += wg;
  }
  den = fmaxf(den, EPS_);
  float x[NPL]; float s = 0.f;
#pragma unroll
  for (int i = 0; i < NPL; i++){ x[i] = num[i]/den; s += x[i]*x[i]; }
  const float k2 = wred(s);
  const float inv = 1.f/(1.f + sqrtf(fmaxf(1.f - k2, EPS_)));
#pragma unroll
  for (int i = 0; i < NPL; i++) outp[(long)b*D + i*64+lane] = x[i]*inv;
}

// wide gyromidpoint for ctx: 1 block (512 thr, 8 waves) per batch row, L=128, D=512
__global__ __launch_bounds__(512) void midpoint_wide(
    const unsigned short* __restrict__ vals,  // [256][128][512] bf16
    const float* __restrict__ wts,            // [256][128]
    float* __restrict__ outp)                 // [256][512]
{
  __shared__ float pnum[8][512];
  __shared__ float pden[8];
  __shared__ float red[512];
  __shared__ float kk2[1];
  const int b = blockIdx.x;
  const int tid = threadIdx.x;
  const int w = tid >> 6, lane = tid & 63;
  float num[8] = {0.f,0.f,0.f,0.f,0.f,0.f,0.f,0.f};
  float den = 0.f;
  for (int l = w; l < 128; l += 8){
    const long base = ((long)b*128 + l)*512;
    float v[8]; float s = 0.f;
#pragma unroll
    for (int i = 0; i < 8; i++){
      v[i] = bf2f(vals[base + i*64 + lane]);
      s += v[i]*v[i];
    }
    const float v2 = wred(s);
    const float f = 2.f/(1.f + v2);
    const float kl2 = v2*f*f;
    const float gamma = 1.f/sqrtf(fmaxf(1.f - kl2, EPS_));
    const float wg = wts[b*128 + l]*gamma;
#pragma unroll
    for (int i = 0; i < 8; i++) num[i] += wg*(f*v[i]);
    den += wg;
  }
#pragma unroll
  for (int i = 0; i < 8; i++) pnum[w][i*64 + lane] = num[i];
  if (lane == 0) pden[w] = den;
  __syncthreads();
  float nsum = 0.f, dsum = 0.f;
#pragma unroll
  for (int p = 0; p < 8; p++){ nsum += pnum[p][tid]; dsum += pden[p]; }
  dsum = fmaxf(dsum, EPS_);
  const float x = nsum/dsum;
  red[tid] = x*x;
  __syncthreads();
  if (tid < 64){
    float s2 = 0.f;
#pragma unroll
    for (int i = 0; i < 8; i++) s2 += red[tid + i*64];
    s2 = wred(s2);
    if (tid == 0) kk2[0] = s2;
  }
  __syncthreads();
  const float k2 = kk2[0];
  const float inv = 1.f/(1.f + sqrtf(fmaxf(1.f - k2, EPS_)));
  outp[(long)b*512 + tid] = x*inv;
}

// mention w2s mobius_linear with tanh nonlinearity
__global__ __launch_bounds__(256) void mv_rowwise(const float* __restrict__ mx,
    const float* __restrict__ xsqn, const float* __restrict__ bb, float* __restrict__ outp)
{
  const int wv = threadIdx.x >> 6, lane = threadIdx.x & 63;
  const long r = blockIdx.x*4 + wv;
  float M[8];
#pragma unroll
  for (int i = 0; i < 8; i++) M[i] = mx[r*512 + i*64+lane];
  { const float n2 = wred(sq_part<8>(M)); float pn2; mt_project<8>(M, n2, xsqn[r], &pn2);
    float Bv[8];
#pragma unroll
    for (int i = 0; i < 8; i++) Bv[i] = bb[i*64+lane];
    const float b2 = wred(sq_part<8>(Bv));
    const float xy = wred(dot_part<8>(M, Bv));
    float O[8]; madd_vec<8>(M, pn2, Bv, b2, xy, O);
#pragma unroll
    for (int i = 0; i < 8; i++) M[i] = O[i];
  }
  float on2 = wred(sq_part<8>(M));
  project_vec<8>(M, &on2);
  { const float n = snorm(on2);
    const float fac = atanhf(clamp11(n))/n;
#pragma unroll
    for (int i = 0; i < 8; i++) M[i] = tanhf(fac*M[i]); }
  const float un2 = wred(sq_part<8>(M));
  { const float n = snorm(un2);
    const float fac = tanhf(n)/n;
    float en2 = fac*fac*un2;
#pragma unroll
    for (int i = 0; i < 8; i++) M[i] *= fac;
    project_vec<8>(M, &en2); }
#pragma unroll
  for (int i = 0; i < 8; i++) outp[r*512 + i*64+lane] = M[i];
}

// joint = project(madd(madd(madd(mt(jm),mt(jc)),mt(jch)),fc_bias))
__global__ __launch_bounds__(256) void final_rowwise(const float* __restrict__ jm,
    const float* __restrict__ jc, const float* __restrict__ jch,
    const float* __restrict__ mvec, const float* __restrict__ cvec,
    const float* __restrict__ chvec, const float* __restrict__ fcb,
    float* __restrict__ joint)
{
  const int wv = threadIdx.x >> 6, lane = threadIdx.x & 63;
  const long b = blockIdx.x*4 + wv;
  float s;
  s = 0.f; for (int i = 0; i < 8; i++){ const float v = mvec[b*512 + i*64+lane]; s += v*v; }
  const float mn2 = wred(s);
  s = 0.f; for (int i = 0; i < 8; i++){ const float v = cvec[b*512 + i*64+lane]; s += v*v; }
  const float cn2 = wred(s);
  s = 0.f; for (int i = 0; i < 4; i++){ const float v = chvec[b*256 + i*64+lane]; s += v*v; }
  const float chn2 = wred(s);
  float A[20];
#pragma unroll
  for (int i = 0; i < 20; i++) A[i] = jm[b*1280 + i*64+lane];
  float an2;
  { const float n2 = wred(sq_part<20>(A)); mt_project<20>(A, n2, mn2, &an2); }
  float T[20];
#pragma unroll
  for (int i = 0; i < 20; i++) T[i] = jc[b*1280 + i*64+lane];
  float tn2;
  { const float n2 = wred(sq_part<20>(T)); mt_project<20>(T, n2, cn2, &tn2); }
  { const float xy = wred(dot_part<20>(A, T));
    float O[20]; madd_vec<20>(A, an2, T, tn2, xy, O);
#pragma unroll
    for (int i = 0; i < 20; i++) A[i] = O[i];
    an2 = wred(sq_part<20>(A)); }
#pragma unroll
  for (int i = 0; i < 20; i++) T[i] = jch[b*1280 + i*64+lane];
  { const float n2 = wred(sq_part<20>(T)); mt_project<20>(T, n2, chn2, &tn2); }
  { const float xy = wred(dot_part<20>(A, T));
    float O[20]; madd_vec<20>(A, an2, T, tn2, xy, O);
#pragma unroll
    for (int i = 0; i < 20; i++) A[i] = O[i];
    an2 = wred(sq_part<20>(A)); }
#pragma unroll
  for (int i = 0; i < 20; i++) T[i] = fcb[i*64+lane];
  tn2 = wred(sq_part<20>(T));
  { const float xy = wred(dot_part<20>(A, T));
    float O[20]; madd_vec<20>(A, an2, T, tn2, xy, O);
#pragma unroll
    for (int i = 0; i < 20; i++) A[i] = O[i];
    an2 = wred(sq_part<20>(A)); }
  project_vec<20>(A, &an2);
#pragma unroll
  for (int i = 0; i < 20; i++) joint[b*1280 + i*64+lane] = A[i];
}

// hyperbolic MLR head
__global__ __launch_bounds__(256) void mlr_kernel(const float* __restrict__ joint,
    const float* __restrict__ P, const float* __restrict__ A, float* __restrict__ outp)
{
  const int wv = threadIdx.x >> 6, lane = threadIdx.x & 63;
  const int pair = blockIdx.x*4 + wv;
  const long b = pair >> 7, c = pair & 127;
  float Pv[20], J[20];
#pragma unroll
  for (int i = 0; i < 20; i++){
    Pv[i] = -P[c*1280 + i*64+lane];
    J[i]  = joint[b*1280 + i*64+lane];
  }
  const float p2 = wred(sq_part<20>(Pv));
  const float j2 = wred(sq_part<20>(J));
  const float xy = wred(dot_part<20>(Pv, J));
  float Z[20]; madd_vec<20>(Pv, p2, J, j2, xy, Z);
  float sza = 0.f, sz2 = 0.f, sa2 = 0.f;
#pragma unroll
  for (int i = 0; i < 20; i++){
    const float a = A[c*1280 + i*64+lane];
    sza += Z[i]*a; sz2 += Z[i]*Z[i]; sa2 += a*a;
  }
  float za = sza, z2 = sz2, a2 = sa2;
  wred3(za, z2, a2);
  const float an = sqrtf(fmaxf(a2, EPS_));
  const float v = 2.f*za / (fmaxf(1.f - z2, EPS_)*an);
  if (lane == 0) outp[pair] = 2.f*an*asinhf(v);
}

// ---------------------------------------------------------------------------
extern "C" void kernel_launch(void* const* d_in, const int* in_sizes, int n_in,
                              void* d_out, int out_size, void* d_ws, size_t ws_size,
                              hipStream_t stream)
{
  (void)in_sizes; (void)n_in; (void)out_size;
  const int*   context   = (const int*)  d_in[0];
  const int*   ctx_position=(const int*) d_in[1];
  const int*   mentions  = (const int*)  d_in[2];
  const int*   mchars    = (const int*)  d_in[3];
  const float* word_lut  = (const float*)d_in[4];
  const float* char_lut  = (const float*)d_in[5];
  const float* gf_Wih    = (const float*)d_in[6];
  const float* gf_Whh    = (const float*)d_in[7];
  const float* gf_b      = (const float*)d_in[8];
  const float* gb_Wih    = (const float*)d_in[9];
  const float* gb_Whh    = (const float*)d_in[10];
  const float* gb_b      = (const float*)d_in[11];
  const float* w2s_W     = (const float*)d_in[12];
  const float* w2s_b     = (const float*)d_in[13];
  const float* men_pos   = (const float*)d_in[14];
  const float* men_Wq    = (const float*)d_in[15];
  const float* men_bq    = (const float*)d_in[16];
  const float* men_Wk    = (const float*)d_in[17];
  const float* men_bk    = (const float*)d_in[18];
  const float* men_beta  = (const float*)d_in[19];
  const float* char_W    = (const float*)d_in[20];
  const float* char_U    = (const float*)d_in[21];
  const float* char_b    = (const float*)d_in[22];
  const float* cc_Wa     = (const float*)d_in[23];
  const float* cc_Wb     = (const float*)d_in[24];
  const float* cc_bias   = (const float*)d_in[25];
  const float* ctx_pos_t = (const float*)d_in[26];
  const float* ctx_Wq    = (const float*)d_in[27];
  const float* ctx_bq    = (const float*)d_in[28];
  const float* ctx_Wk    = (const float*)d_in[29];
  const float* ctx_bk    = (const float*)d_in[30];
  const float* ctx_beta  = (const float*)d_in[31];
  const float* fc_Wm     = (const float*)d_in[32];
  const float* fc_Wc     = (const float*)d_in[33];
  const float* fc_Wch    = (const float*)d_in[34];
  const float* fc_bias   = (const float*)d_in[35];
  const float* mlr_p     = (const float*)d_in[36];
  const float* mlr_a     = (const float*)d_in[37];
  float* out = (float*)d_out;

  // ---- workspace bump allocator ----
  char* wsb = (char*)d_ws;
  size_t off = 0;
  auto alloc = [&](size_t bytes) -> void* {
    void* p = wsb + off;
    off += (bytes + 255) & ~(size_t)255;
    return p;
  };
  float* WtIH = (float*)alloc(2UL*300*768*4);
  float* WtHH = (float*)alloc(2UL*256*768*4);
  unsigned short* Wrz16 = (unsigned short*)alloc(2UL*256*512*2);  // bf16 (r|z)
  unsigned short* Wh16  = (unsigned short*)alloc(2UL*256*256*2);  // bf16 (h)
  int*   ctxidx = (int*)alloc(32768UL*4);
  int*   chidx  = (int*)alloc(4096UL*4);
  float* xsqn   = (float*)alloc(32768UL*4);
  float* msqn   = (float*)alloc(2048UL*4);
  float* chsqn  = (float*)alloc(4096UL*4);
  unsigned short* xg = (unsigned short*)alloc(2UL*32768*768*2);
  float* xgn2 = (float*)alloc(2UL*32768*3*4);
  float* chn2d = (float*)alloc(4096UL*4);
  unsigned short* states_f = (unsigned short*)alloc(32768UL*256*2);
  unsigned short* states_b = (unsigned short*)alloc(32768UL*256*2);
  unsigned short* ctxv = (unsigned short*)alloc(32768UL*512*2);
  float* attn_sqn = (float*)alloc(32768UL*4);
  float* dctx = (float*)alloc(32768UL*4);
  float* wctx = (float*)alloc(32768UL*4);
  float* ctx_vec = (float*)alloc(256UL*512*4);
  float* mxbuf = (float*)alloc(2UL*8192*512*4);
  float* mv = (float*)alloc(2048UL*512*4);
  float* attn_embm = (float*)alloc(2048UL*512*4);
  float* amsqn = (float*)alloc(2048UL*4);
  float* dm = (float*)alloc(2048UL*4);
  float* wm = (float*)alloc(2048UL*4);
  float* mention_vec = (float*)alloc(256UL*512*4);
  unsigned short* xgc = (unsigned short*)alloc(4096UL*256*2);
  float* char_states = (float*)alloc(4096UL*256*4);
  float* char_vec = (float*)alloc(256UL*256*4);
  float* joint = (float*)alloc(256UL*1280*4);
  if (off > ws_size) return;
  float* attn_embc = (float*)xg;                   // overlay: xg dead after GRU
  float* mxh0 = mxbuf;
  float* mxh1 = mxbuf + 8192UL*512;

  // ---- weight transposes + bf16 split/pack ----
  transpose_k<<<dim3(10,24),256,0,stream>>>(gf_Wih, WtIH,            768, 300);
  transpose_k<<<dim3(10,24),256,0,stream>>>(gb_Wih, WtIH + 300*768,  768, 300);
  transpose_k<<<dim3(8,24), 256,0,stream>>>(gf_Whh, WtHH,            768, 256);
  transpose_k<<<dim3(8,24), 256,0,stream>>>(gb_Whh, WtHH + 256*768,  768, 256);
  pack_whh16<<<1536,256,0,stream>>>(WtHH, Wrz16, Wh16);

  // ---- gather indices + input sqn ----
  build_idx<<<144,256,0,stream>>>(context, mchars, ctxidx, chidx);
  sqn_gather<<<8192,256,0,stream>>>(word_lut, ctxidx, 300, xsqn);
  sqn_gather<<<512, 256,0,stream>>>(word_lut, mentions, 300, msqn);
  sqn_gather<<<1024,256,0,stream>>>(char_lut, chidx, 256, chsqn);

  // ---- GRU input precompute: xg[dir] = mobius_matvec(emb, Wih^T), bf16 ----
  for (int d2 = 0; d2 < 2; d2++){
    const float* wih_t = WtIH + (size_t)d2*300*768;
    for (int c = 0; c < 4; c++){
      mm_kernel<1><<<dim3(6,64),256,0,stream>>>(word_lut, ctxidx + c*8192, wih_t,
                                                mxbuf, 8192, 768, 300);
      xg_transform<<<6144,256,0,stream>>>(mxbuf, xsqn + c*8192,
          xg + ((size_t)d2*32768 + (size_t)c*8192)*768,
          xgn2 + ((size_t)d2*32768 + (size_t)c*8192)*3, 3);
    }
  }

  // ---- bidirectional Mobius GRU (LDS-streamed bf16 weights, all CUs) ----
  (void)hipFuncSetAttribute((const void*)gru_kernel,
      hipFuncAttributeMaxDynamicSharedMemorySize, GRU_LDS_BYTES);
  gru_kernel<<<256,256,GRU_LDS_BYTES,stream>>>(xg, xgn2, Wrz16, Wh16,
                                               gf_b, gb_b, states_f, states_b);

  // ---- mobius concat of directions -> ctx (bf16) ----
  for (int c = 0; c < 4; c++){
    mm_kernel<2><<<dim3(4,64),256,0,stream>>>(states_f + (size_t)c*8192*256, nullptr,
                                              cc_Wa, mxh0, 8192, 512, 256);
    mm_kernel<2><<<dim3(4,64),256,0,stream>>>(states_b + (size_t)c*8192*256, nullptr,
                                              cc_Wb, mxh1, 8192, 512, 256);
    cc_rowwise<<<2048,256,0,stream>>>(states_f, states_b, mxh0, mxh1, cc_bias,
                                      ctxv, c*8192);
  }

  // ---- context distance attention ----
  attn_add<<<8192,256,0,stream>>>(ctxv, ctx_position, ctx_pos_t, attn_embc, attn_sqn);
  for (int c = 0; c < 4; c++){
    mm_kernel<0><<<dim3(4,64),256,0,stream>>>(attn_embc + (size_t)c*8192*512, nullptr,
                                              ctx_Wq, mxh0, 8192, 512, 512);
    mm_kernel<0><<<dim3(4,64),256,0,stream>>>(attn_embc + (size_t)c*8192*512, nullptr,
                                              ctx_Wk, mxh1, 8192, 512, 512);
    qk_pdist<<<2048,256,0,stream>>>(mxh0, mxh1, attn_sqn + c*8192, ctx_bq, ctx_bk,
                                    dctx + c*8192);
  }
  softmax128<<<64,256,0,stream>>>(dctx, ctx_beta, wctx);
  midpoint_wide<<<256,512,0,stream>>>(ctxv, wctx, ctx_vec);

  // ---- mention encoder ----
  mm_kernel<1><<<dim3(4,16),256,0,stream>>>(word_lut, mentions, w2s_W, mxh0, 2048, 512, 300);
  mv_rowwise<<<512,256,0,stream>>>(mxh0, msqn, w2s_b, mv);
  attn_add_m<<<512,256,0,stream>>>(mv, mentions, men_pos, attn_embm, amsqn);
  mm_kernel<0><<<dim3(4,16),256,0,stream>>>(attn_embm, nullptr, men_Wq, mxh0, 2048, 512, 512);
  mm_kernel<0><<<dim3(4,16),256,0,stream>>>(attn_embm, nullptr, men_Wk, mxh1, 2048, 512, 512);
  qk_pdist<<<512,256,0,stream>>>(mxh0, mxh1, amsqn, men_bq, men_bk, dm);
  softmax8<<<1,256,0,stream>>>(dm, men_beta, wm);
  midpoint_kernel<8,false,true><<<64,256,0,stream>>>(mv, wm, mention_vec, 8);

  // ---- char encoder ----
  mm_kernel<1><<<dim3(2,32),256,0,stream>>>(char_lut, chidx, char_U, mxh0, 4096, 256, 256);
  xg_transform<<<1024,256,0,stream>>>(mxh0, chsqn, xgc, chn2d, 1);
  char_rnn<<<64,256,0,stream>>>(xgc, char_W, char_b, char_states);
  midpoint_kernel<4,false,false><<<64,256,0,stream>>>(char_states, nullptr, char_vec, 16);

  // ---- full mobius concat + MLR ----
  float* jm = mxh0;
  float* jc = mxh0 + 256UL*1280;
  float* jch = mxh0 + 2UL*256*1280;
  mm_kernel<0><<<dim3(10,2),256,0,stream>>>(mention_vec, nullptr, fc_Wm, jm, 256, 1280, 512);
  mm_kernel<0><<<dim3(10,2),256,0,stream>>>(ctx_vec,     nullptr, fc_Wc, jc, 256, 1280, 512);
  mm_kernel<0><<<dim3(10,2),256,0,stream>>>(char_vec,    nullptr, fc_Wch, jch, 256, 1280, 256);
  final_rowwise<<<64,256,0,stream>>>(jm, jc, jch, mention_vec, ctx_vec, char_vec,
                                     fc_bias, joint);
  mlr_kernel<<<8192,256,0,stream>>>(joint, mlr_p, mlr_a, out);
}

// Round 7
// 3021.241 us; speedup vs baseline: 3.1084x; 1.5026x over previous
//
#include <hip/hip_runtime.h>
#include <cstddef>
#include <cstdint>

// ---------------------------------------------------------------------------
// Hyperbolic (Poincare-ball) entity-typing forward pass, MI355X / gfx950.
// Round 7: bulk GEMMs moved to MFMA bf16 (mfma_mm, 128x128 tile, 16x16x32),
// B^T pre-packed bf16; attn_emb stored bf16. GRU v6c unchanged (round 6).
// ---------------------------------------------------------------------------

#define EPS_  1e-15f
#define PMAX_ 0.99999f    // 1 - 1e-5

typedef __attribute__((ext_vector_type(8))) short bf16x8;
typedef __attribute__((ext_vector_type(4))) float f32x4;
typedef __attribute__((ext_vector_type(8))) unsigned short us8;

__device__ __forceinline__ float wred(float v){
#pragma unroll
  for (int o = 32; o; o >>= 1) v += __shfl_xor(v, o, 64);
  return v;
}
__device__ __forceinline__ void wred2(float& a, float& b){
#pragma unroll
  for (int o = 32; o; o >>= 1){ a += __shfl_xor(a, o, 64); b += __shfl_xor(b, o, 64); }
}
__device__ __forceinline__ void wred3(float& a, float& b, float& c){
#pragma unroll
  for (int o = 32; o; o >>= 1){
    a += __shfl_xor(a, o, 64); b += __shfl_xor(b, o, 64); c += __shfl_xor(c, o, 64);
  }
}
__device__ __forceinline__ void wred4(float& a, float& b, float& c, float& d){
#pragma unroll
  for (int o = 32; o; o >>= 1){
    a += __shfl_xor(a, o, 64); b += __shfl_xor(b, o, 64);
    c += __shfl_xor(c, o, 64); d += __shfl_xor(d, o, 64);
  }
}
__device__ __forceinline__ float wredmax(float v){
#pragma unroll
  for (int o = 32; o; o >>= 1) v = fmaxf(v, __shfl_xor(v, o, 64));
  return v;
}
__device__ __forceinline__ float snorm(float s){ return sqrtf(fmaxf(s, EPS_)); }
__device__ __forceinline__ float clamp11(float x){
  return fminf(fmaxf(x, -1.f + 1e-7f), 1.f - 1e-7f);
}
__device__ __forceinline__ float bf2f(unsigned short u){
  union { unsigned int i; float f; } v; v.i = ((unsigned int)u) << 16; return v.f;
}
__device__ __forceinline__ unsigned short f2bf(float f){
  union { float f; unsigned int i; } v; v.f = f;
  unsigned int x = v.i;
  x += 0x7fffu + ((x >> 16) & 1u);   // RNE
  return (unsigned short)(x >> 16);
}
__device__ __forceinline__ float bflo(unsigned u){
  union { unsigned i; float f; } v; v.i = u << 16; return v.f;
}
__device__ __forceinline__ float bfhi(unsigned u){
  union { unsigned i; float f; } v; v.i = u & 0xffff0000u; return v.f;
}

template<int N>
__device__ __forceinline__ float sq_part(const float* a){
  float s = 0.f;
#pragma unroll
  for (int i = 0; i < N; i++) s += a[i]*a[i];
  return s;
}
template<int N>
__device__ __forceinline__ float dot_part(const float* a, const float* b){
  float s = 0.f;
#pragma unroll
  for (int i = 0; i < N; i++) s += a[i]*b[i];
  return s;
}
template<int N>
__device__ __forceinline__ void madd_vec(const float* x, float x2, const float* y,
                                         float y2, float xy, float* o){
  const float c1 = 1.f + 2.f*xy + y2;
  const float c2 = 1.f - x2;
  const float inv = 1.f / fmaxf(1.f + 2.f*xy + x2*y2, EPS_);
#pragma unroll
  for (int i = 0; i < N; i++) o[i] = (c1*x[i] + c2*y[i]) * inv;
}
template<int N>
__device__ __forceinline__ void mt_project(float* v, float mxn2, float xn2, float* n2out){
  const float xn  = snorm(xn2);
  const float mxn = snorm(mxn2);
  const float t   = tanhf(mxn/xn * atanhf(clamp11(xn)));
  float sc = t/mxn;
  float n2 = sc*sc*mxn2;
  const float n = snorm(n2);
  if (n > PMAX_){ const float s = PMAX_/n; sc *= s; n2 *= s*s; }
#pragma unroll
  for (int i = 0; i < N; i++) v[i] *= sc;
  *n2out = n2;
}
__device__ __forceinline__ void mt_scale(float mxn2, float xn, float art,
                                         float* sc, float* n2){
  const float mxn = snorm(mxn2);
  const float t   = tanhf(mxn/xn * art);
  float s  = t/mxn;
  float nn = t*t;
  const float n = snorm(nn);
  if (n > PMAX_){ const float f = PMAX_/n; s *= f; nn *= f*f; }
  *sc = s; *n2 = nn;
}
template<int N>
__device__ __forceinline__ void project_vec(float* v, float* n2io){
  float n2 = *n2io;
  const float n = snorm(n2);
  if (n > PMAX_){
    const float s = PMAX_/n;
#pragma unroll
    for (int i = 0; i < N; i++) v[i] *= s;
    n2 *= s*s;
  }
  *n2io = n2;
}

// async 16B global->LDS: linear wave-uniform-base + lane*16
__device__ __forceinline__ void gll16(const void* g, void* l){
  __builtin_amdgcn_global_load_lds(
      (const __attribute__((address_space(1))) void*)g,
      (__attribute__((address_space(3))) void*)l, 16, 0, 0);
}
// stage 64KB (256 thr x 16 x 16B), linear layout
__device__ __forceinline__ void stage64k(const void* gsrc, float* lbase, int w, int lane){
#pragma unroll
  for (int i = 0; i < 16; i++){
    const char* g = (const char*)gsrc + (size_t)((i*4 + w)*64 + lane)*16;
    char* l = (char*)lbase + (size_t)((i*4 + w)*64)*16;
    gll16(g, l);
  }
}

// ---------------------------------------------------------------------------
// MFMA bf16 GEMM: C[M,N] = A[M,K] @ B[K,N], B pre-packed as B^T bf16 [N][Kp].
// AMODE: 1 = f32 A gathered via idx (convert on stage), 2 = bf16 A direct.
// M, N multiples of 128; Kp multiple of 32 (zero-padded); K real bound.
// 4 waves: 2x2 quadrants of 64x64, each 4x4 fragments of 16x16x32.
// ---------------------------------------------------------------------------
template<int AMODE>
__global__ __launch_bounds__(256) void mfma_mm(const void* __restrict__ Aptr,
    const int* __restrict__ idx, const unsigned short* __restrict__ Bt,
    float* __restrict__ Cm, int M, int N, int K, int Kp)
{
  __shared__ __align__(16) unsigned short As[128][40];
  __shared__ __align__(16) unsigned short Bs[128][40];
  const int tid = threadIdx.x;
  const int n0 = blockIdx.x * 128;
  const int m0 = blockIdx.y * 128;
  const int srow = tid >> 1, shalf = tid & 1;
  const int wv = tid >> 6, lane = tid & 63;
  const int wm = wv >> 1, wn = wv & 1;
  const int lr = lane & 15, lk = lane >> 4;

  long arow;
  if constexpr (AMODE == 1) arow = (long)idx[m0 + srow] * K;
  else                      arow = (long)(m0 + srow) * K;

  f32x4 acc[4][4];
#pragma unroll
  for (int mf = 0; mf < 4; mf++)
#pragma unroll
    for (int nf = 0; nf < 4; nf++) acc[mf][nf] = (f32x4){0.f,0.f,0.f,0.f};

  for (int k0 = 0; k0 < Kp; k0 += 32){
    const int kb = k0 + shalf*16;
    unsigned short av[16];
    if constexpr (AMODE == 1){
      const float* ar = (const float*)Aptr + arow;
      if (kb + 16 <= K){
#pragma unroll
        for (int v = 0; v < 4; v++){
          const float4 f = *(const float4*)(ar + kb + v*4);
          av[v*4+0]=f2bf(f.x); av[v*4+1]=f2bf(f.y);
          av[v*4+2]=f2bf(f.z); av[v*4+3]=f2bf(f.w);
        }
      } else {
#pragma unroll
        for (int v = 0; v < 16; v++){
          const int col = kb + v;
          av[v] = (col < K) ? f2bf(ar[col]) : (unsigned short)0;
        }
      }
    } else {
      const unsigned short* ar = (const unsigned short*)Aptr + arow + kb;
      const us8 u0 = *(const us8*)ar;
      const us8 u1 = *(const us8*)(ar + 8);
#pragma unroll
      for (int v = 0; v < 8; v++){ av[v] = u0[v]; av[8+v] = u1[v]; }
    }
    unsigned short bvv[16];
    {
      const unsigned short* br = Bt + (long)(n0 + srow)*Kp + kb;
      const us8 u0 = *(const us8*)br;
      const us8 u1 = *(const us8*)(br + 8);
#pragma unroll
      for (int v = 0; v < 8; v++){ bvv[v] = u0[v]; bvv[8+v] = u1[v]; }
    }
    __syncthreads();                    // previous compute done, LDS free
    *(us8*)&As[srow][shalf*16]   = *(const us8*)&av[0];
    *(us8*)&As[srow][shalf*16+8] = *(const us8*)&av[8];
    *(us8*)&Bs[srow][shalf*16]   = *(const us8*)&bvv[0];
    *(us8*)&Bs[srow][shalf*16+8] = *(const us8*)&bvv[8];
    __syncthreads();
    bf16x8 af[4], bfr[4];
#pragma unroll
    for (int mf = 0; mf < 4; mf++)
      af[mf] = *(const bf16x8*)&As[wm*64 + mf*16 + lr][lk*8];
#pragma unroll
    for (int nf = 0; nf < 4; nf++)
      bfr[nf] = *(const bf16x8*)&Bs[wn*64 + nf*16 + lr][lk*8];
#pragma unroll
    for (int mf = 0; mf < 4; mf++)
#pragma unroll
      for (int nf = 0; nf < 4; nf++)
        acc[mf][nf] = __builtin_amdgcn_mfma_f32_16x16x32_bf16(af[mf], bfr[nf],
                                                              acc[mf][nf], 0, 0, 0);
  }
  // epilogue: D row=(lane>>4)*4+reg, col=lane&15 per fragment
#pragma unroll
  for (int mf = 0; mf < 4; mf++){
#pragma unroll
    for (int nf = 0; nf < 4; nf++){
#pragma unroll
      for (int r = 0; r < 4; r++){
        const long grow = m0 + wm*64 + mf*16 + lk*4 + r;
        Cm[grow*N + n0 + wn*64 + nf*16 + lr] = acc[mf][nf][r];
      }
    }
  }
}

// ---------------------------------------------------------------------------
// Generic tiled f32 GEMM (kept for the small fc GEMMs only).
// ---------------------------------------------------------------------------
template<int AMODE>
__global__ __launch_bounds__(256) void mm_kernel(const void* __restrict__ Aptr,
    const int* __restrict__ idx, const float* __restrict__ Bm,
    float* __restrict__ Cm, int M, int N, int K)
{
  __shared__ __align__(16) float As[8][128];
  __shared__ __align__(16) float Bs[8][132];
  const int tid = threadIdx.x;
  const int n0 = blockIdx.x * 128;
  const int m0 = blockIdx.y * 128;
  const int tr = tid >> 4, tc = tid & 15;
  const int sm = tid & 127, sk = (tid >> 7) * 4;
  const int bk = tid >> 5,  bn = (tid & 31) * 4;
  long arow;
  if constexpr (AMODE == 1) arow = (long)idx[m0 + sm] * K;
  else                      arow = (long)(m0 + sm) * K;
  float acc[8][8];
#pragma unroll
  for (int i = 0; i < 8; i++)
#pragma unroll
    for (int j = 0; j < 8; j++) acc[i][j] = 0.f;

  for (int k0 = 0; k0 < K; k0 += 8){
    float av[4], bv[4];
    {
      const float* A = (const float*)Aptr;
      if (k0 + sk + 3 < K){
        const float4 f = *reinterpret_cast<const float4*>(A + arow + k0 + sk);
        av[0]=f.x; av[1]=f.y; av[2]=f.z; av[3]=f.w;
      } else {
#pragma unroll
        for (int i = 0; i < 4; i++){
          const int kk = k0 + sk + i;
          av[i] = (kk < K) ? A[arow + kk] : 0.f;
        }
      }
    }
    {
      const int kb = k0 + bk;
      if (kb < K){
        const float4 f = *reinterpret_cast<const float4*>(Bm + (long)kb*N + n0 + bn);
        bv[0]=f.x; bv[1]=f.y; bv[2]=f.z; bv[3]=f.w;
      } else { bv[0]=bv[1]=bv[2]=bv[3]=0.f; }
    }
    __syncthreads();
    As[sk+0][sm]=av[0]; As[sk+1][sm]=av[1]; As[sk+2][sm]=av[2]; As[sk+3][sm]=av[3];
    *reinterpret_cast<float4*>(&Bs[bk][bn]) = make_float4(bv[0],bv[1],bv[2],bv[3]);
    __syncthreads();
#pragma unroll
    for (int k = 0; k < 8; k++){
      float a[8], bb[8];
      *(float4*)&a[0]  = *(const float4*)&As[k][tr*8];
      *(float4*)&a[4]  = *(const float4*)&As[k][tr*8+4];
      *(float4*)&bb[0] = *(const float4*)&Bs[k][tc*8];
      *(float4*)&bb[4] = *(const float4*)&Bs[k][tc*8+4];
#pragma unroll
      for (int i = 0; i < 8; i++)
#pragma unroll
        for (int j = 0; j < 8; j++) acc[i][j] += a[i]*bb[j];
    }
  }
#pragma unroll
  for (int i = 0; i < 8; i++){
    const long row = m0 + tr*8 + i;
    *(float4*)(Cm + row*N + n0 + tc*8)     = make_float4(acc[i][0],acc[i][1],acc[i][2],acc[i][3]);
    *(float4*)(Cm + row*N + n0 + tc*8 + 4) = make_float4(acc[i][4],acc[i][5],acc[i][6],acc[i][7]);
  }
}

// ---------------------------------------------------------------------------
// 32x32 LDS-tiled transpose: dst[k*R + j] = src[j*Kc + k]   (f32 -> f32)
// ---------------------------------------------------------------------------
__global__ __launch_bounds__(256) void transpose_k(const float* __restrict__ src,
    float* __restrict__ dst, int R, int Kc)
{
  __shared__ float t[32][33];
  const int bx = blockIdx.x * 32;   // k dim
  const int by = blockIdx.y * 32;   // j dim
  const int tx = threadIdx.x & 31, ty = threadIdx.x >> 5;
#pragma unroll
  for (int i = 0; i < 32; i += 8){
    const int j = by + ty + i, k = bx + tx;
    t[ty+i][tx] = (j < R && k < Kc) ? src[(long)j*Kc + k] : 0.f;
  }
  __syncthreads();
#pragma unroll
  for (int i = 0; i < 32; i += 8){
    const int k = bx + ty + i, j = by + tx;
    if (k < Kc && j < R) dst[(long)k*R + j] = t[tx][ty+i];
  }
}

// transpose + bf16 pack: src [K][N] f32 -> dst [N][Kp] bf16 (zero-pad K..Kp)
__global__ __launch_bounds__(256) void packT16(const float* __restrict__ src,
    unsigned short* __restrict__ dst, int K, int N, int Kp)
{
  __shared__ float t[32][33];
  const int bx = blockIdx.x*32;  // k
  const int by = blockIdx.y*32;  // n
  const int tx = threadIdx.x & 31, ty = threadIdx.x >> 5;
#pragma unroll
  for (int i = 0; i < 32; i += 8){
    const int k = bx + ty + i, n = by + tx;
    t[ty+i][tx] = (k < K && n < N) ? src[(long)k*N + n] : 0.f;
  }
  __syncthreads();
#pragma unroll
  for (int i = 0; i < 32; i += 8){
    const int k = bx + tx, n = by + ty + i;
    if (k < Kp && n < N) dst[(long)n*Kp + k] = f2bf(t[tx][ty+i]);
  }
}

// pack Wih (already [768][300] = B^T layout) -> [2][768][320] bf16 zero-padded
__global__ void pack_wih(const float* __restrict__ w0, const float* __restrict__ w1,
                         unsigned short* __restrict__ dst)
{
  const int tid = blockIdx.x*256 + threadIdx.x;
  if (tid < 2*768*320){
    const int d = tid / (768*320);
    const int rem = tid - d*768*320;
    const int n = rem / 320, k = rem - n*320;
    const float* src = d ? w1 : w0;
    dst[tid] = (k < 300) ? f2bf(src[n*300 + k]) : (unsigned short)0;
  }
}

// split+pack WtHH [2][256][768] (r|h|z) f32 -> Wrz16 (r|z) bf16, Wh16 bf16
__global__ void pack_whh16(const float* __restrict__ WtHH,
                           unsigned short* __restrict__ Wrz16,
                           unsigned short* __restrict__ Wh16)
{
  const int tid = blockIdx.x*256 + threadIdx.x;
  if (tid < 2*256*768){
    const int col = tid % 768, rk = tid / 768;
    const unsigned short v = f2bf(WtHH[tid]);
    if (col < 256)       Wrz16[(long)rk*512 + col] = v;
    else if (col < 512)  Wh16 [(long)rk*256 + (col - 256)] = v;
    else                 Wrz16[(long)rk*512 + 256 + (col - 512)] = v;
  }
}

// build gather-index arrays
__global__ void build_idx(const int* __restrict__ context, const int* __restrict__ mchars,
                          int* __restrict__ ctxidx, int* __restrict__ chidx)
{
  const int tid = blockIdx.x*256 + threadIdx.x;
  if (tid < 32768){
    const int t = tid >> 8, b = tid & 255;
    ctxidx[tid] = context[b*128 + t];
  } else if (tid < 32768 + 4096){
    const int o = tid - 32768;
    const int t = o >> 8, b = o & 255;
    chidx[o] = mchars[b*16 + t];
  }
}

// out[r] = sum_k lut[idx[r]][k]^2   (one wave per row)
__global__ __launch_bounds__(256) void sqn_gather(const float* __restrict__ lut,
    const int* __restrict__ idx, int K, float* __restrict__ outp)
{
  const int wv = threadIdx.x >> 6, lane = threadIdx.x & 63;
  const int r = blockIdx.x*4 + wv;
  const float* row = lut + (long)idx[r]*K;
  float s = 0.f;
  for (int k = lane; k < K; k += 64) s += row[k]*row[k];
  s = wred(s);
  if (lane == 0) outp[r] = s;
}

// mobius_matvec tail transform per (row, gate); out bf16 + |out_bf16|^2
__global__ __launch_bounds__(256) void xg_transform(const float* __restrict__ mx,
    const float* __restrict__ xsqn, unsigned short* __restrict__ outp,
    float* __restrict__ n2o, int G)
{
  const int wv = threadIdx.x >> 6, lane = threadIdx.x & 63;
  const int wg = blockIdx.x*4 + wv;
  const int row = wg / G, g = wg - row*G;
  const long base = (long)row*(G*256) + g*256;
  float M[4];
#pragma unroll
  for (int i = 0; i < 4; i++) M[i] = mx[base + i*64 + lane];
  const float mxn2 = wred(sq_part<4>(M));
  float pn2; mt_project<4>(M, mxn2, xsqn[row], &pn2);
  float s = 0.f;
#pragma unroll
  for (int i = 0; i < 4; i++){
    const unsigned short u = f2bf(M[i]);
    outp[base + i*64 + lane] = u;
    const float rv = bf2f(u);
    s += rv*rv;
  }
  s = wred(s);
  if (lane == 0) n2o[wg] = s;
}

// ---------------------------------------------------------------------------
// Mobius GRU v6c (unchanged from round 6, passing)
// ---------------------------------------------------------------------------
#define GRU_LDS_BYTES 145664

__global__ __launch_bounds__(256,1) void gru_kernel(
    const unsigned short* __restrict__ xg,
    const float* __restrict__ xgn2,
    const unsigned short* __restrict__ Wrz16,
    const unsigned short* __restrict__ Wh16,
    const float* __restrict__ bias_f, const float* __restrict__ bias_b,
    unsigned short* __restrict__ states_f, unsigned short* __restrict__ states_b)
{
  extern __shared__ __align__(16) char smem[];
  float* wbuf = (float*)smem;
  float* hs   = (float*)(smem + 131072);
  float* part = (float*)(smem + 133120);
  float* rhb  = (float*)(smem + 141312);
  float* zb   = (float*)(smem + 143360);
  float* scal = (float*)(smem + 145408);

  const int bid = blockIdx.x;
  const int dir = bid >> 7;
  const int brow0 = (bid & 127) * 2;
  const int tid = threadIdx.x;
  const int w = tid >> 6, lane = tid & 63;
  const int j0 = lane << 2;

  const unsigned short* xgd = xg + (long)dir*32768*768;
  const float* xnd = xgn2 + (long)dir*32768*3;
  const unsigned short* wrz_d = Wrz16 + (long)dir*256*512;
  const unsigned short* wh_d  = Wh16  + (long)dir*256*256;
  const float* bias = dir ? bias_b : bias_f;
  unsigned short* states = dir ? states_b : states_f;

  const int fg  = w & 1;
  const int khf = w >> 1;
  const int qk  = w;
  const int crow  = w >> 1;
  const int cgate = w & 1;

  float bg[4], bh4[4] = {0,0,0,0};
  float bg2, bh2 = 0.f;
#pragma unroll
  for (int i = 0; i < 4; i++) bg[i] = bias[(cgate ? 512 : 0) + j0 + i];
  bg2 = wred(sq_part<4>(bg));
  if (w < 2){
#pragma unroll
    for (int i = 0; i < 4; i++) bh4[i] = bias[256 + j0 + i];
    bh2 = wred(sq_part<4>(bh4));
  }

  float h[4] = {0.f,0.f,0.f,0.f};
  float hn2 = 0.f;
  if (w < 2){
#pragma unroll
    for (int i = 0; i < 4; i++) hs[w*256 + j0 + i] = 0.f;
    if (lane == 0){ scal[w*2 + 0] = 0.f; scal[w*2 + 1] = 0.f; }
  }

  int cb = 0;
  stage64k(wrz_d, wbuf, w, lane);

  for (int t = 0; t < 128; t++){
    const int tt = dir ? (127 - t) : t;
    float xgv[4], y2g, xgh4[4] = {0,0,0,0}, y2h = 0.f;
    {
      const long rxg = (long)tt*256 + brow0 + crow;
      const ushort4 u = *(const ushort4*)(xgd + rxg*768 + (cgate ? 512 : 0) + j0);
      xgv[0]=bf2f(u.x); xgv[1]=bf2f(u.y); xgv[2]=bf2f(u.z); xgv[3]=bf2f(u.w);
      y2g = xnd[rxg*3 + (cgate ? 2 : 0)];
      if (w < 2){
        const long rxh = (long)tt*256 + brow0 + w;
        const ushort4 uh = *(const ushort4*)(xgd + rxh*768 + 256 + j0);
        xgh4[0]=bf2f(uh.x); xgh4[1]=bf2f(uh.y); xgh4[2]=bf2f(uh.z); xgh4[3]=bf2f(uh.w);
        y2h = xnd[rxh*3 + 1];
      }
    }

    float s00=0.f,s01=0.f,s02=0.f,s03=0.f, s10=0.f,s11=0.f,s12=0.f,s13=0.f;
#pragma unroll 1
    for (int c = 0; c < 4; c++){
      __syncthreads();
      if (c < 3) stage64k((const char*)wrz_d + (size_t)(c+1)*65536,
                          wbuf + (cb^1)*16384, w, lane);
      const uint2* wb2 = (const uint2*)(wbuf + cb*16384);
      const int kb = c*64 + khf*32;
#pragma unroll
      for (int kq = 0; kq < 8; kq++){
        const float4 hb0 = *(const float4*)&hs[0*256 + kb + kq*4];
        const float4 hb1 = *(const float4*)&hs[1*256 + kb + kq*4];
#pragma unroll
        for (int q = 0; q < 4; q++){
          const uint2 wvv = wb2[(khf*32 + kq*4 + q)*128 + fg*64 + lane];
          const float w0 = bflo(wvv.x), w1 = bfhi(wvv.x);
          const float w2 = bflo(wvv.y), w3 = bfhi(wvv.y);
          const float h0 = (&hb0.x)[q], h1 = (&hb1.x)[q];
          s00 += h0*w0; s01 += h0*w1; s02 += h0*w2; s03 += h0*w3;
          s10 += h1*w0; s11 += h1*w1; s12 += h1*w2; s13 += h1*w3;
        }
      }
      cb ^= 1;
    }
    {
      float* p1 = part + khf*1024 + fg*256 + j0;
      *(float4*)p1         = make_float4(s00,s01,s02,s03);
      *(float4*)(p1 + 512) = make_float4(s10,s11,s12,s13);
    }
    __syncthreads();
    stage64k(wh_d, wbuf + (cb^1)*16384, w, lane);
    cb ^= 1;

    {
      const float* pa = part + crow*512 + cgate*256 + j0;
      const float4 a0 = *(const float4*)pa;
      const float4 a1 = *(const float4*)(pa + 1024);
      float a[4] = { a0.x+a1.x, a0.y+a1.y, a0.z+a1.z, a0.w+a1.w };
      const float hn2v = scal[crow*2 + 0];
      const float xn_h = snorm(hn2v), art_h = atanhf(clamp11(xn_h));
      const float p2 = wred(sq_part<4>(a));
      float sc, n2; mt_scale(p2, xn_h, art_h, &sc, &n2);
#pragma unroll
      for (int i = 0; i < 4; i++) a[i] *= sc;
      const float xy = wred(dot_part<4>(a, xgv));
      float m1[4]; madd_vec<4>(a, n2, xgv, y2g, xy, m1);
      float m1n2 = sq_part<4>(m1), xyb = dot_part<4>(m1, bg);
      wred2(m1n2, xyb);
      float m2[4]; madd_vec<4>(m1, m1n2, bg, bg2, xyb, m2);
      const float m2n2 = wred(sq_part<4>(m2));
      const float nn = snorm(m2n2), fgc = atanhf(clamp11(nn))/nn;
      float g4[4];
#pragma unroll
      for (int i = 0; i < 4; i++) g4[i] = 1.f/(1.f + expf(-fgc*m2[i]));
      if (cgate == 0){
        float h4[4];
        *(float4*)h4 = *(const float4*)&hs[crow*256 + j0];
        float rh[4]; float wx2 = 0.f;
#pragma unroll
        for (int i = 0; i < 4; i++){ rh[i] = g4[i]*h4[i]; wx2 += rh[i]*rh[i]; }
        wx2 = wred(wx2);
        float rhn2, scrh;
        {
          const float wxn = snorm(wx2);
          const float trh = tanhf(wxn/xn_h * art_h);
          scrh = trh/wxn; rhn2 = trh*trh;
          const float n = snorm(rhn2);
          if (n > PMAX_){ const float f = PMAX_/n; scrh *= f; rhn2 *= f*f; }
        }
#pragma unroll
        for (int i = 0; i < 4; i++) rh[i] *= scrh;
        *(float4*)&rhb[crow*256 + j0] = make_float4(rh[0],rh[1],rh[2],rh[3]);
        if (lane == 0) scal[crow*2 + 1] = rhn2;
      } else {
        *(float4*)&zb[crow*256 + j0] = make_float4(g4[0],g4[1],g4[2],g4[3]);
      }
    }

    float r00=0.f,r01=0.f,r02=0.f,r03=0.f, r10=0.f,r11=0.f,r12=0.f,r13=0.f;
#pragma unroll 1
    for (int c = 0; c < 2; c++){
      __syncthreads();
      if (c < 1) stage64k((const char*)wh_d + 65536, wbuf + (cb^1)*16384, w, lane);
      const uint2* wb2 = (const uint2*)(wbuf + cb*16384);
      const int kb = c*128 + qk*32;
#pragma unroll
      for (int kq = 0; kq < 8; kq++){
        const float4 hb0 = *(const float4*)&rhb[0*256 + kb + kq*4];
        const float4 hb1 = *(const float4*)&rhb[1*256 + kb + kq*4];
#pragma unroll
        for (int q = 0; q < 4; q++){
          const uint2 wvv = wb2[(qk*32 + kq*4 + q)*64 + lane];
          const float w0 = bflo(wvv.x), w1 = bfhi(wvv.x);
          const float w2 = bflo(wvv.y), w3 = bfhi(wvv.y);
          const float h0 = (&hb0.x)[q], h1 = (&hb1.x)[q];
          r00 += h0*w0; r01 += h0*w1; r02 += h0*w2; r03 += h0*w3;
          r10 += h1*w0; r11 += h1*w1; r12 += h1*w2; r13 += h1*w3;
        }
      }
      cb ^= 1;
    }
    {
      float* p2 = part + qk*512 + j0;
      *(float4*)p2         = make_float4(r00,r01,r02,r03);
      *(float4*)(p2 + 256) = make_float4(r10,r11,r12,r13);
    }
    __syncthreads();
    if (t < 127){
      stage64k(wrz_d, wbuf + (cb^1)*16384, w, lane);
      cb ^= 1;
    }

    if (w < 2){
      float ah[4];
      {
        const float4 p0 = *(const float4*)(part + 0*512 + w*256 + j0);
        const float4 p1 = *(const float4*)(part + 1*512 + w*256 + j0);
        const float4 p2 = *(const float4*)(part + 2*512 + w*256 + j0);
        const float4 p3 = *(const float4*)(part + 3*512 + w*256 + j0);
        ah[0] = (p0.x+p1.x)+(p2.x+p3.x);
        ah[1] = (p0.y+p1.y)+(p2.y+p3.y);
        ah[2] = (p0.z+p1.z)+(p2.z+p3.z);
        ah[3] = (p0.w+p1.w)+(p2.w+p3.w);
      }
      const float rhn2v = scal[w*2 + 1];
      const float rxn = snorm(rhn2v), artr = atanhf(clamp11(rxn));
      float mx2 = sq_part<4>(ah), xyraw = dot_part<4>(ah, xgh4);
      wred2(mx2, xyraw);
      float sch, pn2; mt_scale(mx2, rxn, artr, &sch, &pn2);
#pragma unroll
      for (int i = 0; i < 4; i++) ah[i] *= sch;
      const float xy = xyraw * sch;
      float m1[4]; madd_vec<4>(ah, pn2, xgh4, y2h, xy, m1);
      float m1n2 = sq_part<4>(m1), xyb = dot_part<4>(m1, bh4);
      wred2(m1n2, xyb);
      float ht[4]; madd_vec<4>(m1, m1n2, bh4, bh2, xyb, ht);
      float htn2 = sq_part<4>(ht);
      float nh[4];
#pragma unroll
      for (int i = 0; i < 4; i++) nh[i] = -h[i];
      float xyd = dot_part<4>(nh, ht);
      wred2(htn2, xyd);
      float dl[4]; madd_vec<4>(nh, hn2, ht, htn2, xyd, dl);
      float z4[4];
      *(float4*)z4 = *(const float4*)&zb[w*256 + j0];
      float pw[4]; float dln2 = 0.f, wz2 = 0.f, xyhr = 0.f;
#pragma unroll
      for (int i = 0; i < 4; i++){
        dln2 += dl[i]*dl[i];
        pw[i] = z4[i]*dl[i];
        wz2  += pw[i]*pw[i];
        xyhr += h[i]*pw[i];
      }
      wred3(dln2, wz2, xyhr);
      float pwn2, scpw;
      {
        const float dn   = snorm(dln2);
        const float artd = atanhf(clamp11(dn));
        const float wzn  = snorm(wz2);
        const float tpw  = tanhf(wzn/dn * artd);
        scpw = tpw/wzn; pwn2 = tpw*tpw;
        const float n = snorm(pwn2);
        if (n > PMAX_){ const float f = PMAX_/n; scpw *= f; pwn2 *= f*f; }
      }
#pragma unroll
      for (int i = 0; i < 4; i++) pw[i] *= scpw;
      const float xyh = xyhr * scpw;
      float hnew[4]; madd_vec<4>(h, hn2, pw, pwn2, xyh, hnew);
#pragma unroll
      for (int i = 0; i < 4; i++) h[i] = hnew[i];
      hn2 = wred(sq_part<4>(h));
      *(float4*)&hs[w*256 + j0] = make_float4(h[0],h[1],h[2],h[3]);
      if (lane == 0) scal[w*2 + 0] = hn2;
      unsigned short* srow = states + ((long)(brow0 + w)*128 + tt)*256 + j0;
      ushort4 su; su.x=f2bf(h[0]); su.y=f2bf(h[1]); su.z=f2bf(h[2]); su.w=f2bf(h[3]);
      *(ushort4*)srow = su;
    }
  }
}

// ---------------------------------------------------------------------------
// Char Mobius-RNN (unchanged)
// ---------------------------------------------------------------------------
__global__ __launch_bounds__(256) void char_rnn(
    const unsigned short* __restrict__ xgc,
    const float* __restrict__ Wc,
    const float* __restrict__ cb,
    float* __restrict__ cstates)
{
  const int wv = threadIdx.x >> 6, lane = threadIdx.x & 63;
  const int b = blockIdx.x*4 + wv;
  const int j0 = lane << 2;
  __shared__ __align__(16) float hs[4][256];
  float h[4] = {0.f,0.f,0.f,0.f};
  float hn2 = 0.f;
#pragma unroll
  for (int i = 0; i < 4; i++) hs[wv][j0+i] = 0.f;
  float cbv[4];
#pragma unroll
  for (int i = 0; i < 4; i++) cbv[i] = cb[j0+i];
  const float cb2 = wred(sq_part<4>(cbv));
  for (int t = 0; t < 16; t++){
    __syncthreads();
    const unsigned short* xr = xgc + ((long)t*256 + b)*256;
    float xgv[4];
    { const ushort4 u = *(const ushort4*)(xr + j0); xgv[0]=bf2f(u.x); xgv[1]=bf2f(u.y); xgv[2]=bf2f(u.z); xgv[3]=bf2f(u.w); }
    float a[4]={0.f,0.f,0.f,0.f};
#pragma unroll 2
    for (int k0 = 0; k0 < 256; k0 += 4){
      const float4 hk = *(const float4*)&hs[wv][k0];
#pragma unroll
      for (int kk = 0; kk < 4; kk++){
        const float hv = (&hk.x)[kk];
        const float4 w4 = *(const float4*)(Wc + (long)(k0+kk)*256 + j0);
        a[0] += hv*w4.x; a[1] += hv*w4.y; a[2] += hv*w4.z; a[3] += hv*w4.w;
      }
    }
    const float mxn2 = wred(sq_part<4>(a));
    float pn2; mt_project<4>(a, mxn2, hn2, &pn2);
    const float y2 = wred(sq_part<4>(xgv));
    const float xy = wred(dot_part<4>(a, xgv));
    float m1[4]; madd_vec<4>(a, pn2, xgv, y2, xy, m1);
    const float m1n2 = wred(sq_part<4>(m1));
    const float xyb  = wred(dot_part<4>(m1, cbv));
    float m2[4]; madd_vec<4>(m1, m1n2, cbv, cb2, xyb, m2);
    float m2n2 = wred(sq_part<4>(m2));
    project_vec<4>(m2, &m2n2);
#pragma unroll
    for (int i = 0; i < 4; i++) h[i] = m2[i];
    hn2 = m2n2;
    *(float4*)&hs[wv][j0] = make_float4(h[0],h[1],h[2],h[3]);
    *(float4*)(cstates + ((long)b*16 + t)*256 + j0) = make_float4(h[0],h[1],h[2],h[3]);
  }
}

// ---------------------------------------------------------------------------
// cc concat (unchanged)
// ---------------------------------------------------------------------------
__global__ __launch_bounds__(256) void cc_rowwise(const unsigned short* __restrict__ sf,
    const unsigned short* __restrict__ sb, const float* __restrict__ mxa,
    const float* __restrict__ mxb, const float* __restrict__ ccb,
    unsigned short* __restrict__ ctxo, int rowoff)
{
  const int wv = threadIdx.x >> 6, lane = threadIdx.x & 63;
  const int rloc = blockIdx.x*4 + wv;
  const long r = rowoff + rloc;
  float s = 0.f;
#pragma unroll
  for (int i = 0; i < 4; i++){ const float v = bf2f(sf[r*256 + i*64+lane]); s += v*v; }
  const float sfn2 = wred(s);
  s = 0.f;
#pragma unroll
  for (int i = 0; i < 4; i++){ const float v = bf2f(sb[r*256 + i*64+lane]); s += v*v; }
  const float sbn2 = wred(s);
  float A[8], Bv[8];
#pragma unroll
  for (int i = 0; i < 8; i++){ A[i]  = mxa[(long)rloc*512 + i*64+lane];
                               Bv[i] = mxb[(long)rloc*512 + i*64+lane]; }
  float pan2, pbn2;
  { const float n2 = wred(sq_part<8>(A));  mt_project<8>(A,  n2, sfn2, &pan2); }
  { const float n2 = wred(sq_part<8>(Bv)); mt_project<8>(Bv, n2, sbn2, &pbn2); }
  const float xy = wred(dot_part<8>(A, Bv));
  float M1[8]; madd_vec<8>(A, pan2, Bv, pbn2, xy, M1);
  const float m1n2 = wred(sq_part<8>(M1));
  float Cb[8];
#pragma unroll
  for (int i = 0; i < 8; i++) Cb[i] = ccb[i*64+lane];
  const float cb2 = wred(sq_part<8>(Cb));
  const float xyb = wred(dot_part<8>(M1, Cb));
  float M2[8]; madd_vec<8>(M1, m1n2, Cb, cb2, xyb, M2);
  float m2n2 = wred(sq_part<8>(M2));
  project_vec<8>(M2, &m2n2);
#pragma unroll
  for (int i = 0; i < 8; i++) ctxo[r*512 + i*64+lane] = f2bf(M2[i]);
}

// attn_emb = madd(ctx(bf16), pe) -> BF16 out + sqn of rounded
__global__ __launch_bounds__(256) void attn_add(const unsigned short* __restrict__ ctxv,
    const int* __restrict__ pos, const float* __restrict__ pet,
    unsigned short* __restrict__ oemb, float* __restrict__ osqn)
{
  const int wv = threadIdx.x >> 6, lane = threadIdx.x & 63;
  const long r = blockIdx.x*4 + wv;
  float X[8];
#pragma unroll
  for (int i = 0; i < 8; i++) X[i] = bf2f(ctxv[r*512 + i*64+lane]);
  const float x2 = wred(sq_part<8>(X));
  const int p = pos[r];
  float Y[8];
#pragma unroll
  for (int i = 0; i < 8; i++) Y[i] = pet[(long)p*512 + i*64+lane];
  const float y2 = wred(sq_part<8>(Y));
  const float xy = wred(dot_part<8>(X, Y));
  float O[8]; madd_vec<8>(X, x2, Y, y2, xy, O);
  float s = 0.f;
#pragma unroll
  for (int i = 0; i < 8; i++){
    const unsigned short u = f2bf(O[i]);
    oemb[r*512 + i*64+lane] = u;
    const float rv = bf2f(u);
    s += rv*rv;
  }
  s = wred(s);
  if (lane == 0) osqn[r] = s;
}

// mention variant (bf16 out)
__global__ __launch_bounds__(256) void attn_add_m(const float* __restrict__ mvv,
    const int* __restrict__ mentions, const float* __restrict__ pet,
    unsigned short* __restrict__ oemb, float* __restrict__ osqn)
{
  const int wv = threadIdx.x >> 6, lane = threadIdx.x & 63;
  const long r = blockIdx.x*4 + wv;
  float X[8];
#pragma unroll
  for (int i = 0; i < 8; i++) X[i] = mvv[r*512 + i*64+lane];
  const float x2 = wred(sq_part<8>(X));
  const int men = mentions[r];
  const int p = (men > 0) ? (int)(r & 7) + 1 : 0;
  float Y[8];
#pragma unroll
  for (int i = 0; i < 8; i++) Y[i] = pet[(long)p*512 + i*64+lane];
  const float y2 = wred(sq_part<8>(Y));
  const float xy = wred(dot_part<8>(X, Y));
  float O[8]; madd_vec<8>(X, x2, Y, y2, xy, O);
  float s = 0.f;
#pragma unroll
  for (int i = 0; i < 8; i++){
    const unsigned short u = f2bf(O[i]);
    oemb[r*512 + i*64+lane] = u;
    const float rv = bf2f(u);
    s += rv*rv;
  }
  s = wred(s);
  if (lane == 0) osqn[r] = s;
}

// q/k projection + pdist (unchanged)
__global__ __launch_bounds__(256) void qk_pdist(const float* __restrict__ mxq,
    const float* __restrict__ mxk, const float* __restrict__ sqn,
    const float* __restrict__ bq, const float* __restrict__ bk,
    float* __restrict__ dout)
{
  const int wv = threadIdx.x >> 6, lane = threadIdx.x & 63;
  const int r = blockIdx.x*4 + wv;
  const float xn2 = sqn[r];
  float Q[8];
#pragma unroll
  for (int i = 0; i < 8; i++) Q[i] = mxq[(long)r*512 + i*64+lane];
  { const float n2 = wred(sq_part<8>(Q)); float pn2; mt_project<8>(Q, n2, xn2, &pn2);
    float Bq[8];
#pragma unroll
    for (int i = 0; i < 8; i++) Bq[i] = bq[i*64+lane];
    const float b2 = wred(sq_part<8>(Bq));
    const float xy = wred(dot_part<8>(Q, Bq));
    float O[8]; madd_vec<8>(Q, pn2, Bq, b2, xy, O);
#pragma unroll
    for (int i = 0; i < 8; i++) Q[i] = O[i];
  }
  float qn2 = wred(sq_part<8>(Q));
  project_vec<8>(Q, &qn2);
  float Kv[8];
#pragma unroll
  for (int i = 0; i < 8; i++) Kv[i] = mxk[(long)r*512 + i*64+lane];
  { const float n2 = wred(sq_part<8>(Kv)); float pn2; mt_project<8>(Kv, n2, xn2, &pn2);
    float Bk[8];
#pragma unroll
    for (int i = 0; i < 8; i++) Bk[i] = bk[i*64+lane];
    const float b2 = wred(sq_part<8>(Bk));
    const float xy = wred(dot_part<8>(Kv, Bk));
    float O[8]; madd_vec<8>(Kv, pn2, Bk, b2, xy, O);
#pragma unroll
    for (int i = 0; i < 8; i++) Kv[i] = O[i];
  }
  float kn2 = wred(sq_part<8>(Kv));
  project_vec<8>(Kv, &kn2);
  float NQ[8];
#pragma unroll
  for (int i = 0; i < 8; i++) NQ[i] = -Q[i];
  const float xy = wred(dot_part<8>(NQ, Kv));
  float Z[8]; madd_vec<8>(NQ, qn2, Kv, kn2, xy, Z);
  const float zn2 = wred(sq_part<8>(Z));
  const float d = 2.f * atanhf(clamp11(snorm(zn2)));
  if (lane == 0) dout[r] = d;
}

__global__ __launch_bounds__(256) void softmax128(const float* __restrict__ d,
    const float* __restrict__ beta, float* __restrict__ w)
{
  const int wv = threadIdx.x >> 6, lane = threadIdx.x & 63;
  const int b = blockIdx.x*4 + wv;
  const float bt = beta[0];
  const float x0 = -bt * d[b*128 + lane];
  const float x1 = -bt * d[b*128 + 64 + lane];
  const float m = wredmax(fmaxf(x0, x1));
  const float e0 = expf(x0 - m), e1 = expf(x1 - m);
  const float s = wred(e0 + e1);
  w[b*128 + lane]      = e0 / s;
  w[b*128 + 64 + lane] = e1 / s;
}

__global__ void softmax8(const float* __restrict__ d, const float* __restrict__ beta,
                         float* __restrict__ w)
{
  const int b = threadIdx.x;   // 256
  const float bt = beta[0];
  float x[8]; float m = -1e30f;
#pragma unroll
  for (int i = 0; i < 8; i++){ x[i] = -bt * d[b*8+i]; m = fmaxf(m, x[i]); }
  float s = 0.f;
#pragma unroll
  for (int i = 0; i < 8; i++){ x[i] = expf(x[i]-m); s += x[i]; }
#pragma unroll
  for (int i = 0; i < 8; i++) w[b*8+i] = x[i] / s;
}

// weighted gyromidpoint via Klein model; one wave per batch row (small Lseq)
template<int NPL, bool BF16V, bool HASW>
__global__ __launch_bounds__(256) void midpoint_kernel(const void* __restrict__ vals,
    const float* __restrict__ wts, float* __restrict__ outp, int Lseq)
{
  const int wv = threadIdx.x >> 6, lane = threadIdx.x & 63;
  const int b = blockIdx.x*4 + wv;
  const int D = NPL*64;
  float num[NPL];
#pragma unroll
  for (int i = 0; i < NPL; i++) num[i] = 0.f;
  float den = 0.f;
  for (int l = 0; l < Lseq; l++){
    const long base = ((long)b*Lseq + l)*D;
    float v[NPL]; float s = 0.f;
#pragma unroll
    for (int i = 0; i < NPL; i++){
      v[i] = BF16V ? bf2f(((const unsigned short*)vals)[base + i*64+lane])
                   : ((const float*)vals)[base + i*64+lane];
      s += v[i]*v[i];
    }
    const float v2 = wred(s);
    const float f = 2.f/(1.f + v2);
    const float kl2 = v2*f*f;
    const float gamma = 1.f/sqrtf(fmaxf(1.f - kl2, EPS_));
    const float wgt = HASW ? wts[b*Lseq + l] : 1.f;
    const float wg = wgt*gamma;
#pragma unroll
    for (int i = 0; i < NPL; i++) num[i] += wg*(f*v[i]);
    den += wg;
  }
  den = fmaxf(den, EPS_);
  float x[NPL]; float s = 0.f;
#pragma unroll
  for (int i = 0; i < NPL; i++){ x[i] = num[i]/den; s += x[i]*x[i]; }
  const float k2 = wred(s);
  const float inv = 1.f/(1.f + sqrtf(fmaxf(1.f - k2, EPS_)));
#pragma unroll
  for (int i = 0; i < NPL; i++) outp[(long)b*D + i*64+lane] = x[i]*inv;
}

// wide gyromidpoint for ctx (unchanged)
__global__ __launch_bounds__(512) void midpoint_wide(
    const unsigned short* __restrict__ vals,
    const float* __restrict__ wts,
    float* __restrict__ outp)
{
  __shared__ float pnum[8][512];
  __shared__ float pden[8];
  __shared__ float red[512];
  __shared__ float kk2[1];
  const int b = blockIdx.x;
  const int tid = threadIdx.x;
  const int w = tid >> 6, lane = tid & 63;
  float num[8] = {0.f,0.f,0.f,0.f,0.f,0.f,0.f,0.f};
  float den = 0.f;
  for (int l = w; l < 128; l += 8){
    const long base = ((long)b*128 + l)*512;
    float v[8]; float s = 0.f;
#pragma unroll
    for (int i = 0; i < 8; i++){
      v[i] = bf2f(vals[base + i*64 + lane]);
      s += v[i]*v[i];
    }
    const float v2 = wred(s);
    const float f = 2.f/(1.f + v2);
    const float kl2 = v2*f*f;
    const float gamma = 1.f/sqrtf(fmaxf(1.f - kl2, EPS_));
    const float wg = wts[b*128 + l]*gamma;
#pragma unroll
    for (int i = 0; i < 8; i++) num[i] += wg*(f*v[i]);
    den += wg;
  }
#pragma unroll
  for (int i = 0; i < 8; i++) pnum[w][i*64 + lane] = num[i];
  if (lane == 0) pden[w] = den;
  __syncthreads();
  float nsum = 0.f, dsum = 0.f;
#pragma unroll
  for (int p = 0; p < 8; p++){ nsum += pnum[p][tid]; dsum += pden[p]; }
  dsum = fmaxf(dsum, EPS_);
  const float x = nsum/dsum;
  red[tid] = x*x;
  __syncthreads();
  if (tid < 64){
    float s2 = 0.f;
#pragma unroll
    for (int i = 0; i < 8; i++) s2 += red[tid + i*64];
    s2 = wred(s2);
    if (tid == 0) kk2[0] = s2;
  }
  __syncthreads();
  const float k2 = kk2[0];
  const float inv = 1.f/(1.f + sqrtf(fmaxf(1.f - k2, EPS_)));
  outp[(long)b*512 + tid] = x*inv;
}

// mention w2s mobius_linear with tanh nonlinearity (unchanged)
__global__ __launch_bounds__(256) void mv_rowwise(const float* __restrict__ mx,
    const float* __restrict__ xsqn, const float* __restrict__ bb, float* __restrict__ outp)
{
  const int wv = threadIdx.x >> 6, lane = threadIdx.x & 63;
  const long r = blockIdx.x*4 + wv;
  float M[8];
#pragma unroll
  for (int i = 0; i < 8; i++) M[i] = mx[r*512 + i*64+lane];
  { const float n2 = wred(sq_part<8>(M)); float pn2; mt_project<8>(M, n2, xsqn[r], &pn2);
    float Bv[8];
#pragma unroll
    for (int i = 0; i < 8; i++) Bv[i] = bb[i*64+lane];
    const float b2 = wred(sq_part<8>(Bv));
    const float xy = wred(dot_part<8>(M, Bv));
    float O[8]; madd_vec<8>(M, pn2, Bv, b2, xy, O);
#pragma unroll
    for (int i = 0; i < 8; i++) M[i] = O[i];
  }
  float on2 = wred(sq_part<8>(M));
  project_vec<8>(M, &on2);
  { const float n = snorm(on2);
    const float fac = atanhf(clamp11(n))/n;
#pragma unroll
    for (int i = 0; i < 8; i++) M[i] = tanhf(fac*M[i]); }
  const float un2 = wred(sq_part<8>(M));
  { const float n = snorm(un2);
    const float fac = tanhf(n)/n;
    float en2 = fac*fac*un2;
#pragma unroll
    for (int i = 0; i < 8; i++) M[i] *= fac;
    project_vec<8>(M, &en2); }
#pragma unroll
  for (int i = 0; i < 8; i++) outp[r*512 + i*64+lane] = M[i];
}

// joint concat (unchanged)
__global__ __launch_bounds__(256) void final_rowwise(const float* __restrict__ jm,
    const float* __restrict__ jc, const float* __restrict__ jch,
    const float* __restrict__ mvec, const float* __restrict__ cvec,
    const float* __restrict__ chvec, const float* __restrict__ fcb,
    float* __restrict__ joint)
{
  const int wv = threadIdx.x >> 6, lane = threadIdx.x & 63;
  const long b = blockIdx.x*4 + wv;
  float s;
  s = 0.f; for (int i = 0; i < 8; i++){ const float v = mvec[b*512 + i*64+lane]; s += v*v; }
  const float mn2 = wred(s);
  s = 0.f; for (int i = 0; i < 8; i++){ const float v = cvec[b*512 + i*64+lane]; s += v*v; }
  const float cn2 = wred(s);
  s = 0.f; for (int i = 0; i < 4; i++){ const float v = chvec[b*256 + i*64+lane]; s += v*v; }
  const float chn2 = wred(s);
  float A[20];
#pragma unroll
  for (int i = 0; i < 20; i++) A[i] = jm[b*1280 + i*64+lane];
  float an2;
  { const float n2 = wred(sq_part<20>(A)); mt_project<20>(A, n2, mn2, &an2); }
  float T[20];
#pragma unroll
  for (int i = 0; i < 20; i++) T[i] = jc[b*1280 + i*64+lane];
  float tn2;
  { const float n2 = wred(sq_part<20>(T)); mt_project<20>(T, n2, cn2, &tn2); }
  { const float xy = wred(dot_part<20>(A, T));
    float O[20]; madd_vec<20>(A, an2, T, tn2, xy, O);
#pragma unroll
    for (int i = 0; i < 20; i++) A[i] = O[i];
    an2 = wred(sq_part<20>(A)); }
#pragma unroll
  for (int i = 0; i < 20; i++) T[i] = jch[b*1280 + i*64+lane];
  { const float n2 = wred(sq_part<20>(T)); mt_project<20>(T, n2, chn2, &tn2); }
  { const float xy = wred(dot_part<20>(A, T));
    float O[20]; madd_vec<20>(A, an2, T, tn2, xy, O);
#pragma unroll
    for (int i = 0; i < 20; i++) A[i] = O[i];
    an2 = wred(sq_part<20>(A)); }
#pragma unroll
  for (int i = 0; i < 20; i++) T[i] = fcb[i*64+lane];
  tn2 = wred(sq_part<20>(T));
  { const float xy = wred(dot_part<20>(A, T));
    float O[20]; madd_vec<20>(A, an2, T, tn2, xy, O);
#pragma unroll
    for (int i = 0; i < 20; i++) A[i] = O[i];
    an2 = wred(sq_part<20>(A)); }
  project_vec<20>(A, &an2);
#pragma unroll
  for (int i = 0; i < 20; i++) joint[b*1280 + i*64+lane] = A[i];
}

// hyperbolic MLR head (unchanged)
__global__ __launch_bounds__(256) void mlr_kernel(const float* __restrict__ joint,
    const float* __restrict__ P, const float* __restrict__ A, float* __restrict__ outp)
{
  const int wv = threadIdx.x >> 6, lane = threadIdx.x & 63;
  const int pair = blockIdx.x*4 + wv;
  const long b = pair >> 7, c = pair & 127;
  float Pv[20], J[20];
#pragma unroll
  for (int i = 0; i < 20; i++){
    Pv[i] = -P[c*1280 + i*64+lane];
    J[i]  = joint[b*1280 + i*64+lane];
  }
  const float p2 = wred(sq_part<20>(Pv));
  const float j2 = wred(sq_part<20>(J));
  const float xy = wred(dot_part<20>(Pv, J));
  float Z[20]; madd_vec<20>(Pv, p2, J, j2, xy, Z);
  float sza = 0.f, sz2 = 0.f, sa2 = 0.f;
#pragma unroll
  for (int i = 0; i < 20; i++){
    const float a = A[c*1280 + i*64+lane];
    sza += Z[i]*a; sz2 += Z[i]*Z[i]; sa2 += a*a;
  }
  float za = sza, z2 = sz2, a2 = sa2;
  wred3(za, z2, a2);
  const float an = sqrtf(fmaxf(a2, EPS_));
  const float v = 2.f*za / (fmaxf(1.f - z2, EPS_)*an);
  if (lane == 0) outp[pair] = 2.f*an*asinhf(v);
}

// ---------------------------------------------------------------------------
extern "C" void kernel_launch(void* const* d_in, const int* in_sizes, int n_in,
                              void* d_out, int out_size, void* d_ws, size_t ws_size,
                              hipStream_t stream)
{
  (void)in_sizes; (void)n_in; (void)out_size;
  const int*   context   = (const int*)  d_in[0];
  const int*   ctx_position=(const int*) d_in[1];
  const int*   mentions  = (const int*)  d_in[2];
  const int*   mchars    = (const int*)  d_in[3];
  const float* word_lut  = (const float*)d_in[4];
  const float* char_lut  = (const float*)d_in[5];
  const float* gf_Wih    = (const float*)d_in[6];
  const float* gf_Whh    = (const float*)d_in[7];
  const float* gf_b      = (const float*)d_in[8];
  const float* gb_Wih    = (const float*)d_in[9];
  const float* gb_Whh    = (const float*)d_in[10];
  const float* gb_b      = (const float*)d_in[11];
  const float* w2s_W     = (const float*)d_in[12];
  const float* w2s_b     = (const float*)d_in[13];
  const float* men_pos   = (const float*)d_in[14];
  const float* men_Wq    = (const float*)d_in[15];
  const float* men_bq    = (const float*)d_in[16];
  const float* men_Wk    = (const float*)d_in[17];
  const float* men_bk    = (const float*)d_in[18];
  const float* men_beta  = (const float*)d_in[19];
  const float* char_W    = (const float*)d_in[20];
  const float* char_U    = (const float*)d_in[21];
  const float* char_b    = (const float*)d_in[22];
  const float* cc_Wa     = (const float*)d_in[23];
  const float* cc_Wb     = (const float*)d_in[24];
  const float* cc_bias   = (const float*)d_in[25];
  const float* ctx_pos_t = (const float*)d_in[26];
  const float* ctx_Wq    = (const float*)d_in[27];
  const float* ctx_bq    = (const float*)d_in[28];
  const float* ctx_Wk    = (const float*)d_in[29];
  const float* ctx_bk    = (const float*)d_in[30];
  const float* ctx_beta  = (const float*)d_in[31];
  const float* fc_Wm     = (const float*)d_in[32];
  const float* fc_Wc     = (const float*)d_in[33];
  const float* fc_Wch    = (const float*)d_in[34];
  const float* fc_bias   = (const float*)d_in[35];
  const float* mlr_p     = (const float*)d_in[36];
  const float* mlr_a     = (const float*)d_in[37];
  float* out = (float*)d_out;

  // ---- workspace bump allocator ----
  char* wsb = (char*)d_ws;
  size_t off = 0;
  auto alloc = [&](size_t bytes) -> void* {
    void* p = wsb + off;
    off += (bytes + 255) & ~(size_t)255;
    return p;
  };
  float* WtHH = (float*)alloc(2UL*256*768*4);
  unsigned short* Wrz16 = (unsigned short*)alloc(2UL*256*512*2);
  unsigned short* Wh16  = (unsigned short*)alloc(2UL*256*256*2);
  unsigned short* WihP  = (unsigned short*)alloc(2UL*768*320*2);
  unsigned short* ctxWqP= (unsigned short*)alloc(512UL*512*2);
  unsigned short* ctxWkP= (unsigned short*)alloc(512UL*512*2);
  unsigned short* ccWaP = (unsigned short*)alloc(512UL*256*2);
  unsigned short* ccWbP = (unsigned short*)alloc(512UL*256*2);
  unsigned short* menWqP= (unsigned short*)alloc(512UL*512*2);
  unsigned short* menWkP= (unsigned short*)alloc(512UL*512*2);
  unsigned short* w2sP  = (unsigned short*)alloc(512UL*320*2);
  unsigned short* charUP= (unsigned short*)alloc(256UL*256*2);
  int*   ctxidx = (int*)alloc(32768UL*4);
  int*   chidx  = (int*)alloc(4096UL*4);
  float* xsqn   = (float*)alloc(32768UL*4);
  float* msqn   = (float*)alloc(2048UL*4);
  float* chsqn  = (float*)alloc(4096UL*4);
  unsigned short* xg = (unsigned short*)alloc(2UL*32768*768*2);
  float* xgn2 = (float*)alloc(2UL*32768*3*4);
  float* chn2d = (float*)alloc(4096UL*4);
  unsigned short* states_f = (unsigned short*)alloc(32768UL*256*2);
  unsigned short* states_b = (unsigned short*)alloc(32768UL*256*2);
  unsigned short* ctxv = (unsigned short*)alloc(32768UL*512*2);
  float* attn_sqn = (float*)alloc(32768UL*4);
  float* dctx = (float*)alloc(32768UL*4);
  float* wctx = (float*)alloc(32768UL*4);
  float* ctx_vec = (float*)alloc(256UL*512*4);
  float* mxbuf = (float*)alloc(2UL*8192*512*4);
  float* mv = (float*)alloc(2048UL*512*4);
  unsigned short* attn_embm = (unsigned short*)alloc(2048UL*512*2);
  float* amsqn = (float*)alloc(2048UL*4);
  float* dm = (float*)alloc(2048UL*4);
  float* wm = (float*)alloc(2048UL*4);
  float* mention_vec = (float*)alloc(256UL*512*4);
  unsigned short* xgc = (unsigned short*)alloc(4096UL*256*2);
  float* char_states = (float*)alloc(4096UL*256*4);
  float* char_vec = (float*)alloc(256UL*256*4);
  float* joint = (float*)alloc(256UL*1280*4);
  if (off > ws_size) return;
  unsigned short* attn_embc = xg;                  // overlay: xg dead after GRU
  float* mxh0 = mxbuf;
  float* mxh1 = mxbuf + 8192UL*512;

  // ---- weight transposes + bf16 packs ----
  transpose_k<<<dim3(8,24), 256,0,stream>>>(gf_Whh, WtHH,            768, 256);
  transpose_k<<<dim3(8,24), 256,0,stream>>>(gb_Whh, WtHH + 256*768,  768, 256);
  pack_whh16<<<1536,256,0,stream>>>(WtHH, Wrz16, Wh16);
  pack_wih<<<1920,256,0,stream>>>(gf_Wih, gb_Wih, WihP);
  packT16<<<dim3(16,16),256,0,stream>>>(ctx_Wq, ctxWqP, 512, 512, 512);
  packT16<<<dim3(16,16),256,0,stream>>>(ctx_Wk, ctxWkP, 512, 512, 512);
  packT16<<<dim3(8,16), 256,0,stream>>>(cc_Wa,  ccWaP,  256, 512, 256);
  packT16<<<dim3(8,16), 256,0,stream>>>(cc_Wb,  ccWbP,  256, 512, 256);
  packT16<<<dim3(16,16),256,0,stream>>>(men_Wq, menWqP, 512, 512, 512);
  packT16<<<dim3(16,16),256,0,stream>>>(men_Wk, menWkP, 512, 512, 512);
  packT16<<<dim3(10,16),256,0,stream>>>(w2s_W,  w2sP,   300, 512, 320);
  packT16<<<dim3(8,8),  256,0,stream>>>(char_U, charUP, 256, 256, 256);

  // ---- gather indices + input sqn ----
  build_idx<<<144,256,0,stream>>>(context, mchars, ctxidx, chidx);
  sqn_gather<<<8192,256,0,stream>>>(word_lut, ctxidx, 300, xsqn);
  sqn_gather<<<512, 256,0,stream>>>(word_lut, mentions, 300, msqn);
  sqn_gather<<<1024,256,0,stream>>>(char_lut, chidx, 256, chsqn);

  // ---- GRU input precompute: xg[dir] = mobius_matvec(emb, Wih^T), bf16 ----
  for (int d2 = 0; d2 < 2; d2++){
    const unsigned short* wihp = WihP + (size_t)d2*768*320;
    for (int c = 0; c < 4; c++){
      mfma_mm<1><<<dim3(6,64),256,0,stream>>>(word_lut, ctxidx + c*8192, wihp,
                                              mxbuf, 8192, 768, 300, 320);
      xg_transform<<<6144,256,0,stream>>>(mxbuf, xsqn + c*8192,
          xg + ((size_t)d2*32768 + (size_t)c*8192)*768,
          xgn2 + ((size_t)d2*32768 + (size_t)c*8192)*3, 3);
    }
  }

  // ---- bidirectional Mobius GRU (unchanged) ----
  (void)hipFuncSetAttribute((const void*)gru_kernel,
      hipFuncAttributeMaxDynamicSharedMemorySize, GRU_LDS_BYTES);
  gru_kernel<<<256,256,GRU_LDS_BYTES,stream>>>(xg, xgn2, Wrz16, Wh16,
                                               gf_b, gb_b, states_f, states_b);

  // ---- mobius concat of directions -> ctx (bf16) ----
  for (int c = 0; c < 4; c++){
    mfma_mm<2><<<dim3(4,64),256,0,stream>>>(states_f + (size_t)c*8192*256, nullptr,
                                            ccWaP, mxh0, 8192, 512, 256, 256);
    mfma_mm<2><<<dim3(4,64),256,0,stream>>>(states_b + (size_t)c*8192*256, nullptr,
                                            ccWbP, mxh1, 8192, 512, 256, 256);
    cc_rowwise<<<2048,256,0,stream>>>(states_f, states_b, mxh0, mxh1, cc_bias,
                                      ctxv, c*8192);
  }

  // ---- context distance attention ----
  attn_add<<<8192,256,0,stream>>>(ctxv, ctx_position, ctx_pos_t, attn_embc, attn_sqn);
  for (int c = 0; c < 4; c++){
    mfma_mm<2><<<dim3(4,64),256,0,stream>>>(attn_embc + (size_t)c*8192*512, nullptr,
                                            ctxWqP, mxh0, 8192, 512, 512, 512);
    mfma_mm<2><<<dim3(4,64),256,0,stream>>>(attn_embc + (size_t)c*8192*512, nullptr,
                                            ctxWkP, mxh1, 8192, 512, 512, 512);
    qk_pdist<<<2048,256,0,stream>>>(mxh0, mxh1, attn_sqn + c*8192, ctx_bq, ctx_bk,
                                    dctx + c*8192);
  }
  softmax128<<<64,256,0,stream>>>(dctx, ctx_beta, wctx);
  midpoint_wide<<<256,512,0,stream>>>(ctxv, wctx, ctx_vec);

  // ---- mention encoder ----
  mfma_mm<1><<<dim3(4,16),256,0,stream>>>(word_lut, mentions, w2sP, mxh0,
                                          2048, 512, 300, 320);
  mv_rowwise<<<512,256,0,stream>>>(mxh0, msqn, w2s_b, mv);
  attn_add_m<<<512,256,0,stream>>>(mv, mentions, men_pos, attn_embm, amsqn);
  mfma_mm<2><<<dim3(4,16),256,0,stream>>>(attn_embm, nullptr, menWqP, mxh0,
                                          2048, 512, 512, 512);
  mfma_mm<2><<<dim3(4,16),256,0,stream>>>(attn_embm, nullptr, menWkP, mxh1,
                                          2048, 512, 512, 512);
  qk_pdist<<<512,256,0,stream>>>(mxh0, mxh1, amsqn, men_bq, men_bk, dm);
  softmax8<<<1,256,0,stream>>>(dm, men_beta, wm);
  midpoint_kernel<8,false,true><<<64,256,0,stream>>>(mv, wm, mention_vec, 8);

  // ---- char encoder ----
  mfma_mm<1><<<dim3(2,32),256,0,stream>>>(char_lut, chidx, charUP, mxh0,
                                          4096, 256, 256, 256);
  xg_transform<<<1024,256,0,stream>>>(mxh0, chsqn, xgc, chn2d, 1);
  char_rnn<<<64,256,0,stream>>>(xgc, char_W, char_b, char_states);
  midpoint_kernel<4,false,false><<<64,256,0,stream>>>(char_states, nullptr, char_vec, 16);

  // ---- full mobius concat + MLR (small, f32 path) ----
  float* jm = mxh0;
  float* jc = mxh0 + 256UL*1280;
  float* jch = mxh0 + 2UL*256*1280;
  mm_kernel<0><<<dim3(10,2),256,0,stream>>>(mention_vec, nullptr, fc_Wm, jm, 256, 1280, 512);
  mm_kernel<0><<<dim3(10,2),256,0,stream>>>(ctx_vec,     nullptr, fc_Wc, jc, 256, 1280, 512);
  mm_kernel<0><<<dim3(10,2),256,0,stream>>>(char_vec,    nullptr, fc_Wch, jch, 256, 1280, 256);
  final_rowwise<<<64,256,0,stream>>>(jm, jc, jch, mention_vec, ctx_vec, char_vec,
                                     fc_bias, joint);
  mlr_kernel<<<8192,256,0,stream>>>(joint, mlr_p, mlr_a, out);
}

// Round 8
// 2807.231 us; speedup vs baseline: 3.3454x; 1.0762x over previous
//
#include <hip/hip_runtime.h>
#include <cstddef>
#include <cstdint>

// ---------------------------------------------------------------------------
// Hyperbolic (Poincare-ball) entity-typing forward pass, MI355X / gfx950.
// Round 8: GRU v7 — 512-thread blocks (8 waves), staging spread over 8 waves
// (2x outstanding loads), phase FMA split 2x finer; chain math identical.
// Non-GRU path unchanged from round 7 (passing, MFMA GEMMs).
// ---------------------------------------------------------------------------

#define EPS_  1e-15f
#define PMAX_ 0.99999f    // 1 - 1e-5

typedef __attribute__((ext_vector_type(8))) short bf16x8;
typedef __attribute__((ext_vector_type(4))) float f32x4;
typedef __attribute__((ext_vector_type(8))) unsigned short us8;

__device__ __forceinline__ float wred(float v){
#pragma unroll
  for (int o = 32; o; o >>= 1) v += __shfl_xor(v, o, 64);
  return v;
}
__device__ __forceinline__ void wred2(float& a, float& b){
#pragma unroll
  for (int o = 32; o; o >>= 1){ a += __shfl_xor(a, o, 64); b += __shfl_xor(b, o, 64); }
}
__device__ __forceinline__ void wred3(float& a, float& b, float& c){
#pragma unroll
  for (int o = 32; o; o >>= 1){
    a += __shfl_xor(a, o, 64); b += __shfl_xor(b, o, 64); c += __shfl_xor(c, o, 64);
  }
}
__device__ __forceinline__ void wred4(float& a, float& b, float& c, float& d){
#pragma unroll
  for (int o = 32; o; o >>= 1){
    a += __shfl_xor(a, o, 64); b += __shfl_xor(b, o, 64);
    c += __shfl_xor(c, o, 64); d += __shfl_xor(d, o, 64);
  }
}
__device__ __forceinline__ float wredmax(float v){
#pragma unroll
  for (int o = 32; o; o >>= 1) v = fmaxf(v, __shfl_xor(v, o, 64));
  return v;
}
__device__ __forceinline__ float snorm(float s){ return sqrtf(fmaxf(s, EPS_)); }
__device__ __forceinline__ float clamp11(float x){
  return fminf(fmaxf(x, -1.f + 1e-7f), 1.f - 1e-7f);
}
__device__ __forceinline__ float bf2f(unsigned short u){
  union { unsigned int i; float f; } v; v.i = ((unsigned int)u) << 16; return v.f;
}
__device__ __forceinline__ unsigned short f2bf(float f){
  union { float f; unsigned int i; } v; v.f = f;
  unsigned int x = v.i;
  x += 0x7fffu + ((x >> 16) & 1u);   // RNE
  return (unsigned short)(x >> 16);
}
__device__ __forceinline__ float bflo(unsigned u){
  union { unsigned i; float f; } v; v.i = u << 16; return v.f;
}
__device__ __forceinline__ float bfhi(unsigned u){
  union { unsigned i; float f; } v; v.i = u & 0xffff0000u; return v.f;
}

template<int N>
__device__ __forceinline__ float sq_part(const float* a){
  float s = 0.f;
#pragma unroll
  for (int i = 0; i < N; i++) s += a[i]*a[i];
  return s;
}
template<int N>
__device__ __forceinline__ float dot_part(const float* a, const float* b){
  float s = 0.f;
#pragma unroll
  for (int i = 0; i < N; i++) s += a[i]*b[i];
  return s;
}
template<int N>
__device__ __forceinline__ void madd_vec(const float* x, float x2, const float* y,
                                         float y2, float xy, float* o){
  const float c1 = 1.f + 2.f*xy + y2;
  const float c2 = 1.f - x2;
  const float inv = 1.f / fmaxf(1.f + 2.f*xy + x2*y2, EPS_);
#pragma unroll
  for (int i = 0; i < N; i++) o[i] = (c1*x[i] + c2*y[i]) * inv;
}
template<int N>
__device__ __forceinline__ void mt_project(float* v, float mxn2, float xn2, float* n2out){
  const float xn  = snorm(xn2);
  const float mxn = snorm(mxn2);
  const float t   = tanhf(mxn/xn * atanhf(clamp11(xn)));
  float sc = t/mxn;
  float n2 = sc*sc*mxn2;
  const float n = snorm(n2);
  if (n > PMAX_){ const float s = PMAX_/n; sc *= s; n2 *= s*s; }
#pragma unroll
  for (int i = 0; i < N; i++) v[i] *= sc;
  *n2out = n2;
}
__device__ __forceinline__ void mt_scale(float mxn2, float xn, float art,
                                         float* sc, float* n2){
  const float mxn = snorm(mxn2);
  const float t   = tanhf(mxn/xn * art);
  float s  = t/mxn;
  float nn = t*t;
  const float n = snorm(nn);
  if (n > PMAX_){ const float f = PMAX_/n; s *= f; nn *= f*f; }
  *sc = s; *n2 = nn;
}
template<int N>
__device__ __forceinline__ void project_vec(float* v, float* n2io){
  float n2 = *n2io;
  const float n = snorm(n2);
  if (n > PMAX_){
    const float s = PMAX_/n;
#pragma unroll
    for (int i = 0; i < N; i++) v[i] *= s;
    n2 *= s*s;
  }
  *n2io = n2;
}

// async 16B global->LDS: linear wave-uniform-base + lane*16
__device__ __forceinline__ void gll16(const void* g, void* l){
  __builtin_amdgcn_global_load_lds(
      (const __attribute__((address_space(1))) void*)g,
      (__attribute__((address_space(3))) void*)l, 16, 0, 0);
}
// stage 64KB with 512 threads (8 waves x 8 x 16B/lane), linear layout
__device__ __forceinline__ void stage64k8(const void* gsrc, float* lbase, int w, int lane){
#pragma unroll
  for (int i = 0; i < 8; i++){
    const char* g = (const char*)gsrc + (size_t)((i*8 + w)*64 + lane)*16;
    char* l = (char*)lbase + (size_t)((i*8 + w)*64)*16;
    gll16(g, l);
  }
}

// ---------------------------------------------------------------------------
// MFMA bf16 GEMM (unchanged from round 7)
// ---------------------------------------------------------------------------
template<int AMODE>
__global__ __launch_bounds__(256) void mfma_mm(const void* __restrict__ Aptr,
    const int* __restrict__ idx, const unsigned short* __restrict__ Bt,
    float* __restrict__ Cm, int M, int N, int K, int Kp)
{
  __shared__ __align__(16) unsigned short As[128][40];
  __shared__ __align__(16) unsigned short Bs[128][40];
  const int tid = threadIdx.x;
  const int n0 = blockIdx.x * 128;
  const int m0 = blockIdx.y * 128;
  const int srow = tid >> 1, shalf = tid & 1;
  const int wv = tid >> 6, lane = tid & 63;
  const int wm = wv >> 1, wn = wv & 1;
  const int lr = lane & 15, lk = lane >> 4;

  long arow;
  if constexpr (AMODE == 1) arow = (long)idx[m0 + srow] * K;
  else                      arow = (long)(m0 + srow) * K;

  f32x4 acc[4][4];
#pragma unroll
  for (int mf = 0; mf < 4; mf++)
#pragma unroll
    for (int nf = 0; nf < 4; nf++) acc[mf][nf] = (f32x4){0.f,0.f,0.f,0.f};

  for (int k0 = 0; k0 < Kp; k0 += 32){
    const int kb = k0 + shalf*16;
    unsigned short av[16];
    if constexpr (AMODE == 1){
      const float* ar = (const float*)Aptr + arow;
      if (kb + 16 <= K){
#pragma unroll
        for (int v = 0; v < 4; v++){
          const float4 f = *(const float4*)(ar + kb + v*4);
          av[v*4+0]=f2bf(f.x); av[v*4+1]=f2bf(f.y);
          av[v*4+2]=f2bf(f.z); av[v*4+3]=f2bf(f.w);
        }
      } else {
#pragma unroll
        for (int v = 0; v < 16; v++){
          const int col = kb + v;
          av[v] = (col < K) ? f2bf(ar[col]) : (unsigned short)0;
        }
      }
    } else {
      const unsigned short* ar = (const unsigned short*)Aptr + arow + kb;
      const us8 u0 = *(const us8*)ar;
      const us8 u1 = *(const us8*)(ar + 8);
#pragma unroll
      for (int v = 0; v < 8; v++){ av[v] = u0[v]; av[8+v] = u1[v]; }
    }
    unsigned short bvv[16];
    {
      const unsigned short* br = Bt + (long)(n0 + srow)*Kp + kb;
      const us8 u0 = *(const us8*)br;
      const us8 u1 = *(const us8*)(br + 8);
#pragma unroll
      for (int v = 0; v < 8; v++){ bvv[v] = u0[v]; bvv[8+v] = u1[v]; }
    }
    __syncthreads();
    *(us8*)&As[srow][shalf*16]   = *(const us8*)&av[0];
    *(us8*)&As[srow][shalf*16+8] = *(const us8*)&av[8];
    *(us8*)&Bs[srow][shalf*16]   = *(const us8*)&bvv[0];
    *(us8*)&Bs[srow][shalf*16+8] = *(const us8*)&bvv[8];
    __syncthreads();
    bf16x8 af[4], bfr[4];
#pragma unroll
    for (int mf = 0; mf < 4; mf++)
      af[mf] = *(const bf16x8*)&As[wm*64 + mf*16 + lr][lk*8];
#pragma unroll
    for (int nf = 0; nf < 4; nf++)
      bfr[nf] = *(const bf16x8*)&Bs[wn*64 + nf*16 + lr][lk*8];
#pragma unroll
    for (int mf = 0; mf < 4; mf++)
#pragma unroll
      for (int nf = 0; nf < 4; nf++)
        acc[mf][nf] = __builtin_amdgcn_mfma_f32_16x16x32_bf16(af[mf], bfr[nf],
                                                              acc[mf][nf], 0, 0, 0);
  }
#pragma unroll
  for (int mf = 0; mf < 4; mf++){
#pragma unroll
    for (int nf = 0; nf < 4; nf++){
#pragma unroll
      for (int r = 0; r < 4; r++){
        const long grow = m0 + wm*64 + mf*16 + lk*4 + r;
        Cm[grow*N + n0 + wn*64 + nf*16 + lr] = acc[mf][nf][r];
      }
    }
  }
}

// ---------------------------------------------------------------------------
// Generic tiled f32 GEMM (small fc GEMMs only)
// ---------------------------------------------------------------------------
template<int AMODE>
__global__ __launch_bounds__(256) void mm_kernel(const void* __restrict__ Aptr,
    const int* __restrict__ idx, const float* __restrict__ Bm,
    float* __restrict__ Cm, int M, int N, int K)
{
  __shared__ __align__(16) float As[8][128];
  __shared__ __align__(16) float Bs[8][132];
  const int tid = threadIdx.x;
  const int n0 = blockIdx.x * 128;
  const int m0 = blockIdx.y * 128;
  const int tr = tid >> 4, tc = tid & 15;
  const int sm = tid & 127, sk = (tid >> 7) * 4;
  const int bk = tid >> 5,  bn = (tid & 31) * 4;
  long arow;
  if constexpr (AMODE == 1) arow = (long)idx[m0 + sm] * K;
  else                      arow = (long)(m0 + sm) * K;
  float acc[8][8];
#pragma unroll
  for (int i = 0; i < 8; i++)
#pragma unroll
    for (int j = 0; j < 8; j++) acc[i][j] = 0.f;

  for (int k0 = 0; k0 < K; k0 += 8){
    float av[4], bv[4];
    {
      const float* A = (const float*)Aptr;
      if (k0 + sk + 3 < K){
        const float4 f = *reinterpret_cast<const float4*>(A + arow + k0 + sk);
        av[0]=f.x; av[1]=f.y; av[2]=f.z; av[3]=f.w;
      } else {
#pragma unroll
        for (int i = 0; i < 4; i++){
          const int kk = k0 + sk + i;
          av[i] = (kk < K) ? A[arow + kk] : 0.f;
        }
      }
    }
    {
      const int kb = k0 + bk;
      if (kb < K){
        const float4 f = *reinterpret_cast<const float4*>(Bm + (long)kb*N + n0 + bn);
        bv[0]=f.x; bv[1]=f.y; bv[2]=f.z; bv[3]=f.w;
      } else { bv[0]=bv[1]=bv[2]=bv[3]=0.f; }
    }
    __syncthreads();
    As[sk+0][sm]=av[0]; As[sk+1][sm]=av[1]; As[sk+2][sm]=av[2]; As[sk+3][sm]=av[3];
    *reinterpret_cast<float4*>(&Bs[bk][bn]) = make_float4(bv[0],bv[1],bv[2],bv[3]);
    __syncthreads();
#pragma unroll
    for (int k = 0; k < 8; k++){
      float a[8], bb[8];
      *(float4*)&a[0]  = *(const float4*)&As[k][tr*8];
      *(float4*)&a[4]  = *(const float4*)&As[k][tr*8+4];
      *(float4*)&bb[0] = *(const float4*)&Bs[k][tc*8];
      *(float4*)&bb[4] = *(const float4*)&Bs[k][tc*8+4];
#pragma unroll
      for (int i = 0; i < 8; i++)
#pragma unroll
        for (int j = 0; j < 8; j++) acc[i][j] += a[i]*bb[j];
    }
  }
#pragma unroll
  for (int i = 0; i < 8; i++){
    const long row = m0 + tr*8 + i;
    *(float4*)(Cm + row*N + n0 + tc*8)     = make_float4(acc[i][0],acc[i][1],acc[i][2],acc[i][3]);
    *(float4*)(Cm + row*N + n0 + tc*8 + 4) = make_float4(acc[i][4],acc[i][5],acc[i][6],acc[i][7]);
  }
}

// ---------------------------------------------------------------------------
// 32x32 LDS-tiled transpose: dst[k*R + j] = src[j*Kc + k]   (f32 -> f32)
// ---------------------------------------------------------------------------
__global__ __launch_bounds__(256) void transpose_k(const float* __restrict__ src,
    float* __restrict__ dst, int R, int Kc)
{
  __shared__ float t[32][33];
  const int bx = blockIdx.x * 32;
  const int by = blockIdx.y * 32;
  const int tx = threadIdx.x & 31, ty = threadIdx.x >> 5;
#pragma unroll
  for (int i = 0; i < 32; i += 8){
    const int j = by + ty + i, k = bx + tx;
    t[ty+i][tx] = (j < R && k < Kc) ? src[(long)j*Kc + k] : 0.f;
  }
  __syncthreads();
#pragma unroll
  for (int i = 0; i < 32; i += 8){
    const int k = bx + ty + i, j = by + tx;
    if (k < Kc && j < R) dst[(long)k*R + j] = t[tx][ty+i];
  }
}

// transpose + bf16 pack: src [K][N] f32 -> dst [N][Kp] bf16 (zero-pad K..Kp)
__global__ __launch_bounds__(256) void packT16(const float* __restrict__ src,
    unsigned short* __restrict__ dst, int K, int N, int Kp)
{
  __shared__ float t[32][33];
  const int bx = blockIdx.x*32;
  const int by = blockIdx.y*32;
  const int tx = threadIdx.x & 31, ty = threadIdx.x >> 5;
#pragma unroll
  for (int i = 0; i < 32; i += 8){
    const int k = bx + ty + i, n = by + tx;
    t[ty+i][tx] = (k < K && n < N) ? src[(long)k*N + n] : 0.f;
  }
  __syncthreads();
#pragma unroll
  for (int i = 0; i < 32; i += 8){
    const int k = bx + tx, n = by + ty + i;
    if (k < Kp && n < N) dst[(long)n*Kp + k] = f2bf(t[tx][ty+i]);
  }
}

// pack Wih (already [768][300] = B^T layout) -> [2][768][320] bf16 zero-padded
__global__ void pack_wih(const float* __restrict__ w0, const float* __restrict__ w1,
                         unsigned short* __restrict__ dst)
{
  const int tid = blockIdx.x*256 + threadIdx.x;
  if (tid < 2*768*320){
    const int d = tid / (768*320);
    const int rem = tid - d*768*320;
    const int n = rem / 320, k = rem - n*320;
    const float* src = d ? w1 : w0;
    dst[tid] = (k < 300) ? f2bf(src[n*300 + k]) : (unsigned short)0;
  }
}

// split+pack WtHH [2][256][768] (r|h|z) f32 -> Wrz16 (r|z) bf16, Wh16 bf16
__global__ void pack_whh16(const float* __restrict__ WtHH,
                           unsigned short* __restrict__ Wrz16,
                           unsigned short* __restrict__ Wh16)
{
  const int tid = blockIdx.x*256 + threadIdx.x;
  if (tid < 2*256*768){
    const int col = tid % 768, rk = tid / 768;
    const unsigned short v = f2bf(WtHH[tid]);
    if (col < 256)       Wrz16[(long)rk*512 + col] = v;
    else if (col < 512)  Wh16 [(long)rk*256 + (col - 256)] = v;
    else                 Wrz16[(long)rk*512 + 256 + (col - 512)] = v;
  }
}

// build gather-index arrays
__global__ void build_idx(const int* __restrict__ context, const int* __restrict__ mchars,
                          int* __restrict__ ctxidx, int* __restrict__ chidx)
{
  const int tid = blockIdx.x*256 + threadIdx.x;
  if (tid < 32768){
    const int t = tid >> 8, b = tid & 255;
    ctxidx[tid] = context[b*128 + t];
  } else if (tid < 32768 + 4096){
    const int o = tid - 32768;
    const int t = o >> 8, b = o & 255;
    chidx[o] = mchars[b*16 + t];
  }
}

// out[r] = sum_k lut[idx[r]][k]^2   (one wave per row)
__global__ __launch_bounds__(256) void sqn_gather(const float* __restrict__ lut,
    const int* __restrict__ idx, int K, float* __restrict__ outp)
{
  const int wv = threadIdx.x >> 6, lane = threadIdx.x & 63;
  const int r = blockIdx.x*4 + wv;
  const float* row = lut + (long)idx[r]*K;
  float s = 0.f;
  for (int k = lane; k < K; k += 64) s += row[k]*row[k];
  s = wred(s);
  if (lane == 0) outp[r] = s;
}

// mobius_matvec tail transform per (row, gate); out bf16 + |out_bf16|^2
__global__ __launch_bounds__(256) void xg_transform(const float* __restrict__ mx,
    const float* __restrict__ xsqn, unsigned short* __restrict__ outp,
    float* __restrict__ n2o, int G)
{
  const int wv = threadIdx.x >> 6, lane = threadIdx.x & 63;
  const int wg = blockIdx.x*4 + wv;
  const int row = wg / G, g = wg - row*G;
  const long base = (long)row*(G*256) + g*256;
  float M[4];
#pragma unroll
  for (int i = 0; i < 4; i++) M[i] = mx[base + i*64 + lane];
  const float mxn2 = wred(sq_part<4>(M));
  float pn2; mt_project<4>(M, mxn2, xsqn[row], &pn2);
  float s = 0.f;
#pragma unroll
  for (int i = 0; i < 4; i++){
    const unsigned short u = f2bf(M[i]);
    outp[base + i*64 + lane] = u;
    const float rv = bf2f(u);
    s += rv*rv;
  }
  s = wred(s);
  if (lane == 0) n2o[wg] = s;
}

// ---------------------------------------------------------------------------
// Mobius GRU v7: 256 blocks x 512 thr (8 waves); 2 batch rows/block.
// Staging over 8 waves (2x outstanding); phase1 roles (gate, k-quarter);
// phase2 roles (k-eighth). Chains verbatim on waves 0-3 / 0-1.
// LDS: wbuf 2x64KB | hs 2K | part 16K | rhb 2K | zb 2K | scal = ~150KB.
// ---------------------------------------------------------------------------
#define GRU_LDS_BYTES 153664

__global__ __launch_bounds__(512,1) void gru_kernel(
    const unsigned short* __restrict__ xg,
    const float* __restrict__ xgn2,
    const unsigned short* __restrict__ Wrz16,
    const unsigned short* __restrict__ Wh16,
    const float* __restrict__ bias_f, const float* __restrict__ bias_b,
    unsigned short* __restrict__ states_f, unsigned short* __restrict__ states_b)
{
  extern __shared__ __align__(16) char smem[];
  float* wbuf = (float*)smem;                    // 2 x 16384 f32 slots (64KB each)
  float* hs   = (float*)(smem + 131072);         // [2][256]
  float* part = (float*)(smem + 133120);         // 4096 floats (16KB)
  float* rhb  = (float*)(smem + 149504);         // [2][256]
  float* zb   = (float*)(smem + 151552);         // [2][256]
  float* scal = (float*)(smem + 153600);         // [2][2]

  const int bid = blockIdx.x;                    // 0..255
  const int dir = bid >> 7;
  const int brow0 = (bid & 127) * 2;
  const int tid = threadIdx.x;
  const int w = tid >> 6, lane = tid & 63;       // w in 0..7
  const int j0 = lane << 2;

  const unsigned short* xgd = xg + (long)dir*32768*768;
  const float* xnd = xgn2 + (long)dir*32768*3;
  const unsigned short* wrz_d = Wrz16 + (long)dir*256*512;
  const unsigned short* wh_d  = Wh16  + (long)dir*256*256;
  const float* bias = dir ? bias_b : bias_f;
  unsigned short* states = dir ? states_b : states_f;

  // FMA roles
  const int fg  = w & 1;             // phase1 gate (0=r cols 0..255, 1=z)
  const int kq4 = w >> 1;            // phase1 k-quarter (16 k) within 64-k chunk
  const int qk8 = w;                 // phase2 k-eighth (16 k) within 128-k chunk
  // chain roles (valid only for small w)
  const int crow  = (w >> 1) & 1;    // gate-chain row (w<4)
  const int cgate = w & 1;           // gate-chain gate (0=r, 1=z)

  float bg[4], bh4[4] = {0,0,0,0};
  float bg2, bh2 = 0.f;
#pragma unroll
  for (int i = 0; i < 4; i++) bg[i] = bias[(cgate ? 512 : 0) + j0 + i];
  bg2 = wred(sq_part<4>(bg));
  if (w < 2){
#pragma unroll
    for (int i = 0; i < 4; i++) bh4[i] = bias[256 + j0 + i];
    bh2 = wred(sq_part<4>(bh4));
  }

  float h[4] = {0.f,0.f,0.f,0.f};    // update-wave register state (w<2)
  float hn2 = 0.f;
  if (w < 2){
#pragma unroll
    for (int i = 0; i < 4; i++) hs[w*256 + j0 + i] = 0.f;
    if (lane == 0){ scal[w*2 + 0] = 0.f; scal[w*2 + 1] = 0.f; }
  }

  int cb = 0;
  stage64k8(wrz_d, wbuf, w, lane);   // Wrz chunk 0 -> buf 0

  for (int t = 0; t < 128; t++){
    const int tt = dir ? (127 - t) : t;
    // ---- role input loads (guarded: only chain waves) ----
    float xgv[4] = {0,0,0,0}, y2g = 0.f, xgh4[4] = {0,0,0,0}, y2h = 0.f;
    if (w < 4){
      const long rxg = (long)tt*256 + brow0 + crow;
      const ushort4 u = *(const ushort4*)(xgd + rxg*768 + (cgate ? 512 : 0) + j0);
      xgv[0]=bf2f(u.x); xgv[1]=bf2f(u.y); xgv[2]=bf2f(u.z); xgv[3]=bf2f(u.w);
      y2g = xnd[rxg*3 + (cgate ? 2 : 0)];
      if (w < 2){
        const long rxh = (long)tt*256 + brow0 + w;
        const ushort4 uh = *(const ushort4*)(xgd + rxh*768 + 256 + j0);
        xgh4[0]=bf2f(uh.x); xgh4[1]=bf2f(uh.y); xgh4[2]=bf2f(uh.z); xgh4[3]=bf2f(uh.w);
        y2h = xnd[rxh*3 + 1];
      }
    }

    // ===== phase 1: r/z matvec, 4 chunks of [64 k][512 cols] bf16 =====
    float s00=0.f,s01=0.f,s02=0.f,s03=0.f, s10=0.f,s11=0.f,s12=0.f,s13=0.f;
#pragma unroll 1
    for (int c = 0; c < 4; c++){
      __syncthreads();                          // chunk c landed, other buf free
      if (c < 3) stage64k8((const char*)wrz_d + (size_t)(c+1)*65536,
                           wbuf + (cb^1)*16384, w, lane);
      const uint2* wb2 = (const uint2*)(wbuf + cb*16384);  // [64][128] uint2
      const int kb = c*64 + kq4*16;
#pragma unroll
      for (int kk = 0; kk < 4; kk++){
        const float4 hb0 = *(const float4*)&hs[0*256 + kb + kk*4];
        const float4 hb1 = *(const float4*)&hs[1*256 + kb + kk*4];
#pragma unroll
        for (int q = 0; q < 4; q++){
          const uint2 wvv = wb2[(kq4*16 + kk*4 + q)*128 + fg*64 + lane];
          const float w0 = bflo(wvv.x), w1 = bfhi(wvv.x);
          const float w2 = bflo(wvv.y), w3 = bfhi(wvv.y);
          const float h0 = (&hb0.x)[q], h1 = (&hb1.x)[q];
          s00 += h0*w0; s01 += h0*w1; s02 += h0*w2; s03 += h0*w3;
          s10 += h1*w0; s11 += h1*w1; s12 += h1*w2; s13 += h1*w3;
        }
      }
      cb ^= 1;
    }
    {
      // part1 layout: [kq4][row][512]; col = fg*256 + j0
      float* p1 = part + kq4*1024 + fg*256 + j0;
      *(float4*)p1         = make_float4(s00,s01,s02,s03);
      *(float4*)(p1 + 512) = make_float4(s10,s11,s12,s13);
    }
    __syncthreads();                            // B_a: partials visible
    stage64k8(wh_d, wbuf + (cb^1)*16384, w, lane);   // prefetch Wh chunk0
    cb ^= 1;

    // ===== gate chain: waves 0..3, role (crow, cgate) =====
    if (w < 4){
      const float* pa = part + crow*512 + cgate*256 + j0;
      const float4 a0 = *(const float4*)pa;
      const float4 a1 = *(const float4*)(pa + 1024);
      const float4 a2 = *(const float4*)(pa + 2048);
      const float4 a3 = *(const float4*)(pa + 3072);
      float a[4] = { (a0.x+a1.x)+(a2.x+a3.x), (a0.y+a1.y)+(a2.y+a3.y),
                     (a0.z+a1.z)+(a2.z+a3.z), (a0.w+a1.w)+(a2.w+a3.w) };
      const float hn2v = scal[crow*2 + 0];
      const float xn_h = snorm(hn2v), art_h = atanhf(clamp11(xn_h));
      const float p2 = wred(sq_part<4>(a));
      float sc, n2; mt_scale(p2, xn_h, art_h, &sc, &n2);
#pragma unroll
      for (int i = 0; i < 4; i++) a[i] *= sc;
      const float xy = wred(dot_part<4>(a, xgv));
      float m1[4]; madd_vec<4>(a, n2, xgv, y2g, xy, m1);
      float m1n2 = sq_part<4>(m1), xyb = dot_part<4>(m1, bg);
      wred2(m1n2, xyb);
      float m2[4]; madd_vec<4>(m1, m1n2, bg, bg2, xyb, m2);
      const float m2n2 = wred(sq_part<4>(m2));
      const float nn = snorm(m2n2), fgc = atanhf(clamp11(nn))/nn;
      float g4[4];
#pragma unroll
      for (int i = 0; i < 4; i++) g4[i] = 1.f/(1.f + expf(-fgc*m2[i]));
      if (cgate == 0){                          // r-gate: compute rh = pwmul(r,h)
        float h4[4];
        *(float4*)h4 = *(const float4*)&hs[crow*256 + j0];
        float rh[4]; float wx2 = 0.f;
#pragma unroll
        for (int i = 0; i < 4; i++){ rh[i] = g4[i]*h4[i]; wx2 += rh[i]*rh[i]; }
        wx2 = wred(wx2);
        float rhn2, scrh;
        {
          const float wxn = snorm(wx2);
          const float trh = tanhf(wxn/xn_h * art_h);
          scrh = trh/wxn; rhn2 = trh*trh;
          const float n = snorm(rhn2);
          if (n > PMAX_){ const float f = PMAX_/n; scrh *= f; rhn2 *= f*f; }
        }
#pragma unroll
        for (int i = 0; i < 4; i++) rh[i] *= scrh;
        *(float4*)&rhb[crow*256 + j0] = make_float4(rh[0],rh[1],rh[2],rh[3]);
        if (lane == 0) scal[crow*2 + 1] = rhn2;
      } else {
        *(float4*)&zb[crow*256 + j0] = make_float4(g4[0],g4[1],g4[2],g4[3]);
      }
    }

    // ===== phase 2: h-gate matvec, 2 chunks of [128 k][256 cols] bf16 =====
    float r00=0.f,r01=0.f,r02=0.f,r03=0.f, r10=0.f,r11=0.f,r12=0.f,r13=0.f;
#pragma unroll 1
    for (int c = 0; c < 2; c++){
      __syncthreads();                          // c==0: rhb/zb ready + chunk landed
      if (c < 1) stage64k8((const char*)wh_d + 65536, wbuf + (cb^1)*16384, w, lane);
      const uint2* wb2 = (const uint2*)(wbuf + cb*16384);  // [128][64] uint2
      const int kb = c*128 + qk8*16;
#pragma unroll
      for (int kk = 0; kk < 4; kk++){
        const float4 hb0 = *(const float4*)&rhb[0*256 + kb + kk*4];
        const float4 hb1 = *(const float4*)&rhb[1*256 + kb + kk*4];
#pragma unroll
        for (int q = 0; q < 4; q++){
          const uint2 wvv = wb2[(qk8*16 + kk*4 + q)*64 + lane];
          const float w0 = bflo(wvv.x), w1 = bfhi(wvv.x);
          const float w2 = bflo(wvv.y), w3 = bfhi(wvv.y);
          const float h0 = (&hb0.x)[q], h1 = (&hb1.x)[q];
          r00 += h0*w0; r01 += h0*w1; r02 += h0*w2; r03 += h0*w3;
          r10 += h1*w0; r11 += h1*w1; r12 += h1*w2; r13 += h1*w3;
        }
      }
      cb ^= 1;
    }
    {
      // part2 layout: [qk8][row][256]
      float* p2 = part + qk8*512 + j0;
      *(float4*)p2         = make_float4(r00,r01,r02,r03);
      *(float4*)(p2 + 256) = make_float4(r10,r11,r12,r13);
    }
    __syncthreads();                            // B_c
    if (t < 127){
      stage64k8(wrz_d, wbuf + (cb^1)*16384, w, lane);
      cb ^= 1;
    }

    // ===== h-update chain: waves 0..1, row = w =====
    if (w < 2){
      float ah[4];
      {
        float4 p[8];
#pragma unroll
        for (int q = 0; q < 8; q++)
          p[q] = *(const float4*)(part + q*512 + w*256 + j0);
        ah[0] = ((p[0].x+p[1].x)+(p[2].x+p[3].x)) + ((p[4].x+p[5].x)+(p[6].x+p[7].x));
        ah[1] = ((p[0].y+p[1].y)+(p[2].y+p[3].y)) + ((p[4].y+p[5].y)+(p[6].y+p[7].y));
        ah[2] = ((p[0].z+p[1].z)+(p[2].z+p[3].z)) + ((p[4].z+p[5].z)+(p[6].z+p[7].z));
        ah[3] = ((p[0].w+p[1].w)+(p[2].w+p[3].w)) + ((p[4].w+p[5].w)+(p[6].w+p[7].w));
      }
      const float rhn2v = scal[w*2 + 1];
      const float rxn = snorm(rhn2v), artr = atanhf(clamp11(rxn));
      float mx2 = sq_part<4>(ah), xyraw = dot_part<4>(ah, xgh4);
      wred2(mx2, xyraw);
      float sch, pn2; mt_scale(mx2, rxn, artr, &sch, &pn2);
#pragma unroll
      for (int i = 0; i < 4; i++) ah[i] *= sch;
      const float xy = xyraw * sch;
      float m1[4]; madd_vec<4>(ah, pn2, xgh4, y2h, xy, m1);
      float m1n2 = sq_part<4>(m1), xyb = dot_part<4>(m1, bh4);
      wred2(m1n2, xyb);
      float ht[4]; madd_vec<4>(m1, m1n2, bh4, bh2, xyb, ht);
      float htn2 = sq_part<4>(ht);
      float nh[4];
#pragma unroll
      for (int i = 0; i < 4; i++) nh[i] = -h[i];
      float xyd = dot_part<4>(nh, ht);
      wred2(htn2, xyd);
      float dl[4]; madd_vec<4>(nh, hn2, ht, htn2, xyd, dl);
      float z4[4];
      *(float4*)z4 = *(const float4*)&zb[w*256 + j0];
      float pw[4]; float dln2 = 0.f, wz2 = 0.f, xyhr = 0.f;
#pragma unroll
      for (int i = 0; i < 4; i++){
        dln2 += dl[i]*dl[i];
        pw[i] = z4[i]*dl[i];
        wz2  += pw[i]*pw[i];
        xyhr += h[i]*pw[i];
      }
      wred3(dln2, wz2, xyhr);
      float pwn2, scpw;
      {
        const float dn   = snorm(dln2);
        const float artd = atanhf(clamp11(dn));
        const float wzn  = snorm(wz2);
        const float tpw  = tanhf(wzn/dn * artd);
        scpw = tpw/wzn; pwn2 = tpw*tpw;
        const float n = snorm(pwn2);
        if (n > PMAX_){ const float f = PMAX_/n; scpw *= f; pwn2 *= f*f; }
      }
#pragma unroll
      for (int i = 0; i < 4; i++) pw[i] *= scpw;
      const float xyh = xyhr * scpw;
      float hnew[4]; madd_vec<4>(h, hn2, pw, pwn2, xyh, hnew);
#pragma unroll
      for (int i = 0; i < 4; i++) h[i] = hnew[i];
      hn2 = wred(sq_part<4>(h));
      *(float4*)&hs[w*256 + j0] = make_float4(h[0],h[1],h[2],h[3]);
      if (lane == 0) scal[w*2 + 0] = hn2;
      unsigned short* srow = states + ((long)(brow0 + w)*128 + tt)*256 + j0;
      ushort4 su; su.x=f2bf(h[0]); su.y=f2bf(h[1]); su.z=f2bf(h[2]); su.w=f2bf(h[3]);
      *(ushort4*)srow = su;
    }
    // next iteration's first __syncthreads orders hs/scal writes vs reads
  }
}

// ---------------------------------------------------------------------------
// Char Mobius-RNN (unchanged)
// ---------------------------------------------------------------------------
__global__ __launch_bounds__(256) void char_rnn(
    const unsigned short* __restrict__ xgc,
    const float* __restrict__ Wc,
    const float* __restrict__ cb,
    float* __restrict__ cstates)
{
  const int wv = threadIdx.x >> 6, lane = threadIdx.x & 63;
  const int b = blockIdx.x*4 + wv;
  const int j0 = lane << 2;
  __shared__ __align__(16) float hs[4][256];
  float h[4] = {0.f,0.f,0.f,0.f};
  float hn2 = 0.f;
#pragma unroll
  for (int i = 0; i < 4; i++) hs[wv][j0+i] = 0.f;
  float cbv[4];
#pragma unroll
  for (int i = 0; i < 4; i++) cbv[i] = cb[j0+i];
  const float cb2 = wred(sq_part<4>(cbv));
  for (int t = 0; t < 16; t++){
    __syncthreads();
    const unsigned short* xr = xgc + ((long)t*256 + b)*256;
    float xgv[4];
    { const ushort4 u = *(const ushort4*)(xr + j0); xgv[0]=bf2f(u.x); xgv[1]=bf2f(u.y); xgv[2]=bf2f(u.z); xgv[3]=bf2f(u.w); }
    float a[4]={0.f,0.f,0.f,0.f};
#pragma unroll 2
    for (int k0 = 0; k0 < 256; k0 += 4){
      const float4 hk = *(const float4*)&hs[wv][k0];
#pragma unroll
      for (int kk = 0; kk < 4; kk++){
        const float hv = (&hk.x)[kk];
        const float4 w4 = *(const float4*)(Wc + (long)(k0+kk)*256 + j0);
        a[0] += hv*w4.x; a[1] += hv*w4.y; a[2] += hv*w4.z; a[3] += hv*w4.w;
      }
    }
    const float mxn2 = wred(sq_part<4>(a));
    float pn2; mt_project<4>(a, mxn2, hn2, &pn2);
    const float y2 = wred(sq_part<4>(xgv));
    const float xy = wred(dot_part<4>(a, xgv));
    float m1[4]; madd_vec<4>(a, pn2, xgv, y2, xy, m1);
    const float m1n2 = wred(sq_part<4>(m1));
    const float xyb  = wred(dot_part<4>(m1, cbv));
    float m2[4]; madd_vec<4>(m1, m1n2, cbv, cb2, xyb, m2);
    float m2n2 = wred(sq_part<4>(m2));
    project_vec<4>(m2, &m2n2);
#pragma unroll
    for (int i = 0; i < 4; i++) h[i] = m2[i];
    hn2 = m2n2;
    *(float4*)&hs[wv][j0] = make_float4(h[0],h[1],h[2],h[3]);
    *(float4*)(cstates + ((long)b*16 + t)*256 + j0) = make_float4(h[0],h[1],h[2],h[3]);
  }
}

// ---------------------------------------------------------------------------
// cc concat (unchanged)
// ---------------------------------------------------------------------------
__global__ __launch_bounds__(256) void cc_rowwise(const unsigned short* __restrict__ sf,
    const unsigned short* __restrict__ sb, const float* __restrict__ mxa,
    const float* __restrict__ mxb, const float* __restrict__ ccb,
    unsigned short* __restrict__ ctxo, int rowoff)
{
  const int wv = threadIdx.x >> 6, lane = threadIdx.x & 63;
  const int rloc = blockIdx.x*4 + wv;
  const long r = rowoff + rloc;
  float s = 0.f;
#pragma unroll
  for (int i = 0; i < 4; i++){ const float v = bf2f(sf[r*256 + i*64+lane]); s += v*v; }
  const float sfn2 = wred(s);
  s = 0.f;
#pragma unroll
  for (int i = 0; i < 4; i++){ const float v = bf2f(sb[r*256 + i*64+lane]); s += v*v; }
  const float sbn2 = wred(s);
  float A[8], Bv[8];
#pragma unroll
  for (int i = 0; i < 8; i++){ A[i]  = mxa[(long)rloc*512 + i*64+lane];
                               Bv[i] = mxb[(long)rloc*512 + i*64+lane]; }
  float pan2, pbn2;
  { const float n2 = wred(sq_part<8>(A));  mt_project<8>(A,  n2, sfn2, &pan2); }
  { const float n2 = wred(sq_part<8>(Bv)); mt_project<8>(Bv, n2, sbn2, &pbn2); }
  const float xy = wred(dot_part<8>(A, Bv));
  float M1[8]; madd_vec<8>(A, pan2, Bv, pbn2, xy, M1);
  const float m1n2 = wred(sq_part<8>(M1));
  float Cb[8];
#pragma unroll
  for (int i = 0; i < 8; i++) Cb[i] = ccb[i*64+lane];
  const float cb2 = wred(sq_part<8>(Cb));
  const float xyb = wred(dot_part<8>(M1, Cb));
  float M2[8]; madd_vec<8>(M1, m1n2, Cb, cb2, xyb, M2);
  float m2n2 = wred(sq_part<8>(M2));
  project_vec<8>(M2, &m2n2);
#pragma unroll
  for (int i = 0; i < 8; i++) ctxo[r*512 + i*64+lane] = f2bf(M2[i]);
}

// attn_emb = madd(ctx(bf16), pe) -> BF16 out + sqn of rounded
__global__ __launch_bounds__(256) void attn_add(const unsigned short* __restrict__ ctxv,
    const int* __restrict__ pos, const float* __restrict__ pet,
    unsigned short* __restrict__ oemb, float* __restrict__ osqn)
{
  const int wv = threadIdx.x >> 6, lane = threadIdx.x & 63;
  const long r = blockIdx.x*4 + wv;
  float X[8];
#pragma unroll
  for (int i = 0; i < 8; i++) X[i] = bf2f(ctxv[r*512 + i*64+lane]);
  const float x2 = wred(sq_part<8>(X));
  const int p = pos[r];
  float Y[8];
#pragma unroll
  for (int i = 0; i < 8; i++) Y[i] = pet[(long)p*512 + i*64+lane];
  const float y2 = wred(sq_part<8>(Y));
  const float xy = wred(dot_part<8>(X, Y));
  float O[8]; madd_vec<8>(X, x2, Y, y2, xy, O);
  float s = 0.f;
#pragma unroll
  for (int i = 0; i < 8; i++){
    const unsigned short u = f2bf(O[i]);
    oemb[r*512 + i*64+lane] = u;
    const float rv = bf2f(u);
    s += rv*rv;
  }
  s = wred(s);
  if (lane == 0) osqn[r] = s;
}

// mention variant (bf16 out)
__global__ __launch_bounds__(256) void attn_add_m(const float* __restrict__ mvv,
    const int* __restrict__ mentions, const float* __restrict__ pet,
    unsigned short* __restrict__ oemb, float* __restrict__ osqn)
{
  const int wv = threadIdx.x >> 6, lane = threadIdx.x & 63;
  const long r = blockIdx.x*4 + wv;
  float X[8];
#pragma unroll
  for (int i = 0; i < 8; i++) X[i] = mvv[r*512 + i*64+lane];
  const float x2 = wred(sq_part<8>(X));
  const int men = mentions[r];
  const int p = (men > 0) ? (int)(r & 7) + 1 : 0;
  float Y[8];
#pragma unroll
  for (int i = 0; i < 8; i++) Y[i] = pet[(long)p*512 + i*64+lane];
  const float y2 = wred(sq_part<8>(Y));
  const float xy = wred(dot_part<8>(X, Y));
  float O[8]; madd_vec<8>(X, x2, Y, y2, xy, O);
  float s = 0.f;
#pragma unroll
  for (int i = 0; i < 8; i++){
    const unsigned short u = f2bf(O[i]);
    oemb[r*512 + i*64+lane] = u;
    const float rv = bf2f(u);
    s += rv*rv;
  }
  s = wred(s);
  if (lane == 0) osqn[r] = s;
}

// q/k projection + pdist (unchanged)
__global__ __launch_bounds__(256) void qk_pdist(const float* __restrict__ mxq,
    const float* __restrict__ mxk, const float* __restrict__ sqn,
    const float* __restrict__ bq, const float* __restrict__ bk,
    float* __restrict__ dout)
{
  const int wv = threadIdx.x >> 6, lane = threadIdx.x & 63;
  const int r = blockIdx.x*4 + wv;
  const float xn2 = sqn[r];
  float Q[8];
#pragma unroll
  for (int i = 0; i < 8; i++) Q[i] = mxq[(long)r*512 + i*64+lane];
  { const float n2 = wred(sq_part<8>(Q)); float pn2; mt_project<8>(Q, n2, xn2, &pn2);
    float Bq[8];
#pragma unroll
    for (int i = 0; i < 8; i++) Bq[i] = bq[i*64+lane];
    const float b2 = wred(sq_part<8>(Bq));
    const float xy = wred(dot_part<8>(Q, Bq));
    float O[8]; madd_vec<8>(Q, pn2, Bq, b2, xy, O);
#pragma unroll
    for (int i = 0; i < 8; i++) Q[i] = O[i];
  }
  float qn2 = wred(sq_part<8>(Q));
  project_vec<8>(Q, &qn2);
  float Kv[8];
#pragma unroll
  for (int i = 0; i < 8; i++) Kv[i] = mxk[(long)r*512 + i*64+lane];
  { const float n2 = wred(sq_part<8>(Kv)); float pn2; mt_project<8>(Kv, n2, xn2, &pn2);
    float Bk[8];
#pragma unroll
    for (int i = 0; i < 8; i++) Bk[i] = bk[i*64+lane];
    const float b2 = wred(sq_part<8>(Bk));
    const float xy = wred(dot_part<8>(Kv, Bk));
    float O[8]; madd_vec<8>(Kv, pn2, Bk, b2, xy, O);
#pragma unroll
    for (int i = 0; i < 8; i++) Kv[i] = O[i];
  }
  float kn2 = wred(sq_part<8>(Kv));
  project_vec<8>(Kv, &kn2);
  float NQ[8];
#pragma unroll
  for (int i = 0; i < 8; i++) NQ[i] = -Q[i];
  const float xy = wred(dot_part<8>(NQ, Kv));
  float Z[8]; madd_vec<8>(NQ, qn2, Kv, kn2, xy, Z);
  const float zn2 = wred(sq_part<8>(Z));
  const float d = 2.f * atanhf(clamp11(snorm(zn2)));
  if (lane == 0) dout[r] = d;
}

__global__ __launch_bounds__(256) void softmax128(const float* __restrict__ d,
    const float* __restrict__ beta, float* __restrict__ w)
{
  const int wv = threadIdx.x >> 6, lane = threadIdx.x & 63;
  const int b = blockIdx.x*4 + wv;
  const float bt = beta[0];
  const float x0 = -bt * d[b*128 + lane];
  const float x1 = -bt * d[b*128 + 64 + lane];
  const float m = wredmax(fmaxf(x0, x1));
  const float e0 = expf(x0 - m), e1 = expf(x1 - m);
  const float s = wred(e0 + e1);
  w[b*128 + lane]      = e0 / s;
  w[b*128 + 64 + lane] = e1 / s;
}

__global__ void softmax8(const float* __restrict__ d, const float* __restrict__ beta,
                         float* __restrict__ w)
{
  const int b = threadIdx.x;   // 256
  const float bt = beta[0];
  float x[8]; float m = -1e30f;
#pragma unroll
  for (int i = 0; i < 8; i++){ x[i] = -bt * d[b*8+i]; m = fmaxf(m, x[i]); }
  float s = 0.f;
#pragma unroll
  for (int i = 0; i < 8; i++){ x[i] = expf(x[i]-m); s += x[i]; }
#pragma unroll
  for (int i = 0; i < 8; i++) w[b*8+i] = x[i] / s;
}

// weighted gyromidpoint via Klein model; one wave per batch row (small Lseq)
template<int NPL, bool BF16V, bool HASW>
__global__ __launch_bounds__(256) void midpoint_kernel(const void* __restrict__ vals,
    const float* __restrict__ wts, float* __restrict__ outp, int Lseq)
{
  const int wv = threadIdx.x >> 6, lane = threadIdx.x & 63;
  const int b = blockIdx.x*4 + wv;
  const int D = NPL*64;
  float num[NPL];
#pragma unroll
  for (int i = 0; i < NPL; i++) num[i] = 0.f;
  float den = 0.f;
  for (int l = 0; l < Lseq; l++){
    const long base = ((long)b*Lseq + l)*D;
    float v[NPL]; float s = 0.f;
#pragma unroll
    for (int i = 0; i < NPL; i++){
      v[i] = BF16V ? bf2f(((const unsigned short*)vals)[base + i*64+lane])
                   : ((const float*)vals)[base + i*64+lane];
      s += v[i]*v[i];
    }
    const float v2 = wred(s);
    const float f = 2.f/(1.f + v2);
    const float kl2 = v2*f*f;
    const float gamma = 1.f/sqrtf(fmaxf(1.f - kl2, EPS_));
    const float wgt = HASW ? wts[b*Lseq + l] : 1.f;
    const float wg = wgt*gamma;
#pragma unroll
    for (int i = 0; i < NPL; i++) num[i] += wg*(f*v[i]);
    den += wg;
  }
  den = fmaxf(den, EPS_);
  float x[NPL]; float s = 0.f;
#pragma unroll
  for (int i = 0; i < NPL; i++){ x[i] = num[i]/den; s += x[i]*x[i]; }
  const float k2 = wred(s);
  const float inv = 1.f/(1.f + sqrtf(fmaxf(1.f - k2, EPS_)));
#pragma unroll
  for (int i = 0; i < NPL; i++) outp[(long)b*D + i*64+lane] = x[i]*inv;
}

// wide gyromidpoint for ctx (unchanged)
__global__ __launch_bounds__(512) void midpoint_wide(
    const unsigned short* __restrict__ vals,
    const float* __restrict__ wts,
    float* __restrict__ outp)
{
  __shared__ float pnum[8][512];
  __shared__ float pden[8];
  __shared__ float red[512];
  __shared__ float kk2[1];
  const int b = blockIdx.x;
  const int tid = threadIdx.x;
  const int w = tid >> 6, lane = tid & 63;
  float num[8] = {0.f,0.f,0.f,0.f,0.f,0.f,0.f,0.f};
  float den = 0.f;
  for (int l = w; l < 128; l += 8){
    const long base = ((long)b*128 + l)*512;
    float v[8]; float s = 0.f;
#pragma unroll
    for (int i = 0; i < 8; i++){
      v[i] = bf2f(vals[base + i*64 + lane]);
      s += v[i]*v[i];
    }
    const float v2 = wred(s);
    const float f = 2.f/(1.f + v2);
    const float kl2 = v2*f*f;
    const float gamma = 1.f/sqrtf(fmaxf(1.f - kl2, EPS_));
    const float wg = wts[b*128 + l]*gamma;
#pragma unroll
    for (int i = 0; i < 8; i++) num[i] += wg*(f*v[i]);
    den += wg;
  }
#pragma unroll
  for (int i = 0; i < 8; i++) pnum[w][i*64 + lane] = num[i];
  if (lane == 0) pden[w] = den;
  __syncthreads();
  float nsum = 0.f, dsum = 0.f;
#pragma unroll
  for (int p = 0; p < 8; p++){ nsum += pnum[p][tid]; dsum += pden[p]; }
  dsum = fmaxf(dsum, EPS_);
  const float x = nsum/dsum;
  red[tid] = x*x;
  __syncthreads();
  if (tid < 64){
    float s2 = 0.f;
#pragma unroll
    for (int i = 0; i < 8; i++) s2 += red[tid + i*64];
    s2 = wred(s2);
    if (tid == 0) kk2[0] = s2;
  }
  __syncthreads();
  const float k2 = kk2[0];
  const float inv = 1.f/(1.f + sqrtf(fmaxf(1.f - k2, EPS_)));
  outp[(long)b*512 + tid] = x*inv;
}

// mention w2s mobius_linear with tanh nonlinearity (unchanged)
__global__ __launch_bounds__(256) void mv_rowwise(const float* __restrict__ mx,
    const float* __restrict__ xsqn, const float* __restrict__ bb, float* __restrict__ outp)
{
  const int wv = threadIdx.x >> 6, lane = threadIdx.x & 63;
  const long r = blockIdx.x*4 + wv;
  float M[8];
#pragma unroll
  for (int i = 0; i < 8; i++) M[i] = mx[r*512 + i*64+lane];
  { const float n2 = wred(sq_part<8>(M)); float pn2; mt_project<8>(M, n2, xsqn[r], &pn2);
    float Bv[8];
#pragma unroll
    for (int i = 0; i < 8; i++) Bv[i] = bb[i*64+lane];
    const float b2 = wred(sq_part<8>(Bv));
    const float xy = wred(dot_part<8>(M, Bv));
    float O[8]; madd_vec<8>(M, pn2, Bv, b2, xy, O);
#pragma unroll
    for (int i = 0; i < 8; i++) M[i] = O[i];
  }
  float on2 = wred(sq_part<8>(M));
  project_vec<8>(M, &on2);
  { const float n = snorm(on2);
    const float fac = atanhf(clamp11(n))/n;
#pragma unroll
    for (int i = 0; i < 8; i++) M[i] = tanhf(fac*M[i]); }
  const float un2 = wred(sq_part<8>(M));
  { const float n = snorm(un2);
    const float fac = tanhf(n)/n;
    float en2 = fac*fac*un2;
#pragma unroll
    for (int i = 0; i < 8; i++) M[i] *= fac;
    project_vec<8>(M, &en2); }
#pragma unroll
  for (int i = 0; i < 8; i++) outp[r*512 + i*64+lane] = M[i];
}

// joint concat (unchanged)
__global__ __launch_bounds__(256) void final_rowwise(const float* __restrict__ jm,
    const float* __restrict__ jc, const float* __restrict__ jch,
    const float* __restrict__ mvec, const float* __restrict__ cvec,
    const float* __restrict__ chvec, const float* __restrict__ fcb,
    float* __restrict__ joint)
{
  const int wv = threadIdx.x >> 6, lane = threadIdx.x & 63;
  const long b = blockIdx.x*4 + wv;
  float s;
  s = 0.f; for (int i = 0; i < 8; i++){ const float v = mvec[b*512 + i*64+lane]; s += v*v; }
  const float mn2 = wred(s);
  s = 0.f; for (int i = 0; i < 8; i++){ const float v = cvec[b*512 + i*64+lane]; s += v*v; }
  const float cn2 = wred(s);
  s = 0.f; for (int i = 0; i < 4; i++){ const float v = chvec[b*256 + i*64+lane]; s += v*v; }
  const float chn2 = wred(s);
  float A[20];
#pragma unroll
  for (int i = 0; i < 20; i++) A[i] = jm[b*1280 + i*64+lane];
  float an2;
  { const float n2 = wred(sq_part<20>(A)); mt_project<20>(A, n2, mn2, &an2); }
  float T[20];
#pragma unroll
  for (int i = 0; i < 20; i++) T[i] = jc[b*1280 + i*64+lane];
  float tn2;
  { const float n2 = wred(sq_part<20>(T)); mt_project<20>(T, n2, cn2, &tn2); }
  { const float xy = wred(dot_part<20>(A, T));
    float O[20]; madd_vec<20>(A, an2, T, tn2, xy, O);
#pragma unroll
    for (int i = 0; i < 20; i++) A[i] = O[i];
    an2 = wred(sq_part<20>(A)); }
#pragma unroll
  for (int i = 0; i < 20; i++) T[i] = jch[b*1280 + i*64+lane];
  { const float n2 = wred(sq_part<20>(T)); mt_project<20>(T, n2, chn2, &tn2); }
  { const float xy = wred(dot_part<20>(A, T));
    float O[20]; madd_vec<20>(A, an2, T, tn2, xy, O);
#pragma unroll
    for (int i = 0; i < 20; i++) A[i] = O[i];
    an2 = wred(sq_part<20>(A)); }
#pragma unroll
  for (int i = 0; i < 20; i++) T[i] = fcb[i*64+lane];
  tn2 = wred(sq_part<20>(T));
  { const float xy = wred(dot_part<20>(A, T));
    float O[20]; madd_vec<20>(A, an2, T, tn2, xy, O);
#pragma unroll
    for (int i = 0; i < 20; i++) A[i] = O[i];
    an2 = wred(sq_part<20>(A)); }
  project_vec<20>(A, &an2);
#pragma unroll
  for (int i = 0; i < 20; i++) joint[b*1280 + i*64+lane] = A[i];
}

// hyperbolic MLR head (unchanged)
__global__ __launch_bounds__(256) void mlr_kernel(const float* __restrict__ joint,
    const float* __restrict__ P, const float* __restrict__ A, float* __restrict__ outp)
{
  const int wv = threadIdx.x >> 6, lane = threadIdx.x & 63;
  const int pair = blockIdx.x*4 + wv;
  const long b = pair >> 7, c = pair & 127;
  float Pv[20], J[20];
#pragma unroll
  for (int i = 0; i < 20; i++){
    Pv[i] = -P[c*1280 + i*64+lane];
    J[i]  = joint[b*1280 + i*64+lane];
  }
  const float p2 = wred(sq_part<20>(Pv));
  const float j2 = wred(sq_part<20>(J));
  const float xy = wred(dot_part<20>(Pv, J));
  float Z[20]; madd_vec<20>(Pv, p2, J, j2, xy, Z);
  float sza = 0.f, sz2 = 0.f, sa2 = 0.f;
#pragma unroll
  for (int i = 0; i < 20; i++){
    const float a = A[c*1280 + i*64+lane];
    sza += Z[i]*a; sz2 += Z[i]*Z[i]; sa2 += a*a;
  }
  float za = sza, z2 = sz2, a2 = sa2;
  wred3(za, z2, a2);
  const float an = sqrtf(fmaxf(a2, EPS_));
  const float v = 2.f*za / (fmaxf(1.f - z2, EPS_)*an);
  if (lane == 0) outp[pair] = 2.f*an*asinhf(v);
}

// ---------------------------------------------------------------------------
extern "C" void kernel_launch(void* const* d_in, const int* in_sizes, int n_in,
                              void* d_out, int out_size, void* d_ws, size_t ws_size,
                              hipStream_t stream)
{
  (void)in_sizes; (void)n_in; (void)out_size;
  const int*   context   = (const int*)  d_in[0];
  const int*   ctx_position=(const int*) d_in[1];
  const int*   mentions  = (const int*)  d_in[2];
  const int*   mchars    = (const int*)  d_in[3];
  const float* word_lut  = (const float*)d_in[4];
  const float* char_lut  = (const float*)d_in[5];
  const float* gf_Wih    = (const float*)d_in[6];
  const float* gf_Whh    = (const float*)d_in[7];
  const float* gf_b      = (const float*)d_in[8];
  const float* gb_Wih    = (const float*)d_in[9];
  const float* gb_Whh    = (const float*)d_in[10];
  const float* gb_b      = (const float*)d_in[11];
  const float* w2s_W     = (const float*)d_in[12];
  const float* w2s_b     = (const float*)d_in[13];
  const float* men_pos   = (const float*)d_in[14];
  const float* men_Wq    = (const float*)d_in[15];
  const float* men_bq    = (const float*)d_in[16];
  const float* men_Wk    = (const float*)d_in[17];
  const float* men_bk    = (const float*)d_in[18];
  const float* men_beta  = (const float*)d_in[19];
  const float* char_W    = (const float*)d_in[20];
  const float* char_U    = (const float*)d_in[21];
  const float* char_b    = (const float*)d_in[22];
  const float* cc_Wa     = (const float*)d_in[23];
  const float* cc_Wb     = (const float*)d_in[24];
  const float* cc_bias   = (const float*)d_in[25];
  const float* ctx_pos_t = (const float*)d_in[26];
  const float* ctx_Wq    = (const float*)d_in[27];
  const float* ctx_bq    = (const float*)d_in[28];
  const float* ctx_Wk    = (const float*)d_in[29];
  const float* ctx_bk    = (const float*)d_in[30];
  const float* ctx_beta  = (const float*)d_in[31];
  const float* fc_Wm     = (const float*)d_in[32];
  const float* fc_Wc     = (const float*)d_in[33];
  const float* fc_Wch    = (const float*)d_in[34];
  const float* fc_bias   = (const float*)d_in[35];
  const float* mlr_p     = (const float*)d_in[36];
  const float* mlr_a     = (const float*)d_in[37];
  float* out = (float*)d_out;

  // ---- workspace bump allocator ----
  char* wsb = (char*)d_ws;
  size_t off = 0;
  auto alloc = [&](size_t bytes) -> void* {
    void* p = wsb + off;
    off += (bytes + 255) & ~(size_t)255;
    return p;
  };
  float* WtHH = (float*)alloc(2UL*256*768*4);
  unsigned short* Wrz16 = (unsigned short*)alloc(2UL*256*512*2);
  unsigned short* Wh16  = (unsigned short*)alloc(2UL*256*256*2);
  unsigned short* WihP  = (unsigned short*)alloc(2UL*768*320*2);
  unsigned short* ctxWqP= (unsigned short*)alloc(512UL*512*2);
  unsigned short* ctxWkP= (unsigned short*)alloc(512UL*512*2);
  unsigned short* ccWaP = (unsigned short*)alloc(512UL*256*2);
  unsigned short* ccWbP = (unsigned short*)alloc(512UL*256*2);
  unsigned short* menWqP= (unsigned short*)alloc(512UL*512*2);
  unsigned short* menWkP= (unsigned short*)alloc(512UL*512*2);
  unsigned short* w2sP  = (unsigned short*)alloc(512UL*320*2);
  unsigned short* charUP= (unsigned short*)alloc(256UL*256*2);
  int*   ctxidx = (int*)alloc(32768UL*4);
  int*   chidx  = (int*)alloc(4096UL*4);
  float* xsqn   = (float*)alloc(32768UL*4);
  float* msqn   = (float*)alloc(2048UL*4);
  float* chsqn  = (float*)alloc(4096UL*4);
  unsigned short* xg = (unsigned short*)alloc(2UL*32768*768*2);
  float* xgn2 = (float*)alloc(2UL*32768*3*4);
  float* chn2d = (float*)alloc(4096UL*4);
  unsigned short* states_f = (unsigned short*)alloc(32768UL*256*2);
  unsigned short* states_b = (unsigned short*)alloc(32768UL*256*2);
  unsigned short* ctxv = (unsigned short*)alloc(32768UL*512*2);
  float* attn_sqn = (float*)alloc(32768UL*4);
  float* dctx = (float*)alloc(32768UL*4);
  float* wctx = (float*)alloc(32768UL*4);
  float* ctx_vec = (float*)alloc(256UL*512*4);
  float* mxbuf = (float*)alloc(2UL*8192*512*4);
  float* mv = (float*)alloc(2048UL*512*4);
  unsigned short* attn_embm = (unsigned short*)alloc(2048UL*512*2);
  float* amsqn = (float*)alloc(2048UL*4);
  float* dm = (float*)alloc(2048UL*4);
  float* wm = (float*)alloc(2048UL*4);
  float* mention_vec = (float*)alloc(256UL*512*4);
  unsigned short* xgc = (unsigned short*)alloc(4096UL*256*2);
  float* char_states = (float*)alloc(4096UL*256*4);
  float* char_vec = (float*)alloc(256UL*256*4);
  float* joint = (float*)alloc(256UL*1280*4);
  if (off > ws_size) return;
  unsigned short* attn_embc = xg;                  // overlay: xg dead after GRU
  float* mxh0 = mxbuf;
  float* mxh1 = mxbuf + 8192UL*512;

  // ---- weight transposes + bf16 packs ----
  transpose_k<<<dim3(8,24), 256,0,stream>>>(gf_Whh, WtHH,            768, 256);
  transpose_k<<<dim3(8,24), 256,0,stream>>>(gb_Whh, WtHH + 256*768,  768, 256);
  pack_whh16<<<1536,256,0,stream>>>(WtHH, Wrz16, Wh16);
  pack_wih<<<1920,256,0,stream>>>(gf_Wih, gb_Wih, WihP);
  packT16<<<dim3(16,16),256,0,stream>>>(ctx_Wq, ctxWqP, 512, 512, 512);
  packT16<<<dim3(16,16),256,0,stream>>>(ctx_Wk, ctxWkP, 512, 512, 512);
  packT16<<<dim3(8,16), 256,0,stream>>>(cc_Wa,  ccWaP,  256, 512, 256);
  packT16<<<dim3(8,16), 256,0,stream>>>(cc_Wb,  ccWbP,  256, 512, 256);
  packT16<<<dim3(16,16),256,0,stream>>>(men_Wq, menWqP, 512, 512, 512);
  packT16<<<dim3(16,16),256,0,stream>>>(men_Wk, menWkP, 512, 512, 512);
  packT16<<<dim3(10,16),256,0,stream>>>(w2s_W,  w2sP,   300, 512, 320);
  packT16<<<dim3(8,8),  256,0,stream>>>(char_U, charUP, 256, 256, 256);

  // ---- gather indices + input sqn ----
  build_idx<<<144,256,0,stream>>>(context, mchars, ctxidx, chidx);
  sqn_gather<<<8192,256,0,stream>>>(word_lut, ctxidx, 300, xsqn);
  sqn_gather<<<512, 256,0,stream>>>(word_lut, mentions, 300, msqn);
  sqn_gather<<<1024,256,0,stream>>>(char_lut, chidx, 256, chsqn);

  // ---- GRU input precompute: xg[dir] = mobius_matvec(emb, Wih^T), bf16 ----
  for (int d2 = 0; d2 < 2; d2++){
    const unsigned short* wihp = WihP + (size_t)d2*768*320;
    for (int c = 0; c < 4; c++){
      mfma_mm<1><<<dim3(6,64),256,0,stream>>>(word_lut, ctxidx + c*8192, wihp,
                                              mxbuf, 8192, 768, 300, 320);
      xg_transform<<<6144,256,0,stream>>>(mxbuf, xsqn + c*8192,
          xg + ((size_t)d2*32768 + (size_t)c*8192)*768,
          xgn2 + ((size_t)d2*32768 + (size_t)c*8192)*3, 3);
    }
  }

  // ---- bidirectional Mobius GRU (8-wave v7) ----
  (void)hipFuncSetAttribute((const void*)gru_kernel,
      hipFuncAttributeMaxDynamicSharedMemorySize, GRU_LDS_BYTES);
  gru_kernel<<<256,512,GRU_LDS_BYTES,stream>>>(xg, xgn2, Wrz16, Wh16,
                                               gf_b, gb_b, states_f, states_b);

  // ---- mobius concat of directions -> ctx (bf16) ----
  for (int c = 0; c < 4; c++){
    mfma_mm<2><<<dim3(4,64),256,0,stream>>>(states_f + (size_t)c*8192*256, nullptr,
                                            ccWaP, mxh0, 8192, 512, 256, 256);
    mfma_mm<2><<<dim3(4,64),256,0,stream>>>(states_b + (size_t)c*8192*256, nullptr,
                                            ccWbP, mxh1, 8192, 512, 256, 256);
    cc_rowwise<<<2048,256,0,stream>>>(states_f, states_b, mxh0, mxh1, cc_bias,
                                      ctxv, c*8192);
  }

  // ---- context distance attention ----
  attn_add<<<8192,256,0,stream>>>(ctxv, ctx_position, ctx_pos_t, attn_embc, attn_sqn);
  for (int c = 0; c < 4; c++){
    mfma_mm<2><<<dim3(4,64),256,0,stream>>>(attn_embc + (size_t)c*8192*512, nullptr,
                                            ctxWqP, mxh0, 8192, 512, 512, 512);
    mfma_mm<2><<<dim3(4,64),256,0,stream>>>(attn_embc + (size_t)c*8192*512, nullptr,
                                            ctxWkP, mxh1, 8192, 512, 512, 512);
    qk_pdist<<<2048,256,0,stream>>>(mxh0, mxh1, attn_sqn + c*8192, ctx_bq, ctx_bk,
                                    dctx + c*8192);
  }
  softmax128<<<64,256,0,stream>>>(dctx, ctx_beta, wctx);
  midpoint_wide<<<256,512,0,stream>>>(ctxv, wctx, ctx_vec);

  // ---- mention encoder ----
  mfma_mm<1><<<dim3(4,16),256,0,stream>>>(word_lut, mentions, w2sP, mxh0,
                                          2048, 512, 300, 320);
  mv_rowwise<<<512,256,0,stream>>>(mxh0, msqn, w2s_b, mv);
  attn_add_m<<<512,256,0,stream>>>(mv, mentions, men_pos, attn_embm, amsqn);
  mfma_mm<2><<<dim3(4,16),256,0,stream>>>(attn_embm, nullptr, menWqP, mxh0,
                                          2048, 512, 512, 512);
  mfma_mm<2><<<dim3(4,16),256,0,stream>>>(attn_embm, nullptr, menWkP, mxh1,
                                          2048, 512, 512, 512);
  qk_pdist<<<512,256,0,stream>>>(mxh0, mxh1, amsqn, men_bq, men_bk, dm);
  softmax8<<<1,256,0,stream>>>(dm, men_beta, wm);
  midpoint_kernel<8,false,true><<<64,256,0,stream>>>(mv, wm, mention_vec, 8);

  // ---- char encoder ----
  mfma_mm<1><<<dim3(2,32),256,0,stream>>>(char_lut, chidx, charUP, mxh0,
                                          4096, 256, 256, 256);
  xg_transform<<<1024,256,0,stream>>>(mxh0, chsqn, xgc, chn2d, 1);
  char_rnn<<<64,256,0,stream>>>(xgc, char_W, char_b, char_states);
  midpoint_kernel<4,false,false><<<64,256,0,stream>>>(char_states, nullptr, char_vec, 16);

  // ---- full mobius concat + MLR (small, f32 path) ----
  float* jm = mxh0;
  float* jc = mxh0 + 256UL*1280;
  float* jch = mxh0 + 2UL*256*1280;
  mm_kernel<0><<<dim3(10,2),256,0,stream>>>(mention_vec, nullptr, fc_Wm, jm, 256, 1280, 512);
  mm_kernel<0><<<dim3(10,2),256,0,stream>>>(ctx_vec,     nullptr, fc_Wc, jc, 256, 1280, 512);
  mm_kernel<0><<<dim3(10,2),256,0,stream>>>(char_vec,    nullptr, fc_Wch, jch, 256, 1280, 256);
  final_rowwise<<<64,256,0,stream>>>(jm, jc, jch, mention_vec, ctx_vec, char_vec,
                                     fc_bias, joint);
  mlr_kernel<<<8192,256,0,stream>>>(joint, mlr_p, mlr_a, out);
}